// Round 1
// baseline (1590.863 us; speedup 1.0000x reference)
//
#include <hip/hip_runtime.h>
#include <math.h>

#define BB 4
#define S 1024
#define D 512
#define H 8
#define DKH 64

// ---------------- block-level reduce helpers (256 threads) ----------------
__device__ __forceinline__ float blk_sum(float* r, int t, float v){
  r[t] = v; __syncthreads();
  for (int s = 128; s > 0; s >>= 1){
    if (t < s) r[t] += r[t + s];
    __syncthreads();
  }
  float res = r[0]; __syncthreads();
  return res;
}

// ---------------- GEMM: C[M,N] = A[M,K] @ W[N,K]^T + bias ----------------
// tile 64x64, thread 4x4, K-chunk 32, k-major LDS
__global__ __launch_bounds__(256) void gemm_bias(
    const float* __restrict__ A, const float* __restrict__ W,
    const float* __restrict__ bias, float* __restrict__ C,
    int M, int N, int K)
{
  __shared__ float As[32][68];
  __shared__ float Ws[32][68];
  const int t = threadIdx.x;
  const int tx = t & 15, ty = t >> 4;
  const int n0 = blockIdx.x * 64, m0 = blockIdx.y * 64;
  const int r  = t >> 3;          // 0..31
  const int kq = (t & 7) << 2;    // 0,4,..,28
  float acc[4][4] = {{0.f}};
  for (int k0 = 0; k0 < K; k0 += 32){
    float4 a0 = *(const float4*)&A[(size_t)(m0 + r)      * K + k0 + kq];
    float4 a1 = *(const float4*)&A[(size_t)(m0 + r + 32) * K + k0 + kq];
    float4 w0 = *(const float4*)&W[(size_t)(n0 + r)      * K + k0 + kq];
    float4 w1 = *(const float4*)&W[(size_t)(n0 + r + 32) * K + k0 + kq];
    As[kq+0][r]    = a0.x; As[kq+1][r]    = a0.y; As[kq+2][r]    = a0.z; As[kq+3][r]    = a0.w;
    As[kq+0][r+32] = a1.x; As[kq+1][r+32] = a1.y; As[kq+2][r+32] = a1.z; As[kq+3][r+32] = a1.w;
    Ws[kq+0][r]    = w0.x; Ws[kq+1][r]    = w0.y; Ws[kq+2][r]    = w0.z; Ws[kq+3][r]    = w0.w;
    Ws[kq+0][r+32] = w1.x; Ws[kq+1][r+32] = w1.y; Ws[kq+2][r+32] = w1.z; Ws[kq+3][r+32] = w1.w;
    __syncthreads();
    #pragma unroll
    for (int kk = 0; kk < 32; kk++){
      float4 av = *(const float4*)&As[kk][ty << 2];
      float4 wv = *(const float4*)&Ws[kk][tx << 2];
      float aa[4] = {av.x, av.y, av.z, av.w};
      float ww[4] = {wv.x, wv.y, wv.z, wv.w};
      #pragma unroll
      for (int ii = 0; ii < 4; ii++)
        #pragma unroll
        for (int jj = 0; jj < 4; jj++)
          acc[ii][jj] += aa[ii] * ww[jj];
    }
    __syncthreads();
  }
  const int n = n0 + (tx << 2);
  float4 bv = *(const float4*)&bias[n];
  #pragma unroll
  for (int ii = 0; ii < 4; ii++){
    const int m = m0 + (ty << 2) + ii;
    float4 o = make_float4(acc[ii][0] + bv.x, acc[ii][1] + bv.y,
                           acc[ii][2] + bv.z, acc[ii][3] + bv.w);
    *(float4*)&C[(size_t)m * N + n] = o;
  }
}

// ---------------- scores: Smat[h,i,j] = dot64(q_i, k_j)/8 (per b) ----------------
// grid (S/64 jtile, S/64 itile, H)
__global__ __launch_bounds__(256) void scores_qk(
    const float* __restrict__ Q, const float* __restrict__ Km,
    float* __restrict__ Smat, int b)
{
  __shared__ float Qs[64][68];
  __shared__ float Ks[64][68];
  const int t = threadIdx.x;
  const int tx = t & 15, ty = t >> 4;
  const int j0 = blockIdx.x * 64, i0 = blockIdx.y * 64, h = blockIdx.z;
  const float* Qb = Q  + (size_t)b * S * D + (size_t)h * DKH;
  const float* Kb = Km + (size_t)b * S * D + (size_t)h * DKH;
  #pragma unroll
  for (int p = 0; p < 4; p++){
    int lin = t + p * 256;
    int rr = lin >> 4;
    int d4 = (lin & 15) << 2;
    float4 q = *(const float4*)&Qb[(size_t)(i0 + rr) * D + d4];
    Qs[d4+0][rr] = q.x; Qs[d4+1][rr] = q.y; Qs[d4+2][rr] = q.z; Qs[d4+3][rr] = q.w;
    float4 k = *(const float4*)&Kb[(size_t)(j0 + rr) * D + d4];
    Ks[d4+0][rr] = k.x; Ks[d4+1][rr] = k.y; Ks[d4+2][rr] = k.z; Ks[d4+3][rr] = k.w;
  }
  __syncthreads();
  float acc[4][4] = {{0.f}};
  #pragma unroll
  for (int d = 0; d < 64; d++){
    float4 qv = *(const float4*)&Qs[d][ty << 2];
    float4 kv = *(const float4*)&Ks[d][tx << 2];
    float aa[4] = {qv.x, qv.y, qv.z, qv.w};
    float ww[4] = {kv.x, kv.y, kv.z, kv.w};
    #pragma unroll
    for (int ii = 0; ii < 4; ii++)
      #pragma unroll
      for (int jj = 0; jj < 4; jj++)
        acc[ii][jj] += aa[ii] * ww[jj];
  }
  #pragma unroll
  for (int ii = 0; ii < 4; ii++){
    const int ig = i0 + (ty << 2) + ii;
    float4 o = make_float4(acc[ii][0]*0.125f, acc[ii][1]*0.125f,
                           acc[ii][2]*0.125f, acc[ii][3]*0.125f);
    *(float4*)&Smat[((size_t)h * S + ig) * S + j0 + (tx << 2)] = o;
  }
}

// ---------------- decay + double softmax, one wave per row ----------------
// grid (S, H), block 64.  c3 != null => scores are c3[(b*H+h)*S + j] (block 3)
__global__ __launch_bounds__(64) void decay_kernel(
    float* __restrict__ Smat, const float* __restrict__ c3,
    const float* __restrict__ g, int diag, int zero_pad, int b)
{
  const int i = blockIdx.x, h = blockIdx.y, l = threadIdx.x;
  float* row = Smat + ((size_t)h * S + i) * S;
  if (zero_pad && i == 0){
    float4 z = make_float4(0.f, 0.f, 0.f, 0.f);
    #pragma unroll
    for (int p = 0; p < 4; p++) ((float4*)row)[l * 4 + p] = z;
    return;
  }
  const float* src = c3 ? (c3 + (size_t)(b * H + h) * S) : row;
  float c[16];
  #pragma unroll
  for (int p = 0; p < 4; p++){
    float4 x = ((const float4*)src)[l * 4 + p];
    c[p*4+0] = x.x; c[p*4+1] = x.y; c[p*4+2] = x.z; c[p*4+3] = x.w;
  }
  const int j0 = l * 16;
  const int jmax = i + diag;           // masked: j <= jmax
  // masked max
  float m1 = -3.0e38f;
  #pragma unroll
  for (int q = 0; q < 16; q++) if (j0 + q <= jmax) m1 = fmaxf(m1, c[q]);
  #pragma unroll
  for (int off = 1; off < 64; off <<= 1) m1 = fmaxf(m1, __shfl_xor(m1, off, 64));
  // masked softmax (normalized)
  float e[16]; float lsum = 0.f;
  #pragma unroll
  for (int q = 0; q < 16; q++){
    float v = (j0 + q <= jmax) ? expf(c[q] - m1) : 0.f;
    e[q] = v; lsum += v;
  }
  float sum1 = lsum;
  #pragma unroll
  for (int off = 1; off < 64; off <<= 1) sum1 += __shfl_xor(sum1, off, 64);
  const float inv1 = (jmax >= 0) ? 1.f / sum1 : 0.f;
  // inclusive cumsum over j
  float pl[16]; float run = 0.f;
  #pragma unroll
  for (int q = 0; q < 16; q++){ run += e[q] * inv1; pl[q] = run; }
  float scn = run;
  #pragma unroll
  for (int off = 1; off < 64; off <<= 1){
    float u = __shfl_up(scn, off, 64);
    if (l >= off) scn += u;
  }
  const float T = __shfl(scn, 63, 64);  // disttotal (1 or 0)
  const float excl = scn - run;
  float gm;
  { float gv = g[h]; gm = -((gv > 20.f) ? gv : log1pf(expf(gv))); }  // -softplus
  // decay rescale of RAW scores
  float sc[16];
  #pragma unroll
  for (int q = 0; q < 16; q++){
    float rem = T - (excl + pl[q]); rem = fmaxf(rem, 0.f);
    float pos = fabsf((float)(i - (j0 + q)));
    float eff = expf(gm * sqrtf(rem * pos));
    eff = fminf(fmaxf(eff, 1e-5f), 1e5f);
    sc[q] = c[q] * eff;
  }
  // second softmax over ALL j (faithful: no re-mask)
  float m2 = sc[0];
  #pragma unroll
  for (int q = 1; q < 16; q++) m2 = fmaxf(m2, sc[q]);
  #pragma unroll
  for (int off = 1; off < 64; off <<= 1) m2 = fmaxf(m2, __shfl_xor(m2, off, 64));
  float p[16]; float ls2 = 0.f;
  #pragma unroll
  for (int q = 0; q < 16; q++){ p[q] = expf(sc[q] - m2); ls2 += p[q]; }
  #pragma unroll
  for (int off = 1; off < 64; off <<= 1) ls2 += __shfl_xor(ls2, off, 64);
  const float inv2 = 1.f / ls2;
  #pragma unroll
  for (int p4 = 0; p4 < 4; p4++){
    float4 o = make_float4(p[p4*4+0]*inv2, p[p4*4+1]*inv2,
                           p[p4*4+2]*inv2, p[p4*4+3]*inv2);
    ((float4*)row)[l * 4 + p4] = o;
  }
}

// ---------------- AV: ctx[b,i,h*64+d] = sum_j att[h,i,j] * v[b,j,h*64+d] ----------------
// grid (S/32, H), tile 32(i) x 64(d), thread 2x4, K-chunk 32
__global__ __launch_bounds__(256) void av_gemm(
    const float* __restrict__ Att, const float* __restrict__ V,
    float* __restrict__ Ctx, int b)
{
  __shared__ float Atts[32][34];
  __shared__ float Vs[32][68];
  const int t = threadIdx.x;
  const int tx = t & 15, ty = t >> 4;
  const int i0 = blockIdx.x * 32, h = blockIdx.y;
  const float* Ab = Att + (size_t)h * S * S;
  const float* Vb = V + (size_t)b * S * D + (size_t)h * DKH;
  const int ar = t >> 3;
  const int aq = (t & 7) << 2;
  float acc[2][4] = {{0.f}};
  for (int jc = 0; jc < S; jc += 32){
    float4 a = *(const float4*)&Ab[(size_t)(i0 + ar) * S + jc + aq];
    Atts[aq+0][ar] = a.x; Atts[aq+1][ar] = a.y; Atts[aq+2][ar] = a.z; Atts[aq+3][ar] = a.w;
    #pragma unroll
    for (int p = 0; p < 2; p++){
      int lin = t + p * 256;
      int jj = lin >> 4;
      int d4 = (lin & 15) << 2;
      float4 v4 = *(const float4*)&Vb[(size_t)(jc + jj) * D + d4];
      *(float4*)&Vs[jj][d4] = v4;
    }
    __syncthreads();
    #pragma unroll
    for (int jj = 0; jj < 32; jj++){
      float a0 = Atts[jj][(ty << 1) + 0];
      float a1 = Atts[jj][(ty << 1) + 1];
      float4 v4 = *(const float4*)&Vs[jj][tx << 2];
      acc[0][0] += a0*v4.x; acc[0][1] += a0*v4.y; acc[0][2] += a0*v4.z; acc[0][3] += a0*v4.w;
      acc[1][0] += a1*v4.x; acc[1][1] += a1*v4.y; acc[1][2] += a1*v4.z; acc[1][3] += a1*v4.w;
    }
    __syncthreads();
  }
  #pragma unroll
  for (int rr = 0; rr < 2; rr++){
    float4 o = make_float4(acc[rr][0], acc[rr][1], acc[rr][2], acc[rr][3]);
    *(float4*)&Ctx[((size_t)b * S + i0 + (ty << 1) + rr) * D + h * DKH + (tx << 2)] = o;
  }
}

// ---------------- residual + LayerNorm ----------------
__global__ __launch_bounds__(256) void ln_residual(
    const float* __restrict__ resid, const float* __restrict__ y,
    const float* __restrict__ ls, const float* __restrict__ lb,
    float* __restrict__ out, int bcast)
{
  const int r = blockIdx.x, t = threadIdx.x;
  __shared__ float red[256];
  const size_t base = (size_t)r * D;
  float r0 = bcast ? resid[t]       : resid[base + t];
  float r1 = bcast ? resid[t + 256] : resid[base + t + 256];
  float x0 = r0 + y[base + t];
  float x1 = r1 + y[base + t + 256];
  float mean = blk_sum(red, t, x0 + x1) * (1.0f / 512.0f);
  float d0 = x0 - mean, d1 = x1 - mean;
  float var = blk_sum(red, t, d0*d0 + d1*d1) * (1.0f / 512.0f);
  float inv = rsqrtf(var + 1e-5f);
  out[base + t]       = d0 * inv * ls[t]       + lb[t];
  out[base + t + 256] = d1 * inv * ls[t + 256] + lb[t + 256];
}

// ---------------- small kernels ----------------
__global__ __launch_bounds__(256) void qvec3_kernel(
    const float* __restrict__ know, const float* __restrict__ Wq3,
    const float* __restrict__ bq3, float* __restrict__ q3)
{
  int n = blockIdx.x * 256 + threadIdx.x;   // 0..511
  float acc = 0.f;
  for (int d = 0; d < 512; d++) acc += know[d] * Wq3[(size_t)n * 512 + d];
  q3[n] = acc + bq3[n];
}

__global__ __launch_bounds__(256) void keyt_kernel(
    const float* __restrict__ know, const float* __restrict__ Wlk,
    const float* __restrict__ blk_, float* __restrict__ keyt)
{
  int idx = blockIdx.x * 256 + threadIdx.x;  // 0..4095
  int h = idx >> 9, n = idx & 511;
  float acc = 0.f;
  for (int i = 0; i < 64; i++) acc += know[h * 64 + i] * Wlk[(size_t)n * 64 + i];
  keyt[idx] = 1.f / (1.f + expf(-(acc + blk_[n])));
}

__global__ __launch_bounds__(256) void scores3_kernel(
    const float* __restrict__ q3, const float* __restrict__ k3,
    float* __restrict__ c3)
{
  int idx = blockIdx.x * 256 + threadIdx.x;  // 0..32767 = (b*H+h)*S + j
  int j  = idx & (S - 1);
  int bh = idx >> 10;
  int h  = bh & 7, b = bh >> 3;
  float acc = 0.f;
  const float* kp = k3 + ((size_t)b * S + j) * D + h * DKH;
  const float* qp = q3 + h * DKH;
  for (int d = 0; d < 64; d++) acc += qp[d] * kp[d];
  c3[idx] = acc * 0.125f;
}

// ---------------- final combine ----------------
__global__ __launch_bounds__(256) void final_kernel(
    const float* __restrict__ q_emb, const float* __restrict__ hfin,
    const float* __restrict__ keyt, const float* __restrict__ Wlv,
    const float* __restrict__ blv, float* __restrict__ out)
{
  const int row = blockIdx.x, t = threadIdx.x;
  __shared__ float hrow[512];
  __shared__ float qrow[512];
  __shared__ float betas[8];
  const size_t base = (size_t)row * D;
  hrow[t] = hfin[base + t];  hrow[t + 256] = hfin[base + t + 256];
  qrow[t] = q_emb[base + t]; qrow[t + 256] = q_emb[base + t + 256];
  __syncthreads();
  {
    const int g = t >> 5, l = t & 31;
    float part = 0.f;
    for (int d = l; d < 512; d += 32) part += keyt[(size_t)g * 512 + d] * qrow[d];
    #pragma unroll
    for (int off = 16; off > 0; off >>= 1) part += __shfl_down(part, off, 32);
    if (l == 0) betas[g] = part;
  }
  __syncthreads();
  float bmax = betas[0];
  #pragma unroll
  for (int hh = 1; hh < 8; hh++) bmax = fmaxf(bmax, betas[hh]);
  float aexp[8]; float asum = 0.f;
  #pragma unroll
  for (int hh = 0; hh < 8; hh++){ aexp[hh] = expf(betas[hh] - bmax); asum += aexp[hh]; }
  const float inva = 1.f / asum;
  #pragma unroll
  for (int p = 0; p < 2; p++){
    const int d = t + p * 256;
    const float* wr = Wlv + (size_t)d * 64;
    float accs[8] = {0.f,0.f,0.f,0.f,0.f,0.f,0.f,0.f};
    #pragma unroll
    for (int i = 0; i < 64; i += 4){
      float4 w = *(const float4*)&wr[i];
      #pragma unroll
      for (int hh = 0; hh < 8; hh++){
        const float* hb = &hrow[hh * 64 + i];
        accs[hh] += w.x*hb[0] + w.y*hb[1] + w.z*hb[2] + w.w*hb[3];
      }
    }
    float o = 0.f; const float bbv = blv[d];
    #pragma unroll
    for (int hh = 0; hh < 8; hh++){
      float vt = 1.f / (1.f + expf(-(accs[hh] + bbv)));
      o += aexp[hh] * inva * vt;
    }
    out[base + d] = o;
  }
}

// ---------------- orchestration ----------------
extern "C" void kernel_launch(void* const* d_in, const int* in_sizes, int n_in,
                              void* d_out, int out_size, void* d_ws, size_t ws_size,
                              hipStream_t stream) {
  const float* q_emb  = (const float*)d_in[0];
  const float* qa_emb = (const float*)d_in[1];
  const float* Wq1 = (const float*)d_in[2],  *bq1 = (const float*)d_in[3];
  const float* Wv1 = (const float*)d_in[4],  *bv1 = (const float*)d_in[5];
  const float* Wo1 = (const float*)d_in[6],  *bo1 = (const float*)d_in[7];
  const float* g1  = (const float*)d_in[8],  *ls1 = (const float*)d_in[9],  *lb1 = (const float*)d_in[10];
  const float* Wq2 = (const float*)d_in[11], *bq2 = (const float*)d_in[12];
  const float* Wv2 = (const float*)d_in[13], *bv2 = (const float*)d_in[14];
  const float* Wo2 = (const float*)d_in[15], *bo2 = (const float*)d_in[16];
  const float* g2  = (const float*)d_in[17], *ls2 = (const float*)d_in[18], *lb2 = (const float*)d_in[19];
  const float* Wq3 = (const float*)d_in[20], *bq3 = (const float*)d_in[21];
  const float* Wk3 = (const float*)d_in[22], *bk3 = (const float*)d_in[23];
  const float* Wv3 = (const float*)d_in[24], *bv3 = (const float*)d_in[25];
  const float* Wo3 = (const float*)d_in[26], *bo3 = (const float*)d_in[27];
  const float* g3  = (const float*)d_in[28], *ls3 = (const float*)d_in[29], *lb3 = (const float*)d_in[30];
  const float* know = (const float*)d_in[31];
  const float* Wlk  = (const float*)d_in[32], *b_lk = (const float*)d_in[33];
  const float* Wlv  = (const float*)d_in[34], *b_lv = (const float*)d_in[35];
  float* outp = (float*)d_out;

  float* ws   = (float*)d_ws;
  float* Smat = ws;                     // H*S*S = 8388608
  float* qk   = Smat + (size_t)H * S * S;
  float* v    = qk   + (size_t)BB * S * D;
  float* ctx  = v    + (size_t)BB * S * D;
  float* hq   = ctx  + (size_t)BB * S * D;
  float* ha   = hq   + (size_t)BB * S * D;
  float* hfin = ha   + (size_t)BB * S * D;
  float* q3   = hfin + (size_t)BB * S * D;
  float* keyt = q3 + 512;
  float* c3   = keyt + 4096;

  const dim3 gG(8, 64);        // GEMM grid: N/64 x M/64
  const dim3 gS(16, 16, 8);    // scores grid
  const dim3 gD(1024, 8);      // decay grid
  const dim3 gA(32, 8);        // AV grid
  const int M = BB * S;

  // ---- block 1 (input q_emb, k==q) ----
  gemm_bias<<<gG, 256, 0, stream>>>(q_emb, Wq1, bq1, qk, M, D, D);
  gemm_bias<<<gG, 256, 0, stream>>>(q_emb, Wv1, bv1, v,  M, D, D);
  for (int b = 0; b < BB; b++){
    scores_qk<<<gS, 256, 0, stream>>>(qk, qk, Smat, b);
    decay_kernel<<<gD, 64, 0, stream>>>(Smat, nullptr, g1, 0, 0, b);
    av_gemm<<<gA, 256, 0, stream>>>(Smat, v, ctx, b);
  }
  gemm_bias<<<gG, 256, 0, stream>>>(ctx, Wo1, bo1, hfin, M, D, D);
  ln_residual<<<M, 256, 0, stream>>>(q_emb, hfin, ls1, lb1, hq, 0);

  // ---- block 2 (input qa_emb, k==q) ----
  gemm_bias<<<gG, 256, 0, stream>>>(qa_emb, Wq2, bq2, qk, M, D, D);
  gemm_bias<<<gG, 256, 0, stream>>>(qa_emb, Wv2, bv2, v,  M, D, D);
  for (int b = 0; b < BB; b++){
    scores_qk<<<gS, 256, 0, stream>>>(qk, qk, Smat, b);
    decay_kernel<<<gD, 64, 0, stream>>>(Smat, nullptr, g2, 0, 0, b);
    av_gemm<<<gA, 256, 0, stream>>>(Smat, v, ctx, b);
  }
  gemm_bias<<<gG, 256, 0, stream>>>(ctx, Wo2, bo2, hfin, M, D, D);
  ln_residual<<<M, 256, 0, stream>>>(qa_emb, hfin, ls2, lb2, ha, 0);

  // ---- block 3 (q = know broadcast, k from hq, v from ha, nopeek, zero_pad) ----
  qvec3_kernel<<<2, 256, 0, stream>>>(know, Wq3, bq3, q3);
  gemm_bias<<<gG, 256, 0, stream>>>(hq, Wk3, bk3, qk, M, D, D);
  gemm_bias<<<gG, 256, 0, stream>>>(ha, Wv3, bv3, v,  M, D, D);
  scores3_kernel<<<128, 256, 0, stream>>>(q3, qk, c3);
  for (int b = 0; b < BB; b++){
    decay_kernel<<<gD, 64, 0, stream>>>(Smat, c3, g3, -1, 1, b);
    av_gemm<<<gA, 256, 0, stream>>>(Smat, v, ctx, b);
  }
  gemm_bias<<<gG, 256, 0, stream>>>(ctx, Wo3, bo3, hq /*tmp*/, M, D, D);
  ln_residual<<<M, 256, 0, stream>>>(know, hq, ls3, lb3, hfin, 1);

  // ---- final combine ----
  keyt_kernel<<<16, 256, 0, stream>>>(know, Wlk, b_lk, keyt);
  final_kernel<<<M, 256, 0, stream>>>(q_emb, hfin, keyt, Wlv, b_lv, outp);
}

// Round 2
// 1027.637 us; speedup vs baseline: 1.5481x; 1.5481x over previous
//
#include <hip/hip_runtime.h>
#include <math.h>

#define BB 4
#define S 1024
#define D 512
#define H 8
#define DKH 64

typedef __attribute__((ext_vector_type(8))) short bf16x8;
typedef __attribute__((ext_vector_type(4))) float f32x4;

__device__ __forceinline__ unsigned short f2bf(float f){
  unsigned int u = __float_as_uint(f);
  u += 0x7FFFu + ((u >> 16) & 1u);
  return (unsigned short)(u >> 16);
}
__device__ __forceinline__ float bf2f(unsigned int v){
  return __uint_as_float(v << 16);
}
__device__ __forceinline__ f32x4 MFMA(bf16x8 a, bf16x8 b, f32x4 c){
  return __builtin_amdgcn_mfma_f32_16x16x32_bf16(a, b, c, 0, 0, 0);
}

// ---------------- block-level reduce helper (256 threads) ----------------
__device__ __forceinline__ float blk_sum(float* r, int t, float v){
  r[t] = v; __syncthreads();
  for (int s = 128; s > 0; s >>= 1){
    if (t < s) r[t] += r[t + s];
    __syncthreads();
  }
  float res = r[0]; __syncthreads();
  return res;
}

// ---------------- generic bf16 MFMA GEMM: C = scale * (A @ W^T) + bias ----------------
// A [M,K] bf16 (lda), W [N,K] bf16 (ldw). 128x128 tile, 256 thr = 4 waves (2x2 of 64x64).
template<int OUTBF, int HASBIAS, int HASSCALE>
__global__ __launch_bounds__(256) void mfma_gemm(
    const unsigned short* __restrict__ A, int lda,
    const unsigned short* __restrict__ W, int ldw,
    const float* __restrict__ bias, float scale,
    void* __restrict__ Cv, int ldc,
    size_t aoffz, size_t woffz, size_t coffz, int K)
{
  __shared__ __align__(16) short As[128][32];
  __shared__ __align__(16) short Ws[128][32];
  const int t = threadIdx.x;
  const int n0 = blockIdx.x * 128, m0 = blockIdx.y * 128;
  A += (size_t)blockIdx.z * aoffz;
  W += (size_t)blockIdx.z * woffz;
  const int w = t >> 6, lane = t & 63;
  const int wm = (w >> 1) << 6, wn = (w & 1) << 6;
  const int lm = lane & 15, q = lane >> 4;
  const int r = t >> 2, cc = (t & 3) << 3;
  f32x4 acc[4][4];
  #pragma unroll
  for (int a_ = 0; a_ < 4; a_++)
    #pragma unroll
    for (int b_ = 0; b_ < 4; b_++)
      acc[a_][b_] = (f32x4){0.f, 0.f, 0.f, 0.f};
  for (int k0 = 0; k0 < K; k0 += 32){
    *(uint4*)&As[r][cc]      = *(const uint4*)&A[(size_t)(m0 + r) * lda + k0 + cc];
    *(uint4*)&As[r + 64][cc] = *(const uint4*)&A[(size_t)(m0 + r + 64) * lda + k0 + cc];
    *(uint4*)&Ws[r][cc]      = *(const uint4*)&W[(size_t)(n0 + r) * ldw + k0 + cc];
    *(uint4*)&Ws[r + 64][cc] = *(const uint4*)&W[(size_t)(n0 + r + 64) * ldw + k0 + cc];
    __syncthreads();
    bf16x8 af[4], bf[4];
    #pragma unroll
    for (int mt = 0; mt < 4; mt++) af[mt] = *(const bf16x8*)&As[wm + mt*16 + lm][q*8];
    #pragma unroll
    for (int nt = 0; nt < 4; nt++) bf[nt] = *(const bf16x8*)&Ws[wn + nt*16 + lm][q*8];
    #pragma unroll
    for (int mt = 0; mt < 4; mt++)
      #pragma unroll
      for (int nt = 0; nt < 4; nt++)
        acc[mt][nt] = MFMA(af[mt], bf[nt], acc[mt][nt]);
    __syncthreads();
  }
  #pragma unroll
  for (int nt = 0; nt < 4; nt++){
    const int n = n0 + wn + nt*16 + lm;
    const float bs = HASBIAS ? bias[n] : 0.f;
    #pragma unroll
    for (int mt = 0; mt < 4; mt++){
      const int mb = m0 + wm + mt*16 + (q << 2);
      f32x4 c = acc[mt][nt];
      #pragma unroll
      for (int rr = 0; rr < 4; rr++){
        float vv = HASSCALE ? (c[rr] * scale) : c[rr];
        vv += bs;
        if (OUTBF)
          ((unsigned short*)Cv)[(size_t)blockIdx.z * coffz + (size_t)(mb + rr) * ldc + n] = f2bf(vv);
        else
          ((float*)Cv)[(size_t)blockIdx.z * coffz + (size_t)(mb + rr) * ldc + n] = vv;
      }
    }
  }
}

// ---------------- AV via MFMA: ctx[i, h*64+d] = sum_j att[h,i,j] * v[j, h*64+d] ----------------
// per b. grid (S/128, H). 4 waves stacked on M (32 rows each), N = 64.
__global__ __launch_bounds__(256) void av_mfma(
    const unsigned short* __restrict__ att,   // [H][S][S] bf16
    const unsigned short* __restrict__ V,     // + b*S*D, [S][D] bf16
    unsigned short* __restrict__ ctx)         // + b*S*D, [S][D] bf16
{
  __shared__ __align__(16) short As[128][32];
  __shared__ __align__(16) unsigned short Vs[32][66];   // pad 66: conflict-free gather
  const int t = threadIdx.x;
  const int i0 = blockIdx.x * 128, h = blockIdx.y;
  const unsigned short* Ab = att + (size_t)h * S * S;
  const unsigned short* Vb = V + h * DKH;
  const int w = t >> 6, lane = t & 63;
  const int lm = lane & 15, q = lane >> 4;
  const int r = t >> 2, cc = (t & 3) << 3;
  const int jj = t >> 3, c8 = (t & 7) << 3;
  f32x4 acc[2][4];
  #pragma unroll
  for (int a_ = 0; a_ < 2; a_++)
    #pragma unroll
    for (int b_ = 0; b_ < 4; b_++)
      acc[a_][b_] = (f32x4){0.f, 0.f, 0.f, 0.f};
  for (int k0 = 0; k0 < S; k0 += 32){
    *(uint4*)&As[r][cc]      = *(const uint4*)&Ab[(size_t)(i0 + r) * S + k0 + cc];
    *(uint4*)&As[r + 64][cc] = *(const uint4*)&Ab[(size_t)(i0 + r + 64) * S + k0 + cc];
    uint4 d4 = *(const uint4*)&Vb[(size_t)(k0 + jj) * D + c8];
    unsigned int* vr = (unsigned int*)&Vs[jj][c8];
    vr[0] = d4.x; vr[1] = d4.y; vr[2] = d4.z; vr[3] = d4.w;
    __syncthreads();
    bf16x8 a0 = *(const bf16x8*)&As[w*32 + lm][q*8];
    bf16x8 a1 = *(const bf16x8*)&As[w*32 + 16 + lm][q*8];
    #pragma unroll
    for (int nt = 0; nt < 4; nt++){
      bf16x8 bv;
      #pragma unroll
      for (int jx = 0; jx < 8; jx++) bv[jx] = (short)Vs[q*8 + jx][nt*16 + lm];
      acc[0][nt] = MFMA(a0, bv, acc[0][nt]);
      acc[1][nt] = MFMA(a1, bv, acc[1][nt]);
    }
    __syncthreads();
  }
  #pragma unroll
  for (int mt = 0; mt < 2; mt++)
    #pragma unroll
    for (int nt = 0; nt < 4; nt++){
      const int irow = i0 + w*32 + mt*16 + (q << 2);
      const int d = nt*16 + lm;
      f32x4 c = acc[mt][nt];
      #pragma unroll
      for (int rr = 0; rr < 4; rr++)
        ctx[(size_t)(irow + rr) * D + h * DKH + d] = f2bf(c[rr]);
    }
}

// ---------------- decay + double softmax, wave-per-row, 4 rows/block ----------------
// grid (S/4, H), block 256. bf16 in-place in smat; block3 reads c3 fp32.
__global__ __launch_bounds__(256) void decay_kernel(
    unsigned short* __restrict__ smat, const float* __restrict__ c3,
    const float* __restrict__ g, int diag, int zero_pad)
{
  const int i = blockIdx.x * 4 + (threadIdx.x >> 6);
  const int h = blockIdx.y;
  const int l = threadIdx.x & 63;
  unsigned short* row = smat + ((size_t)h * S + i) * S;
  if (zero_pad && i == 0){
    uint4 z = make_uint4(0u, 0u, 0u, 0u);
    ((uint4*)row)[l*2] = z; ((uint4*)row)[l*2 + 1] = z;
    return;
  }
  float c[16];
  if (c3){
    const float* src = c3 + (size_t)h * S;
    #pragma unroll
    for (int p4 = 0; p4 < 4; p4++){
      float4 x = ((const float4*)src)[l*4 + p4];
      c[p4*4+0] = x.x; c[p4*4+1] = x.y; c[p4*4+2] = x.z; c[p4*4+3] = x.w;
    }
  } else {
    #pragma unroll
    for (int p4 = 0; p4 < 2; p4++){
      uint4 u = ((const uint4*)row)[l*2 + p4];
      unsigned int uu[4] = {u.x, u.y, u.z, u.w};
      #pragma unroll
      for (int mel = 0; mel < 4; mel++){
        c[p4*8 + mel*2]     = bf2f(uu[mel] & 0xffffu);
        c[p4*8 + mel*2 + 1] = bf2f(uu[mel] >> 16);
      }
    }
  }
  const int j0 = l * 16;
  const int jmax = i + diag;
  float m1 = -3.0e38f;
  #pragma unroll
  for (int qe = 0; qe < 16; qe++) if (j0 + qe <= jmax) m1 = fmaxf(m1, c[qe]);
  #pragma unroll
  for (int off = 1; off < 64; off <<= 1) m1 = fmaxf(m1, __shfl_xor(m1, off, 64));
  float e[16]; float lsum = 0.f;
  #pragma unroll
  for (int qe = 0; qe < 16; qe++){
    float v = (j0 + qe <= jmax) ? expf(c[qe] - m1) : 0.f;
    e[qe] = v; lsum += v;
  }
  float sum1 = lsum;
  #pragma unroll
  for (int off = 1; off < 64; off <<= 1) sum1 += __shfl_xor(sum1, off, 64);
  const float inv1 = (jmax >= 0) ? 1.f / sum1 : 0.f;
  float pl[16]; float run = 0.f;
  #pragma unroll
  for (int qe = 0; qe < 16; qe++){ run += e[qe] * inv1; pl[qe] = run; }
  float scn = run;
  #pragma unroll
  for (int off = 1; off < 64; off <<= 1){
    float u = __shfl_up(scn, off, 64);
    if (l >= off) scn += u;
  }
  const float T = __shfl(scn, 63, 64);
  const float excl = scn - run;
  float gm;
  { float gv = g[h]; gm = -((gv > 20.f) ? gv : log1pf(expf(gv))); }
  float sc[16];
  #pragma unroll
  for (int qe = 0; qe < 16; qe++){
    float rem = T - (excl + pl[qe]); rem = fmaxf(rem, 0.f);
    float pos = fabsf((float)(i - (j0 + qe)));
    float eff = expf(gm * sqrtf(rem * pos));
    eff = fminf(fmaxf(eff, 1e-5f), 1e5f);
    sc[qe] = c[qe] * eff;
  }
  float m2 = sc[0];
  #pragma unroll
  for (int qe = 1; qe < 16; qe++) m2 = fmaxf(m2, sc[qe]);
  #pragma unroll
  for (int off = 1; off < 64; off <<= 1) m2 = fmaxf(m2, __shfl_xor(m2, off, 64));
  float p[16]; float ls2 = 0.f;
  #pragma unroll
  for (int qe = 0; qe < 16; qe++){ p[qe] = expf(sc[qe] - m2); ls2 += p[qe]; }
  #pragma unroll
  for (int off = 1; off < 64; off <<= 1) ls2 += __shfl_xor(ls2, off, 64);
  const float inv2 = 1.f / ls2;
  unsigned int ou[8];
  #pragma unroll
  for (int mel = 0; mel < 8; mel++){
    unsigned int lo = f2bf(p[2*mel] * inv2);
    unsigned int hi = f2bf(p[2*mel + 1] * inv2);
    ou[mel] = lo | (hi << 16);
  }
  ((uint4*)row)[l*2]     = make_uint4(ou[0], ou[1], ou[2], ou[3]);
  ((uint4*)row)[l*2 + 1] = make_uint4(ou[4], ou[5], ou[6], ou[7]);
}

// ---------------- residual + LayerNorm -> bf16 ----------------
__global__ __launch_bounds__(256) void ln_residual(
    const float* __restrict__ resid, const float* __restrict__ y,
    const float* __restrict__ ls, const float* __restrict__ lb,
    unsigned short* __restrict__ out, int bcast)
{
  const int r = blockIdx.x, t = threadIdx.x;
  __shared__ float red[256];
  const size_t base = (size_t)r * D;
  float r0 = bcast ? resid[t]       : resid[base + t];
  float r1 = bcast ? resid[t + 256] : resid[base + t + 256];
  float x0 = r0 + y[base + t];
  float x1 = r1 + y[base + t + 256];
  float mean = blk_sum(red, t, x0 + x1) * (1.0f / 512.0f);
  float d0 = x0 - mean, d1 = x1 - mean;
  float var = blk_sum(red, t, d0*d0 + d1*d1) * (1.0f / 512.0f);
  float inv = rsqrtf(var + 1e-5f);
  out[base + t]       = f2bf(d0 * inv * ls[t]       + lb[t]);
  out[base + t + 256] = f2bf(d1 * inv * ls[t + 256] + lb[t + 256]);
}

// ---------------- fp32 -> bf16 conversion (batched jobs) ----------------
struct CvtJobs {
  const float* s[13];
  unsigned short* d[13];
  int n[13];
};
__global__ __launch_bounds__(256) void cvt_all(CvtJobs jb){
  const int z = blockIdx.y;
  const int n = jb.n[z];
  const float* s = jb.s[z];
  unsigned short* d = jb.d[z];
  for (int idx = blockIdx.x * 256 + threadIdx.x; idx < n; idx += gridDim.x * 256)
    d[idx] = f2bf(s[idx]);
}

// ---------------- small kernels ----------------
__global__ __launch_bounds__(256) void qvec3_kernel(
    const float* __restrict__ know, const float* __restrict__ Wq3,
    const float* __restrict__ bq3, float* __restrict__ q3)
{
  int n = blockIdx.x * 256 + threadIdx.x;
  float acc = 0.f;
  for (int d = 0; d < 512; d++) acc += know[d] * Wq3[(size_t)n * 512 + d];
  q3[n] = acc + bq3[n];
}

__global__ __launch_bounds__(256) void keyt_kernel(
    const float* __restrict__ know, const float* __restrict__ Wlk,
    const float* __restrict__ blk_, float* __restrict__ keyt)
{
  int idx = blockIdx.x * 256 + threadIdx.x;
  int h = idx >> 9, n = idx & 511;
  float acc = 0.f;
  for (int i = 0; i < 64; i++) acc += know[h * 64 + i] * Wlk[(size_t)n * 64 + i];
  keyt[idx] = 1.f / (1.f + expf(-(acc + blk_[n])));
}

__global__ __launch_bounds__(256) void scores3_kernel(
    const float* __restrict__ q3, const unsigned short* __restrict__ k3,
    float* __restrict__ c3)
{
  int idx = blockIdx.x * 256 + threadIdx.x;   // (b*H+h)*S + j
  int j  = idx & (S - 1);
  int bh = idx >> 10;
  int h  = bh & 7, b = bh >> 3;
  const unsigned short* kp = k3 + ((size_t)b * S + j) * D + h * DKH;
  const float* qp = q3 + h * DKH;
  float acc = 0.f;
  #pragma unroll
  for (int d8 = 0; d8 < 64; d8 += 8){
    uint4 u = *(const uint4*)&kp[d8];
    unsigned int uu[4] = {u.x, u.y, u.z, u.w};
    #pragma unroll
    for (int mel = 0; mel < 4; mel++){
      acc += qp[d8 + 2*mel]     * bf2f(uu[mel] & 0xffffu);
      acc += qp[d8 + 2*mel + 1] * bf2f(uu[mel] >> 16);
    }
  }
  c3[idx] = acc * 0.125f;
}

// beta/alpha: wave per (b,s) row, 8 lanes per head
__global__ __launch_bounds__(256) void alphas_kernel(
    const float* __restrict__ keyt, const float* __restrict__ q_emb,
    float* __restrict__ alpha)
{
  const int row = blockIdx.x * 4 + (threadIdx.x >> 6);
  const int l = threadIdx.x & 63;
  const int h = l >> 3, sub = l & 7;
  const float* qr = q_emb + (size_t)row * D;
  const float* kt = keyt + h * D;
  float p = 0.f;
  for (int d = sub; d < D; d += 8) p += kt[d] * qr[d];
  p += __shfl_xor(p, 1, 64);
  p += __shfl_xor(p, 2, 64);
  p += __shfl_xor(p, 4, 64);
  float m = p;
  m = fmaxf(m, __shfl_xor(m, 8, 64));
  m = fmaxf(m, __shfl_xor(m, 16, 64));
  m = fmaxf(m, __shfl_xor(m, 32, 64));
  float e = expf(p - m);
  float ssum = e;
  ssum += __shfl_xor(ssum, 8, 64);
  ssum += __shfl_xor(ssum, 16, 64);
  ssum += __shfl_xor(ssum, 32, 64);
  if (sub == 0) alpha[(size_t)row * H + h] = e / ssum;
}

// ---------------- fused val GEMM + sigmoid + alpha-combine ----------------
// A = hfin bf16 [32768 x 64] (rows = (b,s,h)); W = Wlv bf16 [512 x 64].
// out[s_row, n] = sum over 8 h-rows of alpha[m] * sigmoid(val[m][n] + b_lv[n]).
__global__ __launch_bounds__(256) void val_fused(
    const unsigned short* __restrict__ Ah,
    const unsigned short* __restrict__ Wv,
    const float* __restrict__ blv,
    const float* __restrict__ alpha,
    float* __restrict__ out)
{
  __shared__ __align__(16) short As[128][32];
  __shared__ __align__(16) short Ws[128][32];
  __shared__ float als[128];
  const int t = threadIdx.x;
  const int n0 = blockIdx.x * 128, m0 = blockIdx.y * 128;
  if (t < 128) als[t] = alpha[m0 + t];
  const int w = t >> 6, lane = t & 63;
  const int wm = (w >> 1) << 6, wn = (w & 1) << 6;
  const int lm = lane & 15, q = lane >> 4;
  const int r = t >> 2, cc = (t & 3) << 3;
  f32x4 acc[4][4];
  #pragma unroll
  for (int a_ = 0; a_ < 4; a_++)
    #pragma unroll
    for (int b_ = 0; b_ < 4; b_++)
      acc[a_][b_] = (f32x4){0.f, 0.f, 0.f, 0.f};
  for (int k0 = 0; k0 < 64; k0 += 32){
    *(uint4*)&As[r][cc]      = *(const uint4*)&Ah[(size_t)(m0 + r) * 64 + k0 + cc];
    *(uint4*)&As[r + 64][cc] = *(const uint4*)&Ah[(size_t)(m0 + r + 64) * 64 + k0 + cc];
    *(uint4*)&Ws[r][cc]      = *(const uint4*)&Wv[(size_t)(n0 + r) * 64 + k0 + cc];
    *(uint4*)&Ws[r + 64][cc] = *(const uint4*)&Wv[(size_t)(n0 + r + 64) * 64 + k0 + cc];
    __syncthreads();
    bf16x8 af[4], bf[4];
    #pragma unroll
    for (int mt = 0; mt < 4; mt++) af[mt] = *(const bf16x8*)&As[wm + mt*16 + lm][q*8];
    #pragma unroll
    for (int nt = 0; nt < 4; nt++) bf[nt] = *(const bf16x8*)&Ws[wn + nt*16 + lm][q*8];
    #pragma unroll
    for (int mt = 0; mt < 4; mt++)
      #pragma unroll
      for (int nt = 0; nt < 4; nt++)
        acc[mt][nt] = MFMA(af[mt], bf[nt], acc[mt][nt]);
    __syncthreads();
  }
  #pragma unroll
  for (int nt = 0; nt < 4; nt++){
    const int n = n0 + wn + nt*16 + lm;
    const float bs = blv[n];
    #pragma unroll
    for (int mt = 0; mt < 4; mt++){
      const int mb = m0 + wm + mt*16;       // multiple of 16
      f32x4 c = acc[mt][nt];
      float part = 0.f;
      #pragma unroll
      for (int rr = 0; rr < 4; rr++){
        const int ml = (mb - m0) + (q << 2) + rr;   // local row in [0,128)
        float sg = 1.f / (1.f + expf(-(c[rr] + bs)));
        part += als[ml] * sg;
      }
      part += __shfl_xor(part, 16, 64);
      if ((q & 1) == 0){
        const int srow = (mb >> 3) + (q >> 1);
        out[(size_t)srow * D + n] = part;
      }
    }
  }
}

// ---------------- orchestration ----------------
extern "C" void kernel_launch(void* const* d_in, const int* in_sizes, int n_in,
                              void* d_out, int out_size, void* d_ws, size_t ws_size,
                              hipStream_t stream) {
  const float* q_emb  = (const float*)d_in[0];
  const float* qa_emb = (const float*)d_in[1];
  const float* Wq1 = (const float*)d_in[2],  *bq1 = (const float*)d_in[3];
  const float* Wv1 = (const float*)d_in[4],  *bv1 = (const float*)d_in[5];
  const float* Wo1 = (const float*)d_in[6],  *bo1 = (const float*)d_in[7];
  const float* g1  = (const float*)d_in[8],  *ls1 = (const float*)d_in[9],  *lb1 = (const float*)d_in[10];
  const float* Wq2 = (const float*)d_in[11], *bq2 = (const float*)d_in[12];
  const float* Wv2 = (const float*)d_in[13], *bv2 = (const float*)d_in[14];
  const float* Wo2 = (const float*)d_in[15], *bo2 = (const float*)d_in[16];
  const float* g2  = (const float*)d_in[17], *ls2 = (const float*)d_in[18], *lb2 = (const float*)d_in[19];
  const float* Wq3 = (const float*)d_in[20], *bq3 = (const float*)d_in[21];
  const float* Wk3 = (const float*)d_in[22], *bk3 = (const float*)d_in[23];
  const float* Wv3 = (const float*)d_in[24], *bv3 = (const float*)d_in[25];
  const float* Wo3 = (const float*)d_in[26], *bo3 = (const float*)d_in[27];
  const float* g3  = (const float*)d_in[28], *ls3 = (const float*)d_in[29], *lb3 = (const float*)d_in[30];
  const float* know = (const float*)d_in[31];
  const float* Wlk  = (const float*)d_in[32], *b_lk = (const float*)d_in[33];
  const float* Wlv  = (const float*)d_in[34], *b_lv = (const float*)d_in[35];
  float* outp = (float*)d_out;

  const size_t NSD = (size_t)BB * S * D;     // 2,097,152
  unsigned short* smat16 = (unsigned short*)d_ws;          // H*S*S
  unsigned short* qkb  = smat16 + (size_t)H * S * S;
  unsigned short* vb   = qkb  + NSD;
  unsigned short* ctxb = vb   + NSD;
  unsigned short* xqb  = ctxb + NSD;
  unsigned short* xab  = xqb  + NSD;
  unsigned short* hqb  = xab  + NSD;
  unsigned short* hab  = hqb  + NSD;
  unsigned short* hfb  = hab  + NSD;
  unsigned short* wb   = hfb  + NSD;          // 10 x D*D
  unsigned short* wlvb = wb + (size_t)10 * D * D;
  float* yv    = (float*)(wlvb + (size_t)D * DKH);
  float* q3    = yv + (size_t)BB * S * D;
  float* keyt  = q3 + 512;
  float* c3    = keyt + 4096;
  float* alpha = c3 + (size_t)BB * H * S;

  unsigned short* Wq1b = wb + 0*(size_t)D*D;
  unsigned short* Wv1b = wb + 1*(size_t)D*D;
  unsigned short* Wo1b = wb + 2*(size_t)D*D;
  unsigned short* Wq2b = wb + 3*(size_t)D*D;
  unsigned short* Wv2b = wb + 4*(size_t)D*D;
  unsigned short* Wo2b = wb + 5*(size_t)D*D;
  unsigned short* Wk3b = wb + 6*(size_t)D*D;
  unsigned short* Wv3b = wb + 7*(size_t)D*D;
  unsigned short* Wo3b = wb + 8*(size_t)D*D;
  unsigned short* Wq3b = wb + 9*(size_t)D*D;  // unused (q3 fp32) but converted harmlessly? skip

  // conversions (13 jobs)
  CvtJobs jb;
  jb.s[0] = q_emb;  jb.d[0] = xqb;  jb.n[0] = (int)NSD;
  jb.s[1] = qa_emb; jb.d[1] = xab;  jb.n[1] = (int)NSD;
  jb.s[2] = Wq1; jb.d[2] = Wq1b; jb.n[2] = D*D;
  jb.s[3] = Wv1; jb.d[3] = Wv1b; jb.n[3] = D*D;
  jb.s[4] = Wo1; jb.d[4] = Wo1b; jb.n[4] = D*D;
  jb.s[5] = Wq2; jb.d[5] = Wq2b; jb.n[5] = D*D;
  jb.s[6] = Wv2; jb.d[6] = Wv2b; jb.n[6] = D*D;
  jb.s[7] = Wo2; jb.d[7] = Wo2b; jb.n[7] = D*D;
  jb.s[8] = Wk3; jb.d[8] = Wk3b; jb.n[8] = D*D;
  jb.s[9] = Wv3; jb.d[9] = Wv3b; jb.n[9] = D*D;
  jb.s[10] = Wo3; jb.d[10] = Wo3b; jb.n[10] = D*D;
  jb.s[11] = Wlv; jb.d[11] = wlvb; jb.n[11] = D*DKH;
  jb.s[12] = Wq3; jb.d[12] = Wq3b; jb.n[12] = D*D;   // keep slot count fixed
  cvt_all<<<dim3(256, 13), 256, 0, stream>>>(jb);

  const dim3 gP(4, 32);        // projection gemm: N=512, M=4096
  const dim3 gS(8, 8, 8);      // scores gemm: N=1024, M=1024, z=h
  const dim3 gD(256, 8);       // decay
  const dim3 gA(8, 8);         // av
  const int M = BB * S;

  // ---- block 1 (input q_emb, k==q) ----
  mfma_gemm<1,1,0><<<gP, 256, 0, stream>>>(xqb, D, Wq1b, D, bq1, 1.f, qkb, D, 0,0,0, D);
  mfma_gemm<1,1,0><<<gP, 256, 0, stream>>>(xqb, D, Wv1b, D, bv1, 1.f, vb,  D, 0,0,0, D);
  for (int b = 0; b < BB; b++){
    const unsigned short* qb_ = qkb + (size_t)b * S * D;
    mfma_gemm<1,0,1><<<gS, 256, 0, stream>>>(qb_, D, qb_, D, nullptr, 0.125f,
                                             smat16, S, DKH, DKH, (size_t)S*S, DKH);
    decay_kernel<<<gD, 256, 0, stream>>>(smat16, nullptr, g1, 0, 0);
    av_mfma<<<gA, 256, 0, stream>>>(smat16, vb + (size_t)b*S*D, ctxb + (size_t)b*S*D);
  }
  mfma_gemm<0,1,0><<<gP, 256, 0, stream>>>(ctxb, D, Wo1b, D, bo1, 1.f, yv, D, 0,0,0, D);
  ln_residual<<<M, 256, 0, stream>>>(q_emb, yv, ls1, lb1, hqb, 0);

  // ---- block 2 (input qa_emb, k==q) ----
  mfma_gemm<1,1,0><<<gP, 256, 0, stream>>>(xab, D, Wq2b, D, bq2, 1.f, qkb, D, 0,0,0, D);
  mfma_gemm<1,1,0><<<gP, 256, 0, stream>>>(xab, D, Wv2b, D, bv2, 1.f, vb,  D, 0,0,0, D);
  for (int b = 0; b < BB; b++){
    const unsigned short* qb_ = qkb + (size_t)b * S * D;
    mfma_gemm<1,0,1><<<gS, 256, 0, stream>>>(qb_, D, qb_, D, nullptr, 0.125f,
                                             smat16, S, DKH, DKH, (size_t)S*S, DKH);
    decay_kernel<<<gD, 256, 0, stream>>>(smat16, nullptr, g2, 0, 0);
    av_mfma<<<gA, 256, 0, stream>>>(smat16, vb + (size_t)b*S*D, ctxb + (size_t)b*S*D);
  }
  mfma_gemm<0,1,0><<<gP, 256, 0, stream>>>(ctxb, D, Wo2b, D, bo2, 1.f, yv, D, 0,0,0, D);
  ln_residual<<<M, 256, 0, stream>>>(qa_emb, yv, ls2, lb2, hab, 0);

  // ---- block 3 (q = know broadcast, k from hq, v from ha, nopeek, zero_pad) ----
  qvec3_kernel<<<2, 256, 0, stream>>>(know, Wq3, bq3, q3);
  mfma_gemm<1,1,0><<<gP, 256, 0, stream>>>(hqb, D, Wk3b, D, bk3, 1.f, qkb, D, 0,0,0, D);
  mfma_gemm<1,1,0><<<gP, 256, 0, stream>>>(hab, D, Wv3b, D, bv3, 1.f, vb,  D, 0,0,0, D);
  scores3_kernel<<<128, 256, 0, stream>>>(q3, qkb, c3);
  for (int b = 0; b < BB; b++){
    decay_kernel<<<gD, 256, 0, stream>>>(smat16, c3 + (size_t)b*H*S, g3, -1, 1);
    av_mfma<<<gA, 256, 0, stream>>>(smat16, vb + (size_t)b*S*D, ctxb + (size_t)b*S*D);
  }
  mfma_gemm<0,1,0><<<gP, 256, 0, stream>>>(ctxb, D, Wo3b, D, bo3, 1.f, yv, D, 0,0,0, D);
  ln_residual<<<M, 256, 0, stream>>>(know, yv, ls3, lb3, hfb, 1);

  // ---- final combine ----
  keyt_kernel<<<16, 256, 0, stream>>>(know, Wlk, b_lk, keyt);
  alphas_kernel<<<1024, 256, 0, stream>>>(keyt, q_emb, alpha);
  val_fused<<<dim3(4, 256), 256, 0, stream>>>(hfb, wlvb, b_lv, alpha, outp);
}

// Round 3
// 622.217 us; speedup vs baseline: 2.5568x; 1.6516x over previous
//
#include <hip/hip_runtime.h>
#include <math.h>

#define BB 4
#define S 1024
#define D 512
#define H 8
#define DKH 64

#define ATT_LD 1032   // att row stride (shorts)
#define QS_LD  72
#define KS_LD  66

typedef __attribute__((ext_vector_type(8))) short bf16x8;
typedef __attribute__((ext_vector_type(4))) float f32x4;

__device__ __forceinline__ unsigned short f2bf(float f){
  unsigned int u = __float_as_uint(f);
  u += 0x7FFFu + ((u >> 16) & 1u);
  return (unsigned short)(u >> 16);
}
__device__ __forceinline__ float bf2f(unsigned int v){
  return __uint_as_float(v << 16);
}
__device__ __forceinline__ f32x4 MFMA(bf16x8 a, bf16x8 b, f32x4 c){
  return __builtin_amdgcn_mfma_f32_16x16x32_bf16(a, b, c, 0, 0, 0);
}

__device__ __forceinline__ float blk_sum(float* r, int t, float v){
  r[t] = v; __syncthreads();
  for (int s = 128; s > 0; s >>= 1){
    if (t < s) r[t] += r[t + s];
    __syncthreads();
  }
  float res = r[0]; __syncthreads();
  return res;
}

// ================= batched projection GEMM (M=4096,N=512,K=512) =================
// C = A @ W^T + bias ; 128x128 tile, 4 waves 2x2. grid (4, 32, nz)
struct GemmJobs {
  const unsigned short* A[4];
  const unsigned short* W[4];
  const float* bias[4];
  void* C[4];
};
template<int OUTBF>
__global__ __launch_bounds__(256) void mfma_gemm_b(GemmJobs jb)
{
  __shared__ __align__(16) short As[128][32];
  __shared__ __align__(16) short Ws[128][32];
  const int t = threadIdx.x;
  const int z = blockIdx.z;
  const int n0 = blockIdx.x * 128, m0 = blockIdx.y * 128;
  const unsigned short* A = jb.A[z];
  const unsigned short* W = jb.W[z];
  const float* bias = jb.bias[z];
  const int w = t >> 6, lane = t & 63;
  const int wm = (w >> 1) << 6, wn = (w & 1) << 6;
  const int lm = lane & 15, q = lane >> 4;
  const int r = t >> 2, cc = (t & 3) << 3;
  f32x4 acc[4][4];
  #pragma unroll
  for (int a_ = 0; a_ < 4; a_++)
    #pragma unroll
    for (int b_ = 0; b_ < 4; b_++)
      acc[a_][b_] = (f32x4){0.f, 0.f, 0.f, 0.f};
  for (int k0 = 0; k0 < D; k0 += 32){
    *(uint4*)&As[r][cc]      = *(const uint4*)&A[(size_t)(m0 + r) * D + k0 + cc];
    *(uint4*)&As[r + 64][cc] = *(const uint4*)&A[(size_t)(m0 + r + 64) * D + k0 + cc];
    *(uint4*)&Ws[r][cc]      = *(const uint4*)&W[(size_t)(n0 + r) * D + k0 + cc];
    *(uint4*)&Ws[r + 64][cc] = *(const uint4*)&W[(size_t)(n0 + r + 64) * D + k0 + cc];
    __syncthreads();
    bf16x8 af[4], bf[4];
    #pragma unroll
    for (int mt = 0; mt < 4; mt++) af[mt] = *(const bf16x8*)&As[wm + mt*16 + lm][q*8];
    #pragma unroll
    for (int nt = 0; nt < 4; nt++) bf[nt] = *(const bf16x8*)&Ws[wn + nt*16 + lm][q*8];
    #pragma unroll
    for (int mt = 0; mt < 4; mt++)
      #pragma unroll
      for (int nt = 0; nt < 4; nt++)
        acc[mt][nt] = MFMA(af[mt], bf[nt], acc[mt][nt]);
    __syncthreads();
  }
  #pragma unroll
  for (int nt = 0; nt < 4; nt++){
    const int n = n0 + wn + nt*16 + lm;
    const float bs = bias[n];
    #pragma unroll
    for (int mt = 0; mt < 4; mt++){
      const int mb = m0 + wm + mt*16 + (q << 2);
      f32x4 c = acc[mt][nt];
      #pragma unroll
      for (int rr = 0; rr < 4; rr++){
        float vv = c[rr] + bs;
        if (OUTBF)
          ((unsigned short*)jb.C[z])[(size_t)(mb + rr) * D + n] = f2bf(vv);
        else
          ((float*)jb.C[z])[(size_t)(mb + rr) * D + n] = vv;
      }
    }
  }
}

// ================= V transpose: VT[bh][64][S] from V[b][S][D] =================
struct VTArgs { const unsigned short* v[2]; unsigned short* vt[2]; };
__global__ __launch_bounds__(256) void vt_kernel(VTArgs a)
{
  __shared__ unsigned short tile[64 * KS_LD];
  const int z = blockIdx.z, bh = blockIdx.y, b = bh >> 3, h = bh & 7;
  const int j0 = blockIdx.x * 64;
  const int t = threadIdx.x;
  const unsigned short* vp = a.v[z];
  unsigned short* vtp = a.vt[z] + (size_t)bh * 64 * S;
  #pragma unroll
  for (int p = 0; p < 2; p++){
    int lin = t + p * 256, row = lin >> 3, c8 = (lin & 7) << 3;
    *(uint4*)&tile[row * KS_LD + c8] =
      *(const uint4*)&vp[((size_t)b * S + j0 + row) * D + h * DKH + c8];
  }
  __syncthreads();
  #pragma unroll
  for (int p = 0; p < 2; p++){
    int lin = t + p * 256, d = lin >> 3, c8 = (lin & 7) << 3;
    unsigned short tmp[8];
    #pragma unroll
    for (int jx = 0; jx < 8; jx++) tmp[jx] = tile[(c8 + jx) * KS_LD + d];
    *(uint4*)&vtp[(size_t)d * S + j0 + c8] = *(const uint4*)tmp;
  }
}

// ================= fused attention: scores -> decay -> AV, Smat in LDS =================
// grid (S/32, B*H, nz). block 256 = 4 waves. i-block = 32 rows.
struct FAArgs {
  const unsigned short* qk[2];   // q==k source (bf16, [b][S][D])
  const unsigned short* vt[2];   // VT (bf16, [bh][64][S])
  unsigned short* ctx[2];        // out (bf16, [b][S][D])
  const float* g[2];
  const float* c3;               // fp32 [b][h][S] (C3 mode)
  int diag, zero_pad;
};
template<int C3>
__global__ __launch_bounds__(256) void fused_attn(FAArgs a)
{
  __shared__ __align__(16) unsigned short att[32 * ATT_LD];   // 66,048 B
  __shared__ __align__(16) unsigned short Qs[32 * QS_LD];     //  4,608 B
  __shared__ __align__(16) unsigned short Ks[64 * KS_LD];     //  8,448 B
  const int t = threadIdx.x;
  const int z = blockIdx.z;
  const int bh = blockIdx.y, b = bh >> 3, h = bh & 7;
  const int i0 = blockIdx.x * 32;
  const int w = t >> 6, lane = t & 63, lm = lane & 15, q = lane >> 4;
  const unsigned short* qkp = a.qk[z];
  const unsigned short* vtp = a.vt[z] + (size_t)bh * 64 * S;
  unsigned short* ctxp = a.ctx[z];
  float gm;
  { float gv = a.g[z][h]; gm = -((gv > 20.f) ? gv : log1pf(expf(gv))); }

  // ---------- phase 1: scores tile [32 x 1024] -> att (bf16) ----------
  if (!C3){
    {
      int row = t >> 3, c8 = (t & 7) << 3;
      *(uint4*)&Qs[row * QS_LD + c8] =
        *(const uint4*)&qkp[((size_t)b * S + i0 + row) * D + h * DKH + c8];
    }
    __syncthreads();
    bf16x8 af[2][2];
    #pragma unroll
    for (int mt = 0; mt < 2; mt++)
      #pragma unroll
      for (int kft = 0; kft < 2; kft++)
        af[mt][kft] = *(const bf16x8*)&Qs[(mt*16 + lm) * QS_LD + kft*32 + q*8];
    for (int jc = 0; jc < S; jc += 64){
      #pragma unroll
      for (int p = 0; p < 2; p++){
        int lin = t + p * 256, row = lin >> 3, c8 = (lin & 7) << 3;
        *(uint4*)&Ks[row * KS_LD + c8] =
          *(const uint4*)&qkp[((size_t)b * S + jc + row) * D + h * DKH + c8];
      }
      __syncthreads();
      bf16x8 bv0 = *(const bf16x8*)&Ks[(w*16 + lm) * KS_LD + q*8];
      bf16x8 bv1 = *(const bf16x8*)&Ks[(w*16 + lm) * KS_LD + 32 + q*8];
      #pragma unroll
      for (int mt = 0; mt < 2; mt++){
        f32x4 acc = (f32x4){0.f, 0.f, 0.f, 0.f};
        acc = MFMA(af[mt][0], bv0, acc);
        acc = MFMA(af[mt][1], bv1, acc);
        #pragma unroll
        for (int rr = 0; rr < 4; rr++)
          att[(mt*16 + q*4 + rr) * ATT_LD + jc + w*16 + lm] = f2bf(acc[rr] * 0.125f);
      }
      __syncthreads();
    }
  }

  // ---------- phase 2: decay + double softmax, wave-per-row ----------
  for (int rloc = 0; rloc < 8; rloc++){
    const int i = i0 + w*8 + rloc;
    unsigned short* rowp = &att[(w*8 + rloc) * ATT_LD];
    if (C3 && a.zero_pad && i == 0){
      uint4 zz = make_uint4(0u,0u,0u,0u);
      *(uint4*)&rowp[lane*16]     = zz;
      *(uint4*)&rowp[lane*16 + 8] = zz;
      continue;
    }
    float c[16];
    if (C3){
      const float* c3p = a.c3 + ((size_t)b * H + h) * S;
      #pragma unroll
      for (int p4 = 0; p4 < 4; p4++){
        float4 x = *(const float4*)&c3p[lane*16 + p4*4];
        c[p4*4+0] = x.x; c[p4*4+1] = x.y; c[p4*4+2] = x.z; c[p4*4+3] = x.w;
      }
    } else {
      #pragma unroll
      for (int p4 = 0; p4 < 2; p4++){
        uint4 u = *(const uint4*)&rowp[lane*16 + p4*8];
        unsigned int uu[4] = {u.x, u.y, u.z, u.w};
        #pragma unroll
        for (int mel = 0; mel < 4; mel++){
          c[p4*8 + mel*2]     = bf2f(uu[mel] & 0xffffu);
          c[p4*8 + mel*2 + 1] = bf2f(uu[mel] >> 16);
        }
      }
    }
    const int j0 = lane * 16;
    const int jmax = i + a.diag;
    float m1 = -3.0e38f;
    #pragma unroll
    for (int qe = 0; qe < 16; qe++) if (j0 + qe <= jmax) m1 = fmaxf(m1, c[qe]);
    #pragma unroll
    for (int off = 1; off < 64; off <<= 1) m1 = fmaxf(m1, __shfl_xor(m1, off, 64));
    float e[16]; float lsum = 0.f;
    #pragma unroll
    for (int qe = 0; qe < 16; qe++){
      float v = (j0 + qe <= jmax) ? expf(c[qe] - m1) : 0.f;
      e[qe] = v; lsum += v;
    }
    float sum1 = lsum;
    #pragma unroll
    for (int off = 1; off < 64; off <<= 1) sum1 += __shfl_xor(sum1, off, 64);
    const float inv1 = (jmax >= 0) ? 1.f / sum1 : 0.f;
    float pl[16]; float run = 0.f;
    #pragma unroll
    for (int qe = 0; qe < 16; qe++){ run += e[qe] * inv1; pl[qe] = run; }
    float scn = run;
    #pragma unroll
    for (int off = 1; off < 64; off <<= 1){
      float u = __shfl_up(scn, off, 64);
      if (lane >= off) scn += u;
    }
    const float T = __shfl(scn, 63, 64);
    const float excl = scn - run;
    float sc[16];
    #pragma unroll
    for (int qe = 0; qe < 16; qe++){
      float rem = T - (excl + pl[qe]); rem = fmaxf(rem, 0.f);
      float pos = fabsf((float)(i - (j0 + qe)));
      float eff = expf(gm * sqrtf(rem * pos));
      eff = fminf(fmaxf(eff, 1e-5f), 1e5f);
      sc[qe] = c[qe] * eff;
    }
    float m2 = sc[0];
    #pragma unroll
    for (int qe = 1; qe < 16; qe++) m2 = fmaxf(m2, sc[qe]);
    #pragma unroll
    for (int off = 1; off < 64; off <<= 1) m2 = fmaxf(m2, __shfl_xor(m2, off, 64));
    float p[16]; float ls2 = 0.f;
    #pragma unroll
    for (int qe = 0; qe < 16; qe++){ p[qe] = expf(sc[qe] - m2); ls2 += p[qe]; }
    #pragma unroll
    for (int off = 1; off < 64; off <<= 1) ls2 += __shfl_xor(ls2, off, 64);
    const float inv2 = 1.f / ls2;
    unsigned int ou[8];
    #pragma unroll
    for (int mel = 0; mel < 8; mel++){
      unsigned int lo = f2bf(p[2*mel] * inv2);
      unsigned int hi = f2bf(p[2*mel + 1] * inv2);
      ou[mel] = lo | (hi << 16);
    }
    *(uint4*)&rowp[lane*16]     = make_uint4(ou[0], ou[1], ou[2], ou[3]);
    *(uint4*)&rowp[lane*16 + 8] = make_uint4(ou[4], ou[5], ou[6], ou[7]);
  }
  __syncthreads();

  // ---------- phase 3: ctx = att @ V via VT ----------
  const int mloc = w & 1, nh = w >> 1;
  f32x4 acc0 = (f32x4){0.f,0.f,0.f,0.f};
  f32x4 acc1 = (f32x4){0.f,0.f,0.f,0.f};
  for (int kc = 0; kc < S; kc += 64){
    #pragma unroll
    for (int p = 0; p < 2; p++){
      int lin = t + p * 256, row = lin >> 3, c8 = (lin & 7) << 3;
      *(uint4*)&Ks[row * KS_LD + c8] = *(const uint4*)&vtp[(size_t)row * S + kc + c8];
    }
    __syncthreads();
    #pragma unroll
    for (int kft = 0; kft < 2; kft++){
      bf16x8 afv = *(const bf16x8*)&att[(mloc*16 + lm) * ATT_LD + kc + kft*32 + q*8];
      bf16x8 b0 = *(const bf16x8*)&Ks[((nh*2 + 0)*16 + lm) * KS_LD + kft*32 + q*8];
      bf16x8 b1 = *(const bf16x8*)&Ks[((nh*2 + 1)*16 + lm) * KS_LD + kft*32 + q*8];
      acc0 = MFMA(afv, b0, acc0);
      acc1 = MFMA(afv, b1, acc1);
    }
    __syncthreads();
  }
  #pragma unroll
  for (int nt2 = 0; nt2 < 2; nt2++){
    f32x4 acc = nt2 ? acc1 : acc0;
    const int d = (nh*2 + nt2)*16 + lm;
    #pragma unroll
    for (int rr = 0; rr < 4; rr++){
      const int row = i0 + mloc*16 + q*4 + rr;
      ctxp[((size_t)b * S + row) * D + h * DKH + d] = f2bf(acc[rr]);
    }
  }
}

// ================= residual + LayerNorm -> bf16 =================
__global__ __launch_bounds__(256) void ln_residual(
    const float* __restrict__ resid, const float* __restrict__ y,
    const float* __restrict__ ls, const float* __restrict__ lb,
    unsigned short* __restrict__ out, int bcast)
{
  const int r = blockIdx.x, t = threadIdx.x;
  __shared__ float red[256];
  const size_t base = (size_t)r * D;
  float r0 = bcast ? resid[t]       : resid[base + t];
  float r1 = bcast ? resid[t + 256] : resid[base + t + 256];
  float x0 = r0 + y[base + t];
  float x1 = r1 + y[base + t + 256];
  float mean = blk_sum(red, t, x0 + x1) * (1.0f / 512.0f);
  float d0 = x0 - mean, d1 = x1 - mean;
  float var = blk_sum(red, t, d0*d0 + d1*d1) * (1.0f / 512.0f);
  float inv = rsqrtf(var + 1e-5f);
  out[base + t]       = f2bf(d0 * inv * ls[t]       + lb[t]);
  out[base + t + 256] = f2bf(d1 * inv * ls[t + 256] + lb[t + 256]);
}

// ================= fp32 -> bf16 conversions =================
struct CvtJobs {
  const float* s[12];
  unsigned short* d[12];
  int n[12];
};
__global__ __launch_bounds__(256) void cvt_all(CvtJobs jb){
  const int z = blockIdx.y;
  const int n = jb.n[z];
  const float* s = jb.s[z];
  unsigned short* d = jb.d[z];
  for (int idx = blockIdx.x * 256 + threadIdx.x; idx < n; idx += gridDim.x * 256)
    d[idx] = f2bf(s[idx]);
}

// ================= small kernels =================
__global__ __launch_bounds__(256) void qvec3_kernel(
    const float* __restrict__ know, const float* __restrict__ Wq3,
    const float* __restrict__ bq3, float* __restrict__ q3)
{
  int n = blockIdx.x * 256 + threadIdx.x;
  float acc = 0.f;
  for (int d = 0; d < 512; d++) acc += know[d] * Wq3[(size_t)n * 512 + d];
  q3[n] = acc + bq3[n];
}

__global__ __launch_bounds__(256) void keyt_kernel(
    const float* __restrict__ know, const float* __restrict__ Wlk,
    const float* __restrict__ blk_, float* __restrict__ keyt)
{
  int idx = blockIdx.x * 256 + threadIdx.x;
  int h = idx >> 9, n = idx & 511;
  float acc = 0.f;
  for (int i = 0; i < 64; i++) acc += know[h * 64 + i] * Wlk[(size_t)n * 64 + i];
  keyt[idx] = 1.f / (1.f + expf(-(acc + blk_[n])));
}

__global__ __launch_bounds__(256) void scores3_kernel(
    const float* __restrict__ q3, const unsigned short* __restrict__ k3,
    float* __restrict__ c3)
{
  int idx = blockIdx.x * 256 + threadIdx.x;   // (b*H+h)*S + j
  int j  = idx & (S - 1);
  int bh = idx >> 10;
  int h  = bh & 7, b = bh >> 3;
  const unsigned short* kp = k3 + ((size_t)b * S + j) * D + h * DKH;
  const float* qp = q3 + h * DKH;
  float acc = 0.f;
  #pragma unroll
  for (int d8 = 0; d8 < 64; d8 += 8){
    uint4 u = *(const uint4*)&kp[d8];
    unsigned int uu[4] = {u.x, u.y, u.z, u.w};
    #pragma unroll
    for (int mel = 0; mel < 4; mel++){
      acc += qp[d8 + 2*mel]     * bf2f(uu[mel] & 0xffffu);
      acc += qp[d8 + 2*mel + 1] * bf2f(uu[mel] >> 16);
    }
  }
  c3[idx] = acc * 0.125f;
}

__global__ __launch_bounds__(256) void alphas_kernel(
    const float* __restrict__ keyt, const float* __restrict__ q_emb,
    float* __restrict__ alpha)
{
  const int row = blockIdx.x * 4 + (threadIdx.x >> 6);
  const int l = threadIdx.x & 63;
  const int h = l >> 3, sub = l & 7;
  const float* qr = q_emb + (size_t)row * D;
  const float* kt = keyt + h * D;
  float p = 0.f;
  for (int d = sub; d < D; d += 8) p += kt[d] * qr[d];
  p += __shfl_xor(p, 1, 64);
  p += __shfl_xor(p, 2, 64);
  p += __shfl_xor(p, 4, 64);
  float m = p;
  m = fmaxf(m, __shfl_xor(m, 8, 64));
  m = fmaxf(m, __shfl_xor(m, 16, 64));
  m = fmaxf(m, __shfl_xor(m, 32, 64));
  float e = expf(p - m);
  float ssum = e;
  ssum += __shfl_xor(ssum, 8, 64);
  ssum += __shfl_xor(ssum, 16, 64);
  ssum += __shfl_xor(ssum, 32, 64);
  if (sub == 0) alpha[(size_t)row * H + h] = e / ssum;
}

// ================= fused val GEMM + sigmoid + alpha-combine =================
__global__ __launch_bounds__(256) void val_fused(
    const unsigned short* __restrict__ Ah,
    const unsigned short* __restrict__ Wv,
    const float* __restrict__ blv,
    const float* __restrict__ alpha,
    float* __restrict__ out)
{
  __shared__ __align__(16) short As[128][32];
  __shared__ __align__(16) short Ws[128][32];
  __shared__ float als[128];
  const int t = threadIdx.x;
  const int n0 = blockIdx.x * 128, m0 = blockIdx.y * 128;
  if (t < 128) als[t] = alpha[m0 + t];
  const int w = t >> 6, lane = t & 63;
  const int wm = (w >> 1) << 6, wn = (w & 1) << 6;
  const int lm = lane & 15, q = lane >> 4;
  const int r = t >> 2, cc = (t & 3) << 3;
  f32x4 acc[4][4];
  #pragma unroll
  for (int a_ = 0; a_ < 4; a_++)
    #pragma unroll
    for (int b_ = 0; b_ < 4; b_++)
      acc[a_][b_] = (f32x4){0.f, 0.f, 0.f, 0.f};
  for (int k0 = 0; k0 < 64; k0 += 32){
    *(uint4*)&As[r][cc]      = *(const uint4*)&Ah[(size_t)(m0 + r) * 64 + k0 + cc];
    *(uint4*)&As[r + 64][cc] = *(const uint4*)&Ah[(size_t)(m0 + r + 64) * 64 + k0 + cc];
    *(uint4*)&Ws[r][cc]      = *(const uint4*)&Wv[(size_t)(n0 + r) * 64 + k0 + cc];
    *(uint4*)&Ws[r + 64][cc] = *(const uint4*)&Wv[(size_t)(n0 + r + 64) * 64 + k0 + cc];
    __syncthreads();
    bf16x8 af[4], bf[4];
    #pragma unroll
    for (int mt = 0; mt < 4; mt++) af[mt] = *(const bf16x8*)&As[wm + mt*16 + lm][q*8];
    #pragma unroll
    for (int nt = 0; nt < 4; nt++) bf[nt] = *(const bf16x8*)&Ws[wn + nt*16 + lm][q*8];
    #pragma unroll
    for (int mt = 0; mt < 4; mt++)
      #pragma unroll
      for (int nt = 0; nt < 4; nt++)
        acc[mt][nt] = MFMA(af[mt], bf[nt], acc[mt][nt]);
    __syncthreads();
  }
  #pragma unroll
  for (int nt = 0; nt < 4; nt++){
    const int n = n0 + wn + nt*16 + lm;
    const float bs = blv[n];
    #pragma unroll
    for (int mt = 0; mt < 4; mt++){
      const int mb = m0 + wm + mt*16;
      f32x4 c = acc[mt][nt];
      float part = 0.f;
      #pragma unroll
      for (int rr = 0; rr < 4; rr++){
        const int ml = (mb - m0) + (q << 2) + rr;
        float sg = 1.f / (1.f + expf(-(c[rr] + bs)));
        part += als[ml] * sg;
      }
      part += __shfl_xor(part, 16, 64);
      if ((q & 1) == 0){
        const int srow = (mb >> 3) + (q >> 1);
        out[(size_t)srow * D + n] = part;
      }
    }
  }
}

// ================= orchestration =================
extern "C" void kernel_launch(void* const* d_in, const int* in_sizes, int n_in,
                              void* d_out, int out_size, void* d_ws, size_t ws_size,
                              hipStream_t stream) {
  const float* q_emb  = (const float*)d_in[0];
  const float* qa_emb = (const float*)d_in[1];
  const float* Wq1 = (const float*)d_in[2],  *bq1 = (const float*)d_in[3];
  const float* Wv1 = (const float*)d_in[4],  *bv1 = (const float*)d_in[5];
  const float* Wo1 = (const float*)d_in[6],  *bo1 = (const float*)d_in[7];
  const float* g1  = (const float*)d_in[8],  *ls1 = (const float*)d_in[9],  *lb1 = (const float*)d_in[10];
  const float* Wq2 = (const float*)d_in[11], *bq2 = (const float*)d_in[12];
  const float* Wv2 = (const float*)d_in[13], *bv2 = (const float*)d_in[14];
  const float* Wo2 = (const float*)d_in[15], *bo2 = (const float*)d_in[16];
  const float* g2  = (const float*)d_in[17], *ls2 = (const float*)d_in[18], *lb2 = (const float*)d_in[19];
  const float* Wq3 = (const float*)d_in[20], *bq3 = (const float*)d_in[21];
  const float* Wk3 = (const float*)d_in[22], *bk3 = (const float*)d_in[23];
  const float* Wv3 = (const float*)d_in[24], *bv3 = (const float*)d_in[25];
  const float* Wo3 = (const float*)d_in[26], *bo3 = (const float*)d_in[27];
  const float* g3  = (const float*)d_in[28], *ls3 = (const float*)d_in[29], *lb3 = (const float*)d_in[30];
  const float* know = (const float*)d_in[31];
  const float* Wlk  = (const float*)d_in[32], *b_lk = (const float*)d_in[33];
  const float* Wlv  = (const float*)d_in[34], *b_lv = (const float*)d_in[35];
  float* outp = (float*)d_out;

  const size_t NSD = (size_t)BB * S * D;   // 2,097,152
  unsigned short* p = (unsigned short*)d_ws;
  unsigned short* qk1b = p; p += NSD;
  unsigned short* v1b  = p; p += NSD;
  unsigned short* qk2b = p; p += NSD;
  unsigned short* v2b  = p; p += NSD;
  unsigned short* k3b  = p; p += NSD;
  unsigned short* v3b  = p; p += NSD;
  unsigned short* ctx1b= p; p += NSD;
  unsigned short* ctx2b= p; p += NSD;
  unsigned short* ctx3b= p; p += NSD;
  unsigned short* xqb  = p; p += NSD;
  unsigned short* xab  = p; p += NSD;
  unsigned short* hqb  = p; p += NSD;
  unsigned short* hab  = p; p += NSD;
  unsigned short* hfb  = p; p += NSD;
  unsigned short* vt1  = p; p += NSD;   // [32][64][1024]
  unsigned short* vt2  = p; p += NSD;
  unsigned short* vt3  = p; p += NSD;
  unsigned short* wb   = p; p += (size_t)9 * D * D;
  unsigned short* wlvb = p; p += (size_t)D * DKH;
  float* yv0   = (float*)p;
  float* yv1   = yv0 + NSD;
  float* q3    = yv1 + NSD;
  float* keyt  = q3 + 512;
  float* c3    = keyt + 4096;
  float* alpha = c3 + (size_t)BB * H * S;

  unsigned short* Wq1b = wb + 0*(size_t)D*D;
  unsigned short* Wv1b = wb + 1*(size_t)D*D;
  unsigned short* Wo1b = wb + 2*(size_t)D*D;
  unsigned short* Wq2b = wb + 3*(size_t)D*D;
  unsigned short* Wv2b = wb + 4*(size_t)D*D;
  unsigned short* Wo2b = wb + 5*(size_t)D*D;
  unsigned short* Wk3b = wb + 6*(size_t)D*D;
  unsigned short* Wv3b = wb + 7*(size_t)D*D;
  unsigned short* Wo3b = wb + 8*(size_t)D*D;

  // ---- conversions ----
  CvtJobs jb;
  jb.s[0] = q_emb;  jb.d[0] = xqb;  jb.n[0] = (int)NSD;
  jb.s[1] = qa_emb; jb.d[1] = xab;  jb.n[1] = (int)NSD;
  jb.s[2] = Wq1; jb.d[2] = Wq1b; jb.n[2] = D*D;
  jb.s[3] = Wv1; jb.d[3] = Wv1b; jb.n[3] = D*D;
  jb.s[4] = Wo1; jb.d[4] = Wo1b; jb.n[4] = D*D;
  jb.s[5] = Wq2; jb.d[5] = Wq2b; jb.n[5] = D*D;
  jb.s[6] = Wv2; jb.d[6] = Wv2b; jb.n[6] = D*D;
  jb.s[7] = Wo2; jb.d[7] = Wo2b; jb.n[7] = D*D;
  jb.s[8] = Wk3; jb.d[8] = Wk3b; jb.n[8] = D*D;
  jb.s[9] = Wv3; jb.d[9] = Wv3b; jb.n[9] = D*D;
  jb.s[10] = Wo3; jb.d[10] = Wo3b; jb.n[10] = D*D;
  jb.s[11] = Wlv; jb.d[11] = wlvb; jb.n[11] = D*DKH;
  cvt_all<<<dim3(256, 12), 256, 0, stream>>>(jb);

  // ---- blocks 1&2: projections (z=4) ----
  {
    GemmJobs g;
    g.A[0]=xqb; g.W[0]=Wq1b; g.bias[0]=bq1; g.C[0]=qk1b;
    g.A[1]=xqb; g.W[1]=Wv1b; g.bias[1]=bv1; g.C[1]=v1b;
    g.A[2]=xab; g.W[2]=Wq2b; g.bias[2]=bq2; g.C[2]=qk2b;
    g.A[3]=xab; g.W[3]=Wv2b; g.bias[3]=bv2; g.C[3]=v2b;
    mfma_gemm_b<1><<<dim3(4, 32, 4), 256, 0, stream>>>(g);
  }
  { VTArgs a; a.v[0]=v1b; a.v[1]=v2b; a.vt[0]=vt1; a.vt[1]=vt2;
    vt_kernel<<<dim3(16, 32, 2), 256, 0, stream>>>(a); }
  { FAArgs a;
    a.qk[0]=qk1b; a.qk[1]=qk2b; a.vt[0]=vt1; a.vt[1]=vt2;
    a.ctx[0]=ctx1b; a.ctx[1]=ctx2b; a.g[0]=g1; a.g[1]=g2;
    a.c3=nullptr; a.diag=0; a.zero_pad=0;
    fused_attn<0><<<dim3(32, 32, 2), 256, 0, stream>>>(a); }
  {
    GemmJobs g;
    g.A[0]=ctx1b; g.W[0]=Wo1b; g.bias[0]=bo1; g.C[0]=yv0;
    g.A[1]=ctx2b; g.W[1]=Wo2b; g.bias[1]=bo2; g.C[1]=yv1;
    g.A[2]=ctx1b; g.W[2]=Wo1b; g.bias[2]=bo1; g.C[2]=yv0;
    g.A[3]=ctx1b; g.W[3]=Wo1b; g.bias[3]=bo1; g.C[3]=yv0;
    mfma_gemm_b<0><<<dim3(4, 32, 2), 256, 0, stream>>>(g);
  }
  ln_residual<<<BB*S, 256, 0, stream>>>(q_emb,  yv0, ls1, lb1, hqb, 0);
  ln_residual<<<BB*S, 256, 0, stream>>>(qa_emb, yv1, ls2, lb2, hab, 0);

  // ---- block 3 ----
  qvec3_kernel<<<2, 256, 0, stream>>>(know, Wq3, bq3, q3);
  {
    GemmJobs g;
    g.A[0]=hqb; g.W[0]=Wk3b; g.bias[0]=bk3; g.C[0]=k3b;
    g.A[1]=hab; g.W[1]=Wv3b; g.bias[1]=bv3; g.C[1]=v3b;
    g.A[2]=hqb; g.W[2]=Wk3b; g.bias[2]=bk3; g.C[2]=k3b;
    g.A[3]=hqb; g.W[3]=Wk3b; g.bias[3]=bk3; g.C[3]=k3b;
    mfma_gemm_b<1><<<dim3(4, 32, 2), 256, 0, stream>>>(g);
  }
  { VTArgs a; a.v[0]=v3b; a.v[1]=v3b; a.vt[0]=vt3; a.vt[1]=vt3;
    vt_kernel<<<dim3(16, 32, 1), 256, 0, stream>>>(a); }
  scores3_kernel<<<128, 256, 0, stream>>>(q3, k3b, c3);
  { FAArgs a;
    a.qk[0]=k3b; a.qk[1]=k3b; a.vt[0]=vt3; a.vt[1]=vt3;
    a.ctx[0]=ctx3b; a.ctx[1]=ctx3b; a.g[0]=g3; a.g[1]=g3;
    a.c3=c3; a.diag=-1; a.zero_pad=1;
    fused_attn<1><<<dim3(32, 32, 1), 256, 0, stream>>>(a); }
  {
    GemmJobs g;
    g.A[0]=ctx3b; g.W[0]=Wo3b; g.bias[0]=bo3; g.C[0]=yv0;
    g.A[1]=ctx3b; g.W[1]=Wo3b; g.bias[1]=bo3; g.C[1]=yv0;
    g.A[2]=ctx3b; g.W[2]=Wo3b; g.bias[2]=bo3; g.C[2]=yv0;
    g.A[3]=ctx3b; g.W[3]=Wo3b; g.bias[3]=bo3; g.C[3]=yv0;
    mfma_gemm_b<0><<<dim3(4, 32, 1), 256, 0, stream>>>(g);
  }
  ln_residual<<<BB*S, 256, 0, stream>>>(know, yv0, ls3, lb3, hfb, 1);

  // ---- final combine ----
  keyt_kernel<<<16, 256, 0, stream>>>(know, Wlk, b_lk, keyt);
  alphas_kernel<<<1024, 256, 0, stream>>>(keyt, q_emb, alpha);
  val_fused<<<dim3(4, 256), 256, 0, stream>>>(hfb, wlvb, b_lv, alpha, outp);
}

// Round 4
// 482.353 us; speedup vs baseline: 3.2981x; 1.2900x over previous
//
#include <hip/hip_runtime.h>
#include <math.h>

#define BB 4
#define S 1024
#define D 512
#define H 8
#define DKH 64

#define ATT_LD 1032   // att row stride (shorts): 516 dwords == 4 mod 32
#define KS_LD  66

typedef __attribute__((ext_vector_type(8))) short bf16x8;
typedef __attribute__((ext_vector_type(4))) float f32x4;

__device__ __forceinline__ unsigned short f2bf(float f){
  unsigned int u = __float_as_uint(f);
  u += 0x7FFFu + ((u >> 16) & 1u);
  return (unsigned short)(u >> 16);
}
__device__ __forceinline__ float bf2f(unsigned int v){
  return __uint_as_float(v << 16);
}
__device__ __forceinline__ f32x4 MFMA(bf16x8 a, bf16x8 b, f32x4 c){
  return __builtin_amdgcn_mfma_f32_16x16x32_bf16(a, b, c, 0, 0, 0);
}
// async global->LDS, 16B/lane; lds base must be wave-uniform (lane*16 auto-scatter)
__device__ __forceinline__ void gl_lds16(const void* g, void* l){
  __builtin_amdgcn_global_load_lds(
      (const __attribute__((address_space(1))) void*)g,
      (__attribute__((address_space(3))) void*)l, 16, 0, 0);
}

__device__ __forceinline__ float blk_sum(float* r, int t, float v){
  r[t] = v; __syncthreads();
  for (int s = 128; s > 0; s >>= 1){
    if (t < s) r[t] += r[t + s];
    __syncthreads();
  }
  float res = r[0]; __syncthreads();
  return res;
}

// ================= batched projection GEMM (M=4096,N=512,K=512) =================
struct GemmJobs {
  const unsigned short* A[4];
  const unsigned short* W[4];
  const float* bias[4];
  void* C[4];
};
template<int OUTBF>
__global__ __launch_bounds__(256) void mfma_gemm_b(GemmJobs jb)
{
  __shared__ __align__(16) short As[128][32];
  __shared__ __align__(16) short Ws[128][32];
  const int t = threadIdx.x;
  const int z = blockIdx.z;
  const int n0 = blockIdx.x * 128, m0 = blockIdx.y * 128;
  const unsigned short* A = jb.A[z];
  const unsigned short* W = jb.W[z];
  const float* bias = jb.bias[z];
  const int w = t >> 6, lane = t & 63;
  const int wm = (w >> 1) << 6, wn = (w & 1) << 6;
  const int lm = lane & 15, q = lane >> 4;
  const int r = t >> 2, cc = (t & 3) << 3;
  char* ldsA = ((char*)&As[0][0]) + w * 1024;
  char* ldsW = ((char*)&Ws[0][0]) + w * 1024;
  f32x4 acc[4][4];
  #pragma unroll
  for (int a_ = 0; a_ < 4; a_++)
    #pragma unroll
    for (int b_ = 0; b_ < 4; b_++)
      acc[a_][b_] = (f32x4){0.f, 0.f, 0.f, 0.f};
  for (int k0 = 0; k0 < D; k0 += 32){
    gl_lds16(&A[(size_t)(m0 + r)      * D + k0 + cc], ldsA);
    gl_lds16(&A[(size_t)(m0 + r + 64) * D + k0 + cc], ldsA + 4096);
    gl_lds16(&W[(size_t)(n0 + r)      * D + k0 + cc], ldsW);
    gl_lds16(&W[(size_t)(n0 + r + 64) * D + k0 + cc], ldsW + 4096);
    __syncthreads();
    bf16x8 af[4], bf[4];
    #pragma unroll
    for (int mt = 0; mt < 4; mt++) af[mt] = *(const bf16x8*)&As[wm + mt*16 + lm][q*8];
    #pragma unroll
    for (int nt = 0; nt < 4; nt++) bf[nt] = *(const bf16x8*)&Ws[wn + nt*16 + lm][q*8];
    #pragma unroll
    for (int mt = 0; mt < 4; mt++)
      #pragma unroll
      for (int nt = 0; nt < 4; nt++)
        acc[mt][nt] = MFMA(af[mt], bf[nt], acc[mt][nt]);
    __syncthreads();
  }
  #pragma unroll
  for (int nt = 0; nt < 4; nt++){
    const int n = n0 + wn + nt*16 + lm;
    const float bs = bias[n];
    #pragma unroll
    for (int mt = 0; mt < 4; mt++){
      const int mb = m0 + wm + mt*16 + (q << 2);
      f32x4 c = acc[mt][nt];
      #pragma unroll
      for (int rr = 0; rr < 4; rr++){
        float vv = c[rr] + bs;
        if (OUTBF)
          ((unsigned short*)jb.C[z])[(size_t)(mb + rr) * D + n] = f2bf(vv);
        else
          ((float*)jb.C[z])[(size_t)(mb + rr) * D + n] = vv;
      }
    }
  }
}

// ================= V transpose: VT[bh][64][S] from V[b][S][D] =================
struct VTArgs { const unsigned short* v[2]; unsigned short* vt[2]; };
__global__ __launch_bounds__(256) void vt_kernel(VTArgs a)
{
  __shared__ unsigned short tile[64 * KS_LD];
  const int z = blockIdx.z, bh = blockIdx.y, b = bh >> 3, h = bh & 7;
  const int j0 = blockIdx.x * 64;
  const int t = threadIdx.x;
  const unsigned short* vp = a.v[z];
  unsigned short* vtp = a.vt[z] + (size_t)bh * 64 * S;
  #pragma unroll
  for (int p = 0; p < 2; p++){
    int lin = t + p * 256, row = lin >> 3, c8 = (lin & 7) << 3;
    *(uint4*)&tile[row * KS_LD + c8] =
      *(const uint4*)&vp[((size_t)b * S + j0 + row) * D + h * DKH + c8];
  }
  __syncthreads();
  #pragma unroll
  for (int p = 0; p < 2; p++){
    int lin = t + p * 256, d = lin >> 3, c8 = (lin & 7) << 3;
    unsigned short tmp[8];
    #pragma unroll
    for (int jx = 0; jx < 8; jx++) tmp[jx] = tile[(c8 + jx) * KS_LD + d];
    *(uint4*)&vtp[(size_t)d * S + j0 + c8] = *(const uint4*)tmp;
  }
}

// ================= fused attention: scores -> decay -> AV, Smat in LDS =================
// grid (S/32, B*H, nz). block 256 = 4 waves. i-block = 32 rows.
struct FAArgs {
  const unsigned short* qk[2];   // q==k source (bf16, [b][S][D])
  const unsigned short* vt[2];   // VT (bf16, [bh][64][S])
  unsigned short* ctx[2];        // out (bf16, [b][S][D])
  const float* g[2];
  const float* c3;               // fp32 [b][h][S] (C3 mode)
  int diag, zero_pad;
};
template<int C3>
__global__ __launch_bounds__(256) void fused_attn(FAArgs a)
{
  __shared__ __align__(16) unsigned short att[32 * ATT_LD];   // 66,048 B
  __shared__ __align__(16) unsigned short Ks[64 * KS_LD];     //  8,448 B
  const int t = threadIdx.x;
  const int z = blockIdx.z;
  const int bh = blockIdx.y, b = bh >> 3, h = bh & 7;
  const int i0 = blockIdx.x * 32;
  const int w = t >> 6, lane = t & 63, lm = lane & 15, q = lane >> 4;
  const unsigned short* qkp = a.qk[z];
  const unsigned short* vtp = a.vt[z] + (size_t)bh * 64 * S;
  unsigned short* ctxp = a.ctx[z];
  const int r0 = t >> 3, c8 = (t & 7) << 3;   // staging: 2 chunks, rows r0 / r0+32
  float gm;
  { float gv = a.g[z][h]; gm = -((gv > 20.f) ? gv : log1pf(expf(gv))); }

  // ---------- phase 1: scores tile [32 x 1024] -> att (bf16) ----------
  if (!C3){
    bf16x8 af[2][2];
    #pragma unroll
    for (int mt = 0; mt < 2; mt++)
      #pragma unroll
      for (int kft = 0; kft < 2; kft++)
        af[mt][kft] = *(const bf16x8*)
          &qkp[((size_t)b * S + i0 + mt*16 + lm) * D + h * DKH + kft*32 + q*8];
    uint4 k0v = *(const uint4*)&qkp[((size_t)b * S + r0)      * D + h * DKH + c8];
    uint4 k1v = *(const uint4*)&qkp[((size_t)b * S + r0 + 32) * D + h * DKH + c8];
    for (int jc = 0; jc < S; jc += 64){
      *(uint4*)&Ks[r0 * KS_LD + c8]        = k0v;
      *(uint4*)&Ks[(r0 + 32) * KS_LD + c8] = k1v;
      __syncthreads();
      if (jc + 64 < S){
        k0v = *(const uint4*)&qkp[((size_t)b * S + jc + 64 + r0)      * D + h * DKH + c8];
        k1v = *(const uint4*)&qkp[((size_t)b * S + jc + 64 + r0 + 32) * D + h * DKH + c8];
      }
      bf16x8 bv0 = *(const bf16x8*)&Ks[(w*16 + lm) * KS_LD + q*8];
      bf16x8 bv1 = *(const bf16x8*)&Ks[(w*16 + lm) * KS_LD + 32 + q*8];
      #pragma unroll
      for (int mt = 0; mt < 2; mt++){
        f32x4 acc = (f32x4){0.f, 0.f, 0.f, 0.f};
        acc = MFMA(af[mt][0], bv0, acc);
        acc = MFMA(af[mt][1], bv1, acc);
        #pragma unroll
        for (int rr = 0; rr < 4; rr++)
          att[(mt*16 + q*4 + rr) * ATT_LD + jc + w*16 + lm] = f2bf(acc[rr] * 0.125f);
      }
      __syncthreads();
    }
  }

  // prefetch phase-3 first VT chunk (hides under phase 2)
  uint4 v0 = *(const uint4*)&vtp[(size_t)r0 * S + c8];
  uint4 v1 = *(const uint4*)&vtp[(size_t)(r0 + 32) * S + c8];

  // ---------- phase 2: decay + double softmax, wave-per-row ----------
  // lane owns j in [8*lane, 8*lane+8) and [512+8*lane, 512+8*lane+8)
  const int jA0 = lane * 8, jB0 = 512 + lane * 8;
  for (int rloc = 0; rloc < 8; rloc++){
    const int i = i0 + w*8 + rloc;
    unsigned short* rowp = &att[(w*8 + rloc) * ATT_LD];
    if (C3 && a.zero_pad && i == 0){
      uint4 zz = make_uint4(0u,0u,0u,0u);
      *(uint4*)&rowp[jA0] = zz;
      *(uint4*)&rowp[jB0] = zz;
      continue;
    }
    float c[16];
    if (C3){
      const float* c3p = a.c3 + ((size_t)b * H + h) * S;
      #pragma unroll
      for (int sg = 0; sg < 2; sg++)
        #pragma unroll
        for (int p4 = 0; p4 < 2; p4++){
          float4 x = *(const float4*)&c3p[sg*512 + lane*8 + p4*4];
          c[sg*8+p4*4+0] = x.x; c[sg*8+p4*4+1] = x.y;
          c[sg*8+p4*4+2] = x.z; c[sg*8+p4*4+3] = x.w;
        }
    } else {
      #pragma unroll
      for (int sg = 0; sg < 2; sg++){
        uint4 u = *(const uint4*)&rowp[sg*512 + lane*8];
        unsigned int uu[4] = {u.x, u.y, u.z, u.w};
        #pragma unroll
        for (int mel = 0; mel < 4; mel++){
          c[sg*8 + mel*2]     = bf2f(uu[mel] & 0xffffu);
          c[sg*8 + mel*2 + 1] = bf2f(uu[mel] >> 16);
        }
      }
    }
    const int jmax = i + a.diag;
    // masked exp (no max-shift: |scores| << 80) + in-lane inclusive prefix
    float pl[16];
    float runA = 0.f, runB = 0.f;
    #pragma unroll
    for (int k = 0; k < 8; k++){
      float e = (jA0 + k <= jmax) ? __expf(c[k]) : 0.f;
      runA += e; pl[k] = runA;
    }
    #pragma unroll
    for (int k = 0; k < 8; k++){
      float e = (jB0 + k <= jmax) ? __expf(c[8+k]) : 0.f;
      runB += e; pl[8+k] = runB;
    }
    // wave scans of the two segment sums (raw space; sum folded into scan total)
    float sA = runA, sB = runB;
    #pragma unroll
    for (int off = 1; off < 64; off <<= 1){
      float uA = __shfl_up(sA, off, 64);
      float uB = __shfl_up(sB, off, 64);
      if (lane >= off){ sA += uA; sB += uB; }
    }
    const float TA = __shfl(sA, 63, 64);
    const float T  = TA + __shfl(sB, 63, 64);
    const float inv1 = 1.f / T;
    const float cbaseA = (T - (sA - runA)) * inv1;        // (T - exclA)/T
    const float cbaseB = (T - (TA + sB - runB)) * inv1;
    const float fiA = (float)(i - jA0);
    const float fiB = (float)(i - jB0);
    float ls2 = 0.f;
    #pragma unroll
    for (int k = 0; k < 8; k++){
      float remn = fmaf(-pl[k], inv1, cbaseA);            // (disttotal-distcum)
      float pos  = fabsf(fiA - (float)k);
      float dist = sqrtf(fmaxf(remn * pos, 0.f));
      float eff  = fmaxf(__expf(gm * dist), 1e-5f);       // gm<0 => eff<=1, skip hi clamp
      float pp   = __expf(c[k] * eff);
      ls2 += pp; pl[k] = pp;
    }
    #pragma unroll
    for (int k = 0; k < 8; k++){
      float remn = fmaf(-pl[8+k], inv1, cbaseB);
      float pos  = fabsf(fiB - (float)k);
      float dist = sqrtf(fmaxf(remn * pos, 0.f));
      float eff  = fmaxf(__expf(gm * dist), 1e-5f);
      float pp   = __expf(c[8+k] * eff);
      ls2 += pp; pl[8+k] = pp;
    }
    #pragma unroll
    for (int off = 1; off < 64; off <<= 1) ls2 += __shfl_xor(ls2, off, 64);
    const float inv2 = 1.f / ls2;
    #pragma unroll
    for (int sg = 0; sg < 2; sg++){
      unsigned int ou[4];
      #pragma unroll
      for (int mel = 0; mel < 4; mel++){
        unsigned int lo = f2bf(pl[sg*8 + 2*mel]     * inv2);
        unsigned int hi = f2bf(pl[sg*8 + 2*mel + 1] * inv2);
        ou[mel] = lo | (hi << 16);
      }
      *(uint4*)&rowp[sg*512 + lane*8] = make_uint4(ou[0], ou[1], ou[2], ou[3]);
    }
  }
  __syncthreads();

  // ---------- phase 3: ctx = att @ V via VT ----------
  const int mloc = w & 1, nh = w >> 1;
  f32x4 acc0 = (f32x4){0.f,0.f,0.f,0.f};
  f32x4 acc1 = (f32x4){0.f,0.f,0.f,0.f};
  for (int kc = 0; kc < S; kc += 64){
    *(uint4*)&Ks[r0 * KS_LD + c8]        = v0;
    *(uint4*)&Ks[(r0 + 32) * KS_LD + c8] = v1;
    __syncthreads();
    if (kc + 64 < S){
      v0 = *(const uint4*)&vtp[(size_t)r0 * S + kc + 64 + c8];
      v1 = *(const uint4*)&vtp[(size_t)(r0 + 32) * S + kc + 64 + c8];
    }
    #pragma unroll
    for (int kft = 0; kft < 2; kft++){
      bf16x8 afv = *(const bf16x8*)&att[(mloc*16 + lm) * ATT_LD + kc + kft*32 + q*8];
      bf16x8 b0 = *(const bf16x8*)&Ks[((nh*2 + 0)*16 + lm) * KS_LD + kft*32 + q*8];
      bf16x8 b1 = *(const bf16x8*)&Ks[((nh*2 + 1)*16 + lm) * KS_LD + kft*32 + q*8];
      acc0 = MFMA(afv, b0, acc0);
      acc1 = MFMA(afv, b1, acc1);
    }
    __syncthreads();
  }
  #pragma unroll
  for (int nt2 = 0; nt2 < 2; nt2++){
    f32x4 acc = nt2 ? acc1 : acc0;
    const int d = (nh*2 + nt2)*16 + lm;
    #pragma unroll
    for (int rr = 0; rr < 4; rr++){
      const int row = i0 + mloc*16 + q*4 + rr;
      ctxp[((size_t)b * S + row) * D + h * DKH + d] = f2bf(acc[rr]);
    }
  }
}

// ================= residual + LayerNorm -> bf16 =================
__global__ __launch_bounds__(256) void ln_residual(
    const float* __restrict__ resid, const float* __restrict__ y,
    const float* __restrict__ ls, const float* __restrict__ lb,
    unsigned short* __restrict__ out, int bcast)
{
  const int r = blockIdx.x, t = threadIdx.x;
  __shared__ float red[256];
  const size_t base = (size_t)r * D;
  float r0 = bcast ? resid[t]       : resid[base + t];
  float r1 = bcast ? resid[t + 256] : resid[base + t + 256];
  float x0 = r0 + y[base + t];
  float x1 = r1 + y[base + t + 256];
  float mean = blk_sum(red, t, x0 + x1) * (1.0f / 512.0f);
  float d0 = x0 - mean, d1 = x1 - mean;
  float var = blk_sum(red, t, d0*d0 + d1*d1) * (1.0f / 512.0f);
  float inv = rsqrtf(var + 1e-5f);
  out[base + t]       = f2bf(d0 * inv * ls[t]       + lb[t]);
  out[base + t + 256] = f2bf(d1 * inv * ls[t + 256] + lb[t + 256]);
}

// ================= fp32 -> bf16 conversions =================
struct CvtJobs {
  const float* s[12];
  unsigned short* d[12];
  int n[12];
};
__global__ __launch_bounds__(256) void cvt_all(CvtJobs jb){
  const int z = blockIdx.y;
  const int n = jb.n[z];
  const float* s = jb.s[z];
  unsigned short* d = jb.d[z];
  for (int idx = blockIdx.x * 256 + threadIdx.x; idx < n; idx += gridDim.x * 256)
    d[idx] = f2bf(s[idx]);
}

// ================= small kernels =================
__global__ __launch_bounds__(256) void qvec3_kernel(
    const float* __restrict__ know, const float* __restrict__ Wq3,
    const float* __restrict__ bq3, float* __restrict__ q3)
{
  int n = blockIdx.x * 256 + threadIdx.x;
  float acc = 0.f;
  for (int d = 0; d < 512; d++) acc += know[d] * Wq3[(size_t)n * 512 + d];
  q3[n] = acc + bq3[n];
}

__global__ __launch_bounds__(256) void keyt_kernel(
    const float* __restrict__ know, const float* __restrict__ Wlk,
    const float* __restrict__ blk_, float* __restrict__ keyt)
{
  int idx = blockIdx.x * 256 + threadIdx.x;
  int h = idx >> 9, n = idx & 511;
  float acc = 0.f;
  for (int i = 0; i < 64; i++) acc += know[h * 64 + i] * Wlk[(size_t)n * 64 + i];
  keyt[idx] = 1.f / (1.f + __expf(-(acc + blk_[n])));
}

__global__ __launch_bounds__(256) void scores3_kernel(
    const float* __restrict__ q3, const unsigned short* __restrict__ k3,
    float* __restrict__ c3)
{
  int idx = blockIdx.x * 256 + threadIdx.x;   // (b*H+h)*S + j
  int j  = idx & (S - 1);
  int bh = idx >> 10;
  int h  = bh & 7, b = bh >> 3;
  const unsigned short* kp = k3 + ((size_t)b * S + j) * D + h * DKH;
  const float* qp = q3 + h * DKH;
  float acc = 0.f;
  #pragma unroll
  for (int d8 = 0; d8 < 64; d8 += 8){
    uint4 u = *(const uint4*)&kp[d8];
    unsigned int uu[4] = {u.x, u.y, u.z, u.w};
    #pragma unroll
    for (int mel = 0; mel < 4; mel++){
      acc += qp[d8 + 2*mel]     * bf2f(uu[mel] & 0xffffu);
      acc += qp[d8 + 2*mel + 1] * bf2f(uu[mel] >> 16);
    }
  }
  c3[idx] = acc * 0.125f;
}

__global__ __launch_bounds__(256) void alphas_kernel(
    const float* __restrict__ keyt, const float* __restrict__ q_emb,
    float* __restrict__ alpha)
{
  const int row = blockIdx.x * 4 + (threadIdx.x >> 6);
  const int l = threadIdx.x & 63;
  const int h = l >> 3, sub = l & 7;
  const float* qr = q_emb + (size_t)row * D;
  const float* kt = keyt + h * D;
  float p = 0.f;
  for (int d = sub; d < D; d += 8) p += kt[d] * qr[d];
  p += __shfl_xor(p, 1, 64);
  p += __shfl_xor(p, 2, 64);
  p += __shfl_xor(p, 4, 64);
  float m = p;
  m = fmaxf(m, __shfl_xor(m, 8, 64));
  m = fmaxf(m, __shfl_xor(m, 16, 64));
  m = fmaxf(m, __shfl_xor(m, 32, 64));
  float e = __expf(p - m);
  float ssum = e;
  ssum += __shfl_xor(ssum, 8, 64);
  ssum += __shfl_xor(ssum, 16, 64);
  ssum += __shfl_xor(ssum, 32, 64);
  if (sub == 0) alpha[(size_t)row * H + h] = e / ssum;
}

// ================= fused val GEMM + sigmoid + alpha-combine =================
__global__ __launch_bounds__(256) void val_fused(
    const unsigned short* __restrict__ Ah,
    const unsigned short* __restrict__ Wv,
    const float* __restrict__ blv,
    const float* __restrict__ alpha,
    float* __restrict__ out)
{
  __shared__ __align__(16) short As[128][32];
  __shared__ __align__(16) short Ws[128][32];
  __shared__ float als[128];
  const int t = threadIdx.x;
  const int n0 = blockIdx.x * 128, m0 = blockIdx.y * 128;
  if (t < 128) als[t] = alpha[m0 + t];
  const int w = t >> 6, lane = t & 63;
  const int wm = (w >> 1) << 6, wn = (w & 1) << 6;
  const int lm = lane & 15, q = lane >> 4;
  const int r = t >> 2, cc = (t & 3) << 3;
  f32x4 acc[4][4];
  #pragma unroll
  for (int a_ = 0; a_ < 4; a_++)
    #pragma unroll
    for (int b_ = 0; b_ < 4; b_++)
      acc[a_][b_] = (f32x4){0.f, 0.f, 0.f, 0.f};
  for (int k0 = 0; k0 < 64; k0 += 32){
    *(uint4*)&As[r][cc]      = *(const uint4*)&Ah[(size_t)(m0 + r) * 64 + k0 + cc];
    *(uint4*)&As[r + 64][cc] = *(const uint4*)&Ah[(size_t)(m0 + r + 64) * 64 + k0 + cc];
    *(uint4*)&Ws[r][cc]      = *(const uint4*)&Wv[(size_t)(n0 + r) * 64 + k0 + cc];
    *(uint4*)&Ws[r + 64][cc] = *(const uint4*)&Wv[(size_t)(n0 + r + 64) * 64 + k0 + cc];
    __syncthreads();
    bf16x8 af[4], bf[4];
    #pragma unroll
    for (int mt = 0; mt < 4; mt++) af[mt] = *(const bf16x8*)&As[wm + mt*16 + lm][q*8];
    #pragma unroll
    for (int nt = 0; nt < 4; nt++) bf[nt] = *(const bf16x8*)&Ws[wn + nt*16 + lm][q*8];
    #pragma unroll
    for (int mt = 0; mt < 4; mt++)
      #pragma unroll
      for (int nt = 0; nt < 4; nt++)
        acc[mt][nt] = MFMA(af[mt], bf[nt], acc[mt][nt]);
    __syncthreads();
  }
  #pragma unroll
  for (int nt = 0; nt < 4; nt++){
    const int n = n0 + wn + nt*16 + lm;
    const float bs = blv[n];
    #pragma unroll
    for (int mt = 0; mt < 4; mt++){
      const int mb = m0 + wm + mt*16;
      f32x4 c = acc[mt][nt];
      float part = 0.f;
      #pragma unroll
      for (int rr = 0; rr < 4; rr++){
        const int ml = (mb - m0) + (q << 2) + rr;
        float sg = 1.f / (1.f + __expf(-(c[rr] + bs)));
        part += als[ml] * sg;
      }
      part += __shfl_xor(part, 16, 64);
      if ((q & 1) == 0){
        const int srow = (mb >> 3) + (q >> 1);
        out[(size_t)srow * D + n] = part;
      }
    }
  }
}

// ================= orchestration =================
extern "C" void kernel_launch(void* const* d_in, const int* in_sizes, int n_in,
                              void* d_out, int out_size, void* d_ws, size_t ws_size,
                              hipStream_t stream) {
  const float* q_emb  = (const float*)d_in[0];
  const float* qa_emb = (const float*)d_in[1];
  const float* Wq1 = (const float*)d_in[2],  *bq1 = (const float*)d_in[3];
  const float* Wv1 = (const float*)d_in[4],  *bv1 = (const float*)d_in[5];
  const float* Wo1 = (const float*)d_in[6],  *bo1 = (const float*)d_in[7];
  const float* g1  = (const float*)d_in[8],  *ls1 = (const float*)d_in[9],  *lb1 = (const float*)d_in[10];
  const float* Wq2 = (const float*)d_in[11], *bq2 = (const float*)d_in[12];
  const float* Wv2 = (const float*)d_in[13], *bv2 = (const float*)d_in[14];
  const float* Wo2 = (const float*)d_in[15], *bo2 = (const float*)d_in[16];
  const float* g2  = (const float*)d_in[17], *ls2 = (const float*)d_in[18], *lb2 = (const float*)d_in[19];
  const float* Wq3 = (const float*)d_in[20], *bq3 = (const float*)d_in[21];
  const float* Wk3 = (const float*)d_in[22], *bk3 = (const float*)d_in[23];
  const float* Wv3 = (const float*)d_in[24], *bv3 = (const float*)d_in[25];
  const float* Wo3 = (const float*)d_in[26], *bo3 = (const float*)d_in[27];
  const float* g3  = (const float*)d_in[28], *ls3 = (const float*)d_in[29], *lb3 = (const float*)d_in[30];
  const float* know = (const float*)d_in[31];
  const float* Wlk  = (const float*)d_in[32], *b_lk = (const float*)d_in[33];
  const float* Wlv  = (const float*)d_in[34], *b_lv = (const float*)d_in[35];
  float* outp = (float*)d_out;

  const size_t NSD = (size_t)BB * S * D;   // 2,097,152
  unsigned short* p = (unsigned short*)d_ws;
  unsigned short* qk1b = p; p += NSD;
  unsigned short* v1b  = p; p += NSD;
  unsigned short* qk2b = p; p += NSD;
  unsigned short* v2b  = p; p += NSD;
  unsigned short* k3b  = p; p += NSD;
  unsigned short* v3b  = p; p += NSD;
  unsigned short* ctx1b= p; p += NSD;
  unsigned short* ctx2b= p; p += NSD;
  unsigned short* ctx3b= p; p += NSD;
  unsigned short* xqb  = p; p += NSD;
  unsigned short* xab  = p; p += NSD;
  unsigned short* hqb  = p; p += NSD;
  unsigned short* hab  = p; p += NSD;
  unsigned short* hfb  = p; p += NSD;
  unsigned short* vt1  = p; p += NSD;   // [32][64][1024]
  unsigned short* vt2  = p; p += NSD;
  unsigned short* vt3  = p; p += NSD;
  unsigned short* wb   = p; p += (size_t)9 * D * D;
  unsigned short* wlvb = p; p += (size_t)D * DKH;
  float* yv0   = (float*)p;
  float* yv1   = yv0 + NSD;
  float* q3    = yv1 + NSD;
  float* keyt  = q3 + 512;
  float* c3    = keyt + 4096;
  float* alpha = c3 + (size_t)BB * H * S;

  unsigned short* Wq1b = wb + 0*(size_t)D*D;
  unsigned short* Wv1b = wb + 1*(size_t)D*D;
  unsigned short* Wo1b = wb + 2*(size_t)D*D;
  unsigned short* Wq2b = wb + 3*(size_t)D*D;
  unsigned short* Wv2b = wb + 4*(size_t)D*D;
  unsigned short* Wo2b = wb + 5*(size_t)D*D;
  unsigned short* Wk3b = wb + 6*(size_t)D*D;
  unsigned short* Wv3b = wb + 7*(size_t)D*D;
  unsigned short* Wo3b = wb + 8*(size_t)D*D;

  // ---- conversions ----
  CvtJobs jb;
  jb.s[0] = q_emb;  jb.d[0] = xqb;  jb.n[0] = (int)NSD;
  jb.s[1] = qa_emb; jb.d[1] = xab;  jb.n[1] = (int)NSD;
  jb.s[2] = Wq1; jb.d[2] = Wq1b; jb.n[2] = D*D;
  jb.s[3] = Wv1; jb.d[3] = Wv1b; jb.n[3] = D*D;
  jb.s[4] = Wo1; jb.d[4] = Wo1b; jb.n[4] = D*D;
  jb.s[5] = Wq2; jb.d[5] = Wq2b; jb.n[5] = D*D;
  jb.s[6] = Wv2; jb.d[6] = Wv2b; jb.n[6] = D*D;
  jb.s[7] = Wo2; jb.d[7] = Wo2b; jb.n[7] = D*D;
  jb.s[8] = Wk3; jb.d[8] = Wk3b; jb.n[8] = D*D;
  jb.s[9] = Wv3; jb.d[9] = Wv3b; jb.n[9] = D*D;
  jb.s[10] = Wo3; jb.d[10] = Wo3b; jb.n[10] = D*D;
  jb.s[11] = Wlv; jb.d[11] = wlvb; jb.n[11] = D*DKH;
  cvt_all<<<dim3(256, 12), 256, 0, stream>>>(jb);

  // ---- blocks 1&2: projections (z=4) ----
  {
    GemmJobs g;
    g.A[0]=xqb; g.W[0]=Wq1b; g.bias[0]=bq1; g.C[0]=qk1b;
    g.A[1]=xqb; g.W[1]=Wv1b; g.bias[1]=bv1; g.C[1]=v1b;
    g.A[2]=xab; g.W[2]=Wq2b; g.bias[2]=bq2; g.C[2]=qk2b;
    g.A[3]=xab; g.W[3]=Wv2b; g.bias[3]=bv2; g.C[3]=v2b;
    mfma_gemm_b<1><<<dim3(4, 32, 4), 256, 0, stream>>>(g);
  }
  { VTArgs a; a.v[0]=v1b; a.v[1]=v2b; a.vt[0]=vt1; a.vt[1]=vt2;
    vt_kernel<<<dim3(16, 32, 2), 256, 0, stream>>>(a); }
  { FAArgs a;
    a.qk[0]=qk1b; a.qk[1]=qk2b; a.vt[0]=vt1; a.vt[1]=vt2;
    a.ctx[0]=ctx1b; a.ctx[1]=ctx2b; a.g[0]=g1; a.g[1]=g2;
    a.c3=nullptr; a.diag=0; a.zero_pad=0;
    fused_attn<0><<<dim3(32, 32, 2), 256, 0, stream>>>(a); }
  {
    GemmJobs g;
    g.A[0]=ctx1b; g.W[0]=Wo1b; g.bias[0]=bo1; g.C[0]=yv0;
    g.A[1]=ctx2b; g.W[1]=Wo2b; g.bias[1]=bo2; g.C[1]=yv1;
    g.A[2]=ctx1b; g.W[2]=Wo1b; g.bias[2]=bo1; g.C[2]=yv0;
    g.A[3]=ctx1b; g.W[3]=Wo1b; g.bias[3]=bo1; g.C[3]=yv0;
    mfma_gemm_b<0><<<dim3(4, 32, 2), 256, 0, stream>>>(g);
  }
  ln_residual<<<BB*S, 256, 0, stream>>>(q_emb,  yv0, ls1, lb1, hqb, 0);
  ln_residual<<<BB*S, 256, 0, stream>>>(qa_emb, yv1, ls2, lb2, hab, 0);

  // ---- block 3 ----
  qvec3_kernel<<<2, 256, 0, stream>>>(know, Wq3, bq3, q3);
  {
    GemmJobs g;
    g.A[0]=hqb; g.W[0]=Wk3b; g.bias[0]=bk3; g.C[0]=k3b;
    g.A[1]=hab; g.W[1]=Wv3b; g.bias[1]=bv3; g.C[1]=v3b;
    g.A[2]=hqb; g.W[2]=Wk3b; g.bias[2]=bk3; g.C[2]=k3b;
    g.A[3]=hqb; g.W[3]=Wk3b; g.bias[3]=bk3; g.C[3]=k3b;
    mfma_gemm_b<1><<<dim3(4, 32, 2), 256, 0, stream>>>(g);
  }
  { VTArgs a; a.v[0]=v3b; a.v[1]=v3b; a.vt[0]=vt3; a.vt[1]=vt3;
    vt_kernel<<<dim3(16, 32, 1), 256, 0, stream>>>(a); }
  scores3_kernel<<<128, 256, 0, stream>>>(q3, k3b, c3);
  { FAArgs a;
    a.qk[0]=k3b; a.qk[1]=k3b; a.vt[0]=vt3; a.vt[1]=vt3;
    a.ctx[0]=ctx3b; a.ctx[1]=ctx3b; a.g[0]=g3; a.g[1]=g3;
    a.c3=c3; a.diag=-1; a.zero_pad=1;
    fused_attn<1><<<dim3(32, 32, 1), 256, 0, stream>>>(a); }
  {
    GemmJobs g;
    g.A[0]=ctx3b; g.W[0]=Wo3b; g.bias[0]=bo3; g.C[0]=yv0;
    g.A[1]=ctx3b; g.W[1]=Wo3b; g.bias[1]=bo3; g.C[1]=yv0;
    g.A[2]=ctx3b; g.W[2]=Wo3b; g.bias[2]=bo3; g.C[2]=yv0;
    g.A[3]=ctx3b; g.W[3]=Wo3b; g.bias[3]=bo3; g.C[3]=yv0;
    mfma_gemm_b<0><<<dim3(4, 32, 1), 256, 0, stream>>>(g);
  }
  ln_residual<<<BB*S, 256, 0, stream>>>(know, yv0, ls3, lb3, hfb, 1);

  // ---- final combine ----
  keyt_kernel<<<16, 256, 0, stream>>>(know, Wlk, b_lk, keyt);
  alphas_kernel<<<1024, 256, 0, stream>>>(keyt, q_emb, alpha);
  val_fused<<<dim3(4, 256), 256, 0, stream>>>(hfb, wlvb, b_lv, alpha, outp);
}

// Round 5
// 478.826 us; speedup vs baseline: 3.3224x; 1.0074x over previous
//
#include <hip/hip_runtime.h>
#include <math.h>

#define BB 4
#define S 1024
#define D 512
#define H 8
#define DKH 64

#define ATT_LD 1032   // att row stride (shorts): 516 dwords == 4 mod 32 (2-way = free)
#define LOG2E 1.4426950408889634f

typedef __attribute__((ext_vector_type(8))) short bf16x8;
typedef __attribute__((ext_vector_type(4))) float f32x4;

__device__ __forceinline__ unsigned short f2bf(float f){
  unsigned int u = __float_as_uint(f);
  u += 0x7FFFu + ((u >> 16) & 1u);
  return (unsigned short)(u >> 16);
}
__device__ __forceinline__ float bf2f(unsigned int v){
  return __uint_as_float(v << 16);
}
__device__ __forceinline__ f32x4 MFMA(bf16x8 a, bf16x8 b, f32x4 c){
  return __builtin_amdgcn_mfma_f32_16x16x32_bf16(a, b, c, 0, 0, 0);
}
__device__ __forceinline__ void gl_lds16(const void* g, void* l){
  __builtin_amdgcn_global_load_lds(
      (const __attribute__((address_space(1))) void*)g,
      (__attribute__((address_space(3))) void*)l, 16, 0, 0);
}

__device__ __forceinline__ float blk_sum(float* r, int t, float v){
  r[t] = v; __syncthreads();
  for (int s = 128; s > 0; s >>= 1){
    if (t < s) r[t] += r[t + s];
    __syncthreads();
  }
  float res = r[0]; __syncthreads();
  return res;
}

// ================= batched projection GEMM (M=4096,N=512,K=512) =================
struct GemmJobs {
  const unsigned short* A[4];
  const unsigned short* W[4];
  const float* bias[4];
  void* C[4];
};
template<int OUTBF>
__global__ __launch_bounds__(256) void mfma_gemm_b(GemmJobs jb)
{
  __shared__ __align__(16) short As[128][32];
  __shared__ __align__(16) short Ws[128][32];
  const int t = threadIdx.x;
  const int z = blockIdx.z;
  const int n0 = blockIdx.x * 128, m0 = blockIdx.y * 128;
  const unsigned short* A = jb.A[z];
  const unsigned short* W = jb.W[z];
  const float* bias = jb.bias[z];
  const int w = t >> 6, lane = t & 63;
  const int wm = (w >> 1) << 6, wn = (w & 1) << 6;
  const int lm = lane & 15, q = lane >> 4;
  const int r = t >> 2, cc = (t & 3) << 3;
  char* ldsA = ((char*)&As[0][0]) + w * 1024;
  char* ldsW = ((char*)&Ws[0][0]) + w * 1024;
  f32x4 acc[4][4];
  #pragma unroll
  for (int a_ = 0; a_ < 4; a_++)
    #pragma unroll
    for (int b_ = 0; b_ < 4; b_++)
      acc[a_][b_] = (f32x4){0.f, 0.f, 0.f, 0.f};
  for (int k0 = 0; k0 < D; k0 += 32){
    gl_lds16(&A[(size_t)(m0 + r)      * D + k0 + cc], ldsA);
    gl_lds16(&A[(size_t)(m0 + r + 64) * D + k0 + cc], ldsA + 4096);
    gl_lds16(&W[(size_t)(n0 + r)      * D + k0 + cc], ldsW);
    gl_lds16(&W[(size_t)(n0 + r + 64) * D + k0 + cc], ldsW + 4096);
    __syncthreads();
    bf16x8 af[4], bf[4];
    #pragma unroll
    for (int mt = 0; mt < 4; mt++) af[mt] = *(const bf16x8*)&As[wm + mt*16 + lm][q*8];
    #pragma unroll
    for (int nt = 0; nt < 4; nt++) bf[nt] = *(const bf16x8*)&Ws[wn + nt*16 + lm][q*8];
    #pragma unroll
    for (int mt = 0; mt < 4; mt++)
      #pragma unroll
      for (int nt = 0; nt < 4; nt++)
        acc[mt][nt] = MFMA(af[mt], bf[nt], acc[mt][nt]);
    __syncthreads();
  }
  #pragma unroll
  for (int nt = 0; nt < 4; nt++){
    const int n = n0 + wn + nt*16 + lm;
    const float bs = bias[n];
    #pragma unroll
    for (int mt = 0; mt < 4; mt++){
      const int mb = m0 + wm + mt*16 + (q << 2);
      f32x4 c = acc[mt][nt];
      #pragma unroll
      for (int rr = 0; rr < 4; rr++){
        float vv = c[rr] + bs;
        if (OUTBF)
          ((unsigned short*)jb.C[z])[(size_t)(mb + rr) * D + n] = f2bf(vv);
        else
          ((float*)jb.C[z])[(size_t)(mb + rr) * D + n] = vv;
      }
    }
  }
}

// ================= V transpose: VT[bh][64][S] from V[b][S][D] =================
#define KS_LD 66
struct VTArgs { const unsigned short* v[2]; unsigned short* vt[2]; };
__global__ __launch_bounds__(256) void vt_kernel(VTArgs a)
{
  __shared__ unsigned short tile[64 * KS_LD];
  const int z = blockIdx.z, bh = blockIdx.y, b = bh >> 3, h = bh & 7;
  const int j0 = blockIdx.x * 64;
  const int t = threadIdx.x;
  const unsigned short* vp = a.v[z];
  unsigned short* vtp = a.vt[z] + (size_t)bh * 64 * S;
  #pragma unroll
  for (int p = 0; p < 2; p++){
    int lin = t + p * 256, row = lin >> 3, c8 = (lin & 7) << 3;
    *(uint4*)&tile[row * KS_LD + c8] =
      *(const uint4*)&vp[((size_t)b * S + j0 + row) * D + h * DKH + c8];
  }
  __syncthreads();
  #pragma unroll
  for (int p = 0; p < 2; p++){
    int lin = t + p * 256, d = lin >> 3, c8 = (lin & 7) << 3;
    unsigned short tmp[8];
    #pragma unroll
    for (int jx = 0; jx < 8; jx++) tmp[jx] = tile[(c8 + jx) * KS_LD + d];
    *(uint4*)&vtp[(size_t)d * S + j0 + c8] = *(const uint4*)tmp;
  }
}

// ================= fused attention: scores -> decay -> AV =================
// 16-row i-blocks, att in LDS (33 KB -> 4 blocks/CU). B-frags direct from global.
// grid (S/16, B*H, nz). block 256 = 4 waves.
struct FAArgs {
  const unsigned short* qk[2];   // q==k source (bf16, [b][S][D])
  const unsigned short* vt[2];   // VT (bf16, [bh][64][S])
  unsigned short* ctx[2];        // out (bf16, [b][S][D])
  const float* g[2];
  const float* c3;               // fp32 [b][h][S] (C3 mode)
  int diag, zero_pad;
};
template<int C3>
__global__ __launch_bounds__(256) void fused_attn(FAArgs a)
{
  __shared__ __align__(16) unsigned short att[16 * ATT_LD];   // 33,024 B
  const int t = threadIdx.x;
  const int z = blockIdx.z;
  const int bh = blockIdx.y, b = bh >> 3, h = bh & 7;
  const int i0 = blockIdx.x * 16;
  const int w = t >> 6, lane = t & 63, lm = lane & 15, q = lane >> 4;
  const unsigned short* qkp = a.qk[z];
  const unsigned short* vtp = a.vt[z] + (size_t)bh * 64 * S;
  unsigned short* ctxp = a.ctx[z];
  float gm2;
  { float gv = a.g[z][h];
    gm2 = -((gv > 20.f) ? gv : log1pf(expf(gv))) * LOG2E; }   // log2-space gamma

  // ---------- phase 1: scores tile [16 x 1024] -> att (bf16) ----------
  if (!C3){
    bf16x8 af0 = *(const bf16x8*)&qkp[((size_t)b * S + i0 + lm) * D + h * DKH + q*8];
    bf16x8 af1 = *(const bf16x8*)&qkp[((size_t)b * S + i0 + lm) * D + h * DKH + 32 + q*8];
    for (int jc = 0; jc < S; jc += 64){
      const int jrow = jc + w*16 + lm;
      const size_t kb = ((size_t)b * S + jrow) * D + h * DKH;
      bf16x8 bv0 = *(const bf16x8*)&qkp[kb + q*8];
      bf16x8 bv1 = *(const bf16x8*)&qkp[kb + 32 + q*8];
      f32x4 acc = (f32x4){0.f, 0.f, 0.f, 0.f};
      acc = MFMA(af0, bv0, acc);
      acc = MFMA(af1, bv1, acc);
      #pragma unroll
      for (int rr = 0; rr < 4; rr++)
        att[(q*4 + rr) * ATT_LD + jc + w*16 + lm] = f2bf(acc[rr] * 0.125f);
    }
  }
  __syncthreads();

  // ---------- phase 2: decay + double softmax, wave-per-row (4 rows/wave) ----------
  // lane owns j in [8*lane, 8*lane+8) and [512+8*lane, 512+8*lane+8)
  const int jA0 = lane * 8, jB0 = 512 + lane * 8;
  for (int rloc = 0; rloc < 4; rloc++){
    const int i = i0 + w*4 + rloc;
    unsigned short* rowp = &att[(w*4 + rloc) * ATT_LD];
    if (C3 && a.zero_pad && i == 0){
      uint4 zz = make_uint4(0u,0u,0u,0u);
      *(uint4*)&rowp[jA0] = zz;
      *(uint4*)&rowp[jB0] = zz;
      continue;
    }
    float c[16];   // c * log2(e)
    if (C3){
      const float* c3p = a.c3 + ((size_t)b * H + h) * S;
      #pragma unroll
      for (int sg = 0; sg < 2; sg++)
        #pragma unroll
        for (int p4 = 0; p4 < 2; p4++){
          float4 x = *(const float4*)&c3p[sg*512 + lane*8 + p4*4];
          c[sg*8+p4*4+0] = x.x * LOG2E; c[sg*8+p4*4+1] = x.y * LOG2E;
          c[sg*8+p4*4+2] = x.z * LOG2E; c[sg*8+p4*4+3] = x.w * LOG2E;
        }
    } else {
      #pragma unroll
      for (int sg = 0; sg < 2; sg++){
        uint4 u = *(const uint4*)&rowp[sg*512 + lane*8];
        unsigned int uu[4] = {u.x, u.y, u.z, u.w};
        #pragma unroll
        for (int mel = 0; mel < 4; mel++){
          c[sg*8 + mel*2]     = bf2f(uu[mel] & 0xffffu) * LOG2E;
          c[sg*8 + mel*2 + 1] = bf2f(uu[mel] >> 16) * LOG2E;
        }
      }
    }
    const int jmax = i + a.diag;
    float pl[16];
    float runA = 0.f, runB = 0.f;
    #pragma unroll
    for (int k = 0; k < 8; k++){
      float e = (jA0 + k <= jmax) ? exp2f(c[k]) : 0.f;
      runA += e; pl[k] = runA;
    }
    #pragma unroll
    for (int k = 0; k < 8; k++){
      float e = (jB0 + k <= jmax) ? exp2f(c[8+k]) : 0.f;
      runB += e; pl[8+k] = runB;
    }
    float sA = runA, sB = runB;
    #pragma unroll
    for (int off = 1; off < 64; off <<= 1){
      float uA = __shfl_up(sA, off, 64);
      float uB = __shfl_up(sB, off, 64);
      if (lane >= off){ sA += uA; sB += uB; }
    }
    const float TA = __shfl(sA, 63, 64);
    const float T  = TA + __shfl(sB, 63, 64);
    const float inv1 = 1.f / T;
    const float cbaseA = (T - (sA - runA)) * inv1;
    const float cbaseB = (T - (TA + sB - runB)) * inv1;
    const float fiA = (float)(i - jA0);
    const float fiB = (float)(i - jB0);
    float ls2 = 0.f;
    #pragma unroll
    for (int k = 0; k < 8; k++){
      float remn = fmaf(-pl[k], inv1, cbaseA);
      float pos  = fabsf(fiA - (float)k);
      float dist = sqrtf(fmaxf(remn * pos, 0.f));
      float eff  = fmaxf(exp2f(gm2 * dist), 1e-5f);
      float pp   = exp2f(c[k] * eff);
      ls2 += pp; pl[k] = pp;
    }
    #pragma unroll
    for (int k = 0; k < 8; k++){
      float remn = fmaf(-pl[8+k], inv1, cbaseB);
      float pos  = fabsf(fiB - (float)k);
      float dist = sqrtf(fmaxf(remn * pos, 0.f));
      float eff  = fmaxf(exp2f(gm2 * dist), 1e-5f);
      float pp   = exp2f(c[8+k] * eff);
      ls2 += pp; pl[8+k] = pp;
    }
    #pragma unroll
    for (int off = 1; off < 64; off <<= 1) ls2 += __shfl_xor(ls2, off, 64);
    const float inv2 = 1.f / ls2;
    #pragma unroll
    for (int sg = 0; sg < 2; sg++){
      unsigned int ou[4];
      #pragma unroll
      for (int mel = 0; mel < 4; mel++){
        unsigned int lo = f2bf(pl[sg*8 + 2*mel]     * inv2);
        unsigned int hi = f2bf(pl[sg*8 + 2*mel + 1] * inv2);
        ou[mel] = lo | (hi << 16);
      }
      *(uint4*)&rowp[sg*512 + lane*8] = make_uint4(ou[0], ou[1], ou[2], ou[3]);
    }
  }
  __syncthreads();

  // ---------- phase 3: ctx = att @ V (B direct from VT in global) ----------
  f32x4 acc = (f32x4){0.f,0.f,0.f,0.f};
  for (int kc = 0; kc < S; kc += 64){
    #pragma unroll
    for (int kft = 0; kft < 2; kft++){
      bf16x8 afv = *(const bf16x8*)&att[lm * ATT_LD + kc + kft*32 + q*8];
      bf16x8 bv  = *(const bf16x8*)&vtp[(size_t)(w*16 + lm) * S + kc + kft*32 + q*8];
      acc = MFMA(afv, bv, acc);
    }
  }
  #pragma unroll
  for (int rr = 0; rr < 4; rr++){
    const int row = i0 + q*4 + rr;
    ctxp[((size_t)b * S + row) * D + h * DKH + w*16 + lm] = f2bf(acc[rr]);
  }
}

// ================= residual + LayerNorm -> bf16 =================
__global__ __launch_bounds__(256) void ln_residual(
    const float* __restrict__ resid, const float* __restrict__ y,
    const float* __restrict__ ls, const float* __restrict__ lb,
    unsigned short* __restrict__ out, int bcast)
{
  const int r = blockIdx.x, t = threadIdx.x;
  __shared__ float red[256];
  const size_t base = (size_t)r * D;
  float r0 = bcast ? resid[t]       : resid[base + t];
  float r1 = bcast ? resid[t + 256] : resid[base + t + 256];
  float x0 = r0 + y[base + t];
  float x1 = r1 + y[base + t + 256];
  float mean = blk_sum(red, t, x0 + x1) * (1.0f / 512.0f);
  float d0 = x0 - mean, d1 = x1 - mean;
  float var = blk_sum(red, t, d0*d0 + d1*d1) * (1.0f / 512.0f);
  float inv = rsqrtf(var + 1e-5f);
  out[base + t]       = f2bf(d0 * inv * ls[t]       + lb[t]);
  out[base + t + 256] = f2bf(d1 * inv * ls[t + 256] + lb[t + 256]);
}

// ================= fp32 -> bf16 conversions =================
struct CvtJobs {
  const float* s[12];
  unsigned short* d[12];
  int n[12];
};
__global__ __launch_bounds__(256) void cvt_all(CvtJobs jb){
  const int z = blockIdx.y;
  const int n = jb.n[z];
  const float* s = jb.s[z];
  unsigned short* d = jb.d[z];
  for (int idx = blockIdx.x * 256 + threadIdx.x; idx < n; idx += gridDim.x * 256)
    d[idx] = f2bf(s[idx]);
}

// ================= small kernels =================
// wave-per-output-n: grid 128 x 256 = 512 waves
__global__ __launch_bounds__(256) void qvec3_kernel(
    const float* __restrict__ know, const float* __restrict__ Wq3,
    const float* __restrict__ bq3, float* __restrict__ q3)
{
  const int wv = (blockIdx.x * 256 + threadIdx.x) >> 6;
  const int lane = threadIdx.x & 63;
  const float* wr = Wq3 + (size_t)wv * 512 + lane * 8;
  const float* kr = know + lane * 8;
  float4 w0 = *(const float4*)&wr[0], w1 = *(const float4*)&wr[4];
  float4 k0 = *(const float4*)&kr[0], k1 = *(const float4*)&kr[4];
  float p = w0.x*k0.x + w0.y*k0.y + w0.z*k0.z + w0.w*k0.w
          + w1.x*k1.x + w1.y*k1.y + w1.z*k1.z + w1.w*k1.w;
  #pragma unroll
  for (int off = 1; off < 64; off <<= 1) p += __shfl_xor(p, off, 64);
  if (lane == 0) q3[wv] = p + bq3[wv];
}

__global__ __launch_bounds__(256) void keyt_kernel(
    const float* __restrict__ know, const float* __restrict__ Wlk,
    const float* __restrict__ blk_, float* __restrict__ keyt)
{
  int idx = blockIdx.x * 256 + threadIdx.x;
  int h = idx >> 9, n = idx & 511;
  float acc = 0.f;
  for (int i = 0; i < 64; i++) acc += know[h * 64 + i] * Wlk[(size_t)n * 64 + i];
  keyt[idx] = 1.f / (1.f + __expf(-(acc + blk_[n])));
}

__global__ __launch_bounds__(256) void scores3_kernel(
    const float* __restrict__ q3, const unsigned short* __restrict__ k3,
    float* __restrict__ c3)
{
  int idx = blockIdx.x * 256 + threadIdx.x;   // (b*H+h)*S + j
  int j  = idx & (S - 1);
  int bh = idx >> 10;
  int h  = bh & 7, b = bh >> 3;
  const unsigned short* kp = k3 + ((size_t)b * S + j) * D + h * DKH;
  const float* qp = q3 + h * DKH;
  float acc = 0.f;
  #pragma unroll
  for (int d8 = 0; d8 < 64; d8 += 8){
    uint4 u = *(const uint4*)&kp[d8];
    unsigned int uu[4] = {u.x, u.y, u.z, u.w};
    #pragma unroll
    for (int mel = 0; mel < 4; mel++){
      acc += qp[d8 + 2*mel]     * bf2f(uu[mel] & 0xffffu);
      acc += qp[d8 + 2*mel + 1] * bf2f(uu[mel] >> 16);
    }
  }
  c3[idx] = acc * 0.125f;
}

__global__ __launch_bounds__(256) void alphas_kernel(
    const float* __restrict__ keyt, const float* __restrict__ q_emb,
    float* __restrict__ alpha)
{
  const int row = blockIdx.x * 4 + (threadIdx.x >> 6);
  const int l = threadIdx.x & 63;
  const int h = l >> 3, sub = l & 7;
  const float* qr = q_emb + (size_t)row * D;
  const float* kt = keyt + h * D;
  float p = 0.f;
  for (int d = sub; d < D; d += 8) p += kt[d] * qr[d];
  p += __shfl_xor(p, 1, 64);
  p += __shfl_xor(p, 2, 64);
  p += __shfl_xor(p, 4, 64);
  float m = p;
  m = fmaxf(m, __shfl_xor(m, 8, 64));
  m = fmaxf(m, __shfl_xor(m, 16, 64));
  m = fmaxf(m, __shfl_xor(m, 32, 64));
  float e = __expf(p - m);
  float ssum = e;
  ssum += __shfl_xor(ssum, 8, 64);
  ssum += __shfl_xor(ssum, 16, 64);
  ssum += __shfl_xor(ssum, 32, 64);
  if (sub == 0) alpha[(size_t)row * H + h] = e / ssum;
}

// ================= fused val GEMM + sigmoid + alpha-combine =================
__global__ __launch_bounds__(256) void val_fused(
    const unsigned short* __restrict__ Ah,
    const unsigned short* __restrict__ Wv,
    const float* __restrict__ blv,
    const float* __restrict__ alpha,
    float* __restrict__ out)
{
  __shared__ __align__(16) short As[128][32];
  __shared__ __align__(16) short Ws[128][32];
  __shared__ float als[128];
  const int t = threadIdx.x;
  const int n0 = blockIdx.x * 128, m0 = blockIdx.y * 128;
  if (t < 128) als[t] = alpha[m0 + t];
  const int w = t >> 6, lane = t & 63;
  const int wm = (w >> 1) << 6, wn = (w & 1) << 6;
  const int lm = lane & 15, q = lane >> 4;
  const int r = t >> 2, cc = (t & 3) << 3;
  f32x4 acc[4][4];
  #pragma unroll
  for (int a_ = 0; a_ < 4; a_++)
    #pragma unroll
    for (int b_ = 0; b_ < 4; b_++)
      acc[a_][b_] = (f32x4){0.f, 0.f, 0.f, 0.f};
  for (int k0 = 0; k0 < 64; k0 += 32){
    *(uint4*)&As[r][cc]      = *(const uint4*)&Ah[(size_t)(m0 + r) * 64 + k0 + cc];
    *(uint4*)&As[r + 64][cc] = *(const uint4*)&Ah[(size_t)(m0 + r + 64) * 64 + k0 + cc];
    *(uint4*)&Ws[r][cc]      = *(const uint4*)&Wv[(size_t)(n0 + r) * 64 + k0 + cc];
    *(uint4*)&Ws[r + 64][cc] = *(const uint4*)&Wv[(size_t)(n0 + r + 64) * 64 + k0 + cc];
    __syncthreads();
    bf16x8 af[4], bf[4];
    #pragma unroll
    for (int mt = 0; mt < 4; mt++) af[mt] = *(const bf16x8*)&As[wm + mt*16 + lm][q*8];
    #pragma unroll
    for (int nt = 0; nt < 4; nt++) bf[nt] = *(const bf16x8*)&Ws[wn + nt*16 + lm][q*8];
    #pragma unroll
    for (int mt = 0; mt < 4; mt++)
      #pragma unroll
      for (int nt = 0; nt < 4; nt++)
        acc[mt][nt] = MFMA(af[mt], bf[nt], acc[mt][nt]);
    __syncthreads();
  }
  #pragma unroll
  for (int nt = 0; nt < 4; nt++){
    const int n = n0 + wn + nt*16 + lm;
    const float bs = blv[n];
    #pragma unroll
    for (int mt = 0; mt < 4; mt++){
      const int mb = m0 + wm + mt*16;
      f32x4 c = acc[mt][nt];
      float part = 0.f;
      #pragma unroll
      for (int rr = 0; rr < 4; rr++){
        const int ml = (mb - m0) + (q << 2) + rr;
        float sg = 1.f / (1.f + __expf(-(c[rr] + bs)));
        part += als[ml] * sg;
      }
      part += __shfl_xor(part, 16, 64);
      if ((q & 1) == 0){
        const int srow = (mb >> 3) + (q >> 1);
        out[(size_t)srow * D + n] = part;
      }
    }
  }
}

// ================= orchestration =================
extern "C" void kernel_launch(void* const* d_in, const int* in_sizes, int n_in,
                              void* d_out, int out_size, void* d_ws, size_t ws_size,
                              hipStream_t stream) {
  const float* q_emb  = (const float*)d_in[0];
  const float* qa_emb = (const float*)d_in[1];
  const float* Wq1 = (const float*)d_in[2],  *bq1 = (const float*)d_in[3];
  const float* Wv1 = (const float*)d_in[4],  *bv1 = (const float*)d_in[5];
  const float* Wo1 = (const float*)d_in[6],  *bo1 = (const float*)d_in[7];
  const float* g1  = (const float*)d_in[8],  *ls1 = (const float*)d_in[9],  *lb1 = (const float*)d_in[10];
  const float* Wq2 = (const float*)d_in[11], *bq2 = (const float*)d_in[12];
  const float* Wv2 = (const float*)d_in[13], *bv2 = (const float*)d_in[14];
  const float* Wo2 = (const float*)d_in[15], *bo2 = (const float*)d_in[16];
  const float* g2  = (const float*)d_in[17], *ls2 = (const float*)d_in[18], *lb2 = (const float*)d_in[19];
  const float* Wq3 = (const float*)d_in[20], *bq3 = (const float*)d_in[21];
  const float* Wk3 = (const float*)d_in[22], *bk3 = (const float*)d_in[23];
  const float* Wv3 = (const float*)d_in[24], *bv3 = (const float*)d_in[25];
  const float* Wo3 = (const float*)d_in[26], *bo3 = (const float*)d_in[27];
  const float* g3  = (const float*)d_in[28], *ls3 = (const float*)d_in[29], *lb3 = (const float*)d_in[30];
  const float* know = (const float*)d_in[31];
  const float* Wlk  = (const float*)d_in[32], *b_lk = (const float*)d_in[33];
  const float* Wlv  = (const float*)d_in[34], *b_lv = (const float*)d_in[35];
  float* outp = (float*)d_out;

  const size_t NSD = (size_t)BB * S * D;   // 2,097,152
  unsigned short* p = (unsigned short*)d_ws;
  unsigned short* qk1b = p; p += NSD;
  unsigned short* v1b  = p; p += NSD;
  unsigned short* qk2b = p; p += NSD;
  unsigned short* v2b  = p; p += NSD;
  unsigned short* k3b  = p; p += NSD;
  unsigned short* v3b  = p; p += NSD;
  unsigned short* ctx1b= p; p += NSD;
  unsigned short* ctx2b= p; p += NSD;
  unsigned short* ctx3b= p; p += NSD;
  unsigned short* xqb  = p; p += NSD;
  unsigned short* xab  = p; p += NSD;
  unsigned short* hqb  = p; p += NSD;
  unsigned short* hab  = p; p += NSD;
  unsigned short* hfb  = p; p += NSD;
  unsigned short* vt1  = p; p += NSD;   // [32][64][1024]
  unsigned short* vt2  = p; p += NSD;
  unsigned short* vt3  = p; p += NSD;
  unsigned short* wb   = p; p += (size_t)9 * D * D;
  unsigned short* wlvb = p; p += (size_t)D * DKH;
  float* yv0   = (float*)p;
  float* yv1   = yv0 + NSD;
  float* q3    = yv1 + NSD;
  float* keyt  = q3 + 512;
  float* c3    = keyt + 4096;
  float* alpha = c3 + (size_t)BB * H * S;

  unsigned short* Wq1b = wb + 0*(size_t)D*D;
  unsigned short* Wv1b = wb + 1*(size_t)D*D;
  unsigned short* Wo1b = wb + 2*(size_t)D*D;
  unsigned short* Wq2b = wb + 3*(size_t)D*D;
  unsigned short* Wv2b = wb + 4*(size_t)D*D;
  unsigned short* Wo2b = wb + 5*(size_t)D*D;
  unsigned short* Wk3b = wb + 6*(size_t)D*D;
  unsigned short* Wv3b = wb + 7*(size_t)D*D;
  unsigned short* Wo3b = wb + 8*(size_t)D*D;

  // ---- conversions ----
  CvtJobs jb;
  jb.s[0] = q_emb;  jb.d[0] = xqb;  jb.n[0] = (int)NSD;
  jb.s[1] = qa_emb; jb.d[1] = xab;  jb.n[1] = (int)NSD;
  jb.s[2] = Wq1; jb.d[2] = Wq1b; jb.n[2] = D*D;
  jb.s[3] = Wv1; jb.d[3] = Wv1b; jb.n[3] = D*D;
  jb.s[4] = Wo1; jb.d[4] = Wo1b; jb.n[4] = D*D;
  jb.s[5] = Wq2; jb.d[5] = Wq2b; jb.n[5] = D*D;
  jb.s[6] = Wv2; jb.d[6] = Wv2b; jb.n[6] = D*D;
  jb.s[7] = Wo2; jb.d[7] = Wo2b; jb.n[7] = D*D;
  jb.s[8] = Wk3; jb.d[8] = Wk3b; jb.n[8] = D*D;
  jb.s[9] = Wv3; jb.d[9] = Wv3b; jb.n[9] = D*D;
  jb.s[10] = Wo3; jb.d[10] = Wo3b; jb.n[10] = D*D;
  jb.s[11] = Wlv; jb.d[11] = wlvb; jb.n[11] = D*DKH;
  cvt_all<<<dim3(256, 12), 256, 0, stream>>>(jb);

  // ---- blocks 1&2: projections (z=4) ----
  {
    GemmJobs g;
    g.A[0]=xqb; g.W[0]=Wq1b; g.bias[0]=bq1; g.C[0]=qk1b;
    g.A[1]=xqb; g.W[1]=Wv1b; g.bias[1]=bv1; g.C[1]=v1b;
    g.A[2]=xab; g.W[2]=Wq2b; g.bias[2]=bq2; g.C[2]=qk2b;
    g.A[3]=xab; g.W[3]=Wv2b; g.bias[3]=bv2; g.C[3]=v2b;
    mfma_gemm_b<1><<<dim3(4, 32, 4), 256, 0, stream>>>(g);
  }
  { VTArgs a; a.v[0]=v1b; a.v[1]=v2b; a.vt[0]=vt1; a.vt[1]=vt2;
    vt_kernel<<<dim3(16, 32, 2), 256, 0, stream>>>(a); }
  { FAArgs a;
    a.qk[0]=qk1b; a.qk[1]=qk2b; a.vt[0]=vt1; a.vt[1]=vt2;
    a.ctx[0]=ctx1b; a.ctx[1]=ctx2b; a.g[0]=g1; a.g[1]=g2;
    a.c3=nullptr; a.diag=0; a.zero_pad=0;
    fused_attn<0><<<dim3(64, 32, 2), 256, 0, stream>>>(a); }
  {
    GemmJobs g;
    g.A[0]=ctx1b; g.W[0]=Wo1b; g.bias[0]=bo1; g.C[0]=yv0;
    g.A[1]=ctx2b; g.W[1]=Wo2b; g.bias[1]=bo2; g.C[1]=yv1;
    g.A[2]=ctx1b; g.W[2]=Wo1b; g.bias[2]=bo1; g.C[2]=yv0;
    g.A[3]=ctx1b; g.W[3]=Wo1b; g.bias[3]=bo1; g.C[3]=yv0;
    mfma_gemm_b<0><<<dim3(4, 32, 2), 256, 0, stream>>>(g);
  }
  ln_residual<<<BB*S, 256, 0, stream>>>(q_emb,  yv0, ls1, lb1, hqb, 0);
  ln_residual<<<BB*S, 256, 0, stream>>>(qa_emb, yv1, ls2, lb2, hab, 0);

  // ---- block 3 ----
  qvec3_kernel<<<128, 256, 0, stream>>>(know, Wq3, bq3, q3);
  {
    GemmJobs g;
    g.A[0]=hqb; g.W[0]=Wk3b; g.bias[0]=bk3; g.C[0]=k3b;
    g.A[1]=hab; g.W[1]=Wv3b; g.bias[1]=bv3; g.C[1]=v3b;
    g.A[2]=hqb; g.W[2]=Wk3b; g.bias[2]=bk3; g.C[2]=k3b;
    g.A[3]=hqb; g.W[3]=Wk3b; g.bias[3]=bk3; g.C[3]=k3b;
    mfma_gemm_b<1><<<dim3(4, 32, 2), 256, 0, stream>>>(g);
  }
  { VTArgs a; a.v[0]=v3b; a.v[1]=v3b; a.vt[0]=vt3; a.vt[1]=vt3;
    vt_kernel<<<dim3(16, 32, 1), 256, 0, stream>>>(a); }
  scores3_kernel<<<128, 256, 0, stream>>>(q3, k3b, c3);
  { FAArgs a;
    a.qk[0]=k3b; a.qk[1]=k3b; a.vt[0]=vt3; a.vt[1]=vt3;
    a.ctx[0]=ctx3b; a.ctx[1]=ctx3b; a.g[0]=g3; a.g[1]=g3;
    a.c3=c3; a.diag=-1; a.zero_pad=1;
    fused_attn<1><<<dim3(64, 32, 1), 256, 0, stream>>>(a); }
  {
    GemmJobs g;
    g.A[0]=ctx3b; g.W[0]=Wo3b; g.bias[0]=bo3; g.C[0]=yv0;
    g.A[1]=ctx3b; g.W[1]=Wo3b; g.bias[1]=bo3; g.C[1]=yv0;
    g.A[2]=ctx3b; g.W[2]=Wo3b; g.bias[2]=bo3; g.C[2]=yv0;
    g.A[3]=ctx3b; g.W[3]=Wo3b; g.bias[3]=bo3; g.C[3]=yv0;
    mfma_gemm_b<0><<<dim3(4, 32, 1), 256, 0, stream>>>(g);
  }
  ln_residual<<<BB*S, 256, 0, stream>>>(know, yv0, ls3, lb3, hfb, 1);

  // ---- final combine ----
  keyt_kernel<<<16, 256, 0, stream>>>(know, Wlk, b_lk, keyt);
  alphas_kernel<<<1024, 256, 0, stream>>>(keyt, q_emb, alpha);
  val_fused<<<dim3(4, 256), 256, 0, stream>>>(hfb, wlvb, b_lv, alpha, outp);
}

// Round 6
// 438.935 us; speedup vs baseline: 3.6244x; 1.0909x over previous
//
#include <hip/hip_runtime.h>
#include <math.h>

#define BB 4
#define S 1024
#define D 512
#define H 8
#define DKH 64

#define ATT_LD 1032   // att row stride (shorts): 516 dwords == 4 mod 32 (2-way = free)
#define LOG2E 1.4426950408889634f

typedef __attribute__((ext_vector_type(8))) short bf16x8;
typedef __attribute__((ext_vector_type(4))) float f32x4;

#if __has_builtin(__builtin_amdgcn_exp2f)
#define EXP2(x) __builtin_amdgcn_exp2f(x)
#else
#define EXP2(x) exp2f(x)
#endif
#if __has_builtin(__builtin_amdgcn_sqrtf)
#define SQRTF(x) __builtin_amdgcn_sqrtf(x)
#else
#define SQRTF(x) sqrtf(x)
#endif
#if __has_builtin(__builtin_amdgcn_rcpf)
#define RCPF(x) __builtin_amdgcn_rcpf(x)
#else
#define RCPF(x) (1.0f / (x))
#endif

__device__ __forceinline__ unsigned short f2bf(float f){
  unsigned int u = __float_as_uint(f);
  u += 0x7FFFu + ((u >> 16) & 1u);
  return (unsigned short)(u >> 16);
}
// round-half-up bf16 (1 add + shr)
__device__ __forceinline__ unsigned short f2bf_rhu(float f){
  return (unsigned short)((__float_as_uint(f) + 0x8000u) >> 16);
}
// pack two fp32 -> two bf16 (round-half-up) in one dword
__device__ __forceinline__ unsigned int pk_rhu(float lo, float hi){
  unsigned int a = __float_as_uint(lo) + 0x8000u;
  unsigned int b = __float_as_uint(hi) + 0x8000u;
#if __has_builtin(__builtin_amdgcn_perm)
  return __builtin_amdgcn_perm(b, a, 0x07060302u);
#else
  return (a >> 16) | (b & 0xffff0000u);
#endif
}
__device__ __forceinline__ float bf2f(unsigned int v){
  return __uint_as_float(v << 16);
}
__device__ __forceinline__ f32x4 MFMA(bf16x8 a, bf16x8 b, f32x4 c){
  return __builtin_amdgcn_mfma_f32_16x16x32_bf16(a, b, c, 0, 0, 0);
}
__device__ __forceinline__ void gl_lds16(const void* g, void* l){
  __builtin_amdgcn_global_load_lds(
      (const __attribute__((address_space(1))) void*)g,
      (__attribute__((address_space(3))) void*)l, 16, 0, 0);
}

__device__ __forceinline__ float blk_sum(float* r, int t, float v){
  r[t] = v; __syncthreads();
  for (int s = 128; s > 0; s >>= 1){
    if (t < s) r[t] += r[t + s];
    __syncthreads();
  }
  float res = r[0]; __syncthreads();
  return res;
}

// ================= batched projection GEMM (M=4096,N=512,K=512) =================
struct GemmJobs {
  const unsigned short* A[4];
  const unsigned short* W[4];
  const float* bias[4];
  void* C[4];
};
template<int OUTBF>
__global__ __launch_bounds__(256) void mfma_gemm_b(GemmJobs jb)
{
  __shared__ __align__(16) short As[128][32];
  __shared__ __align__(16) short Ws[128][32];
  const int t = threadIdx.x;
  const int z = blockIdx.z;
  const int n0 = blockIdx.x * 128, m0 = blockIdx.y * 128;
  const unsigned short* A = jb.A[z];
  const unsigned short* W = jb.W[z];
  const float* bias = jb.bias[z];
  const int w = t >> 6, lane = t & 63;
  const int wm = (w >> 1) << 6, wn = (w & 1) << 6;
  const int lm = lane & 15, q = lane >> 4;
  const int r = t >> 2, cc = (t & 3) << 3;
  char* ldsA = ((char*)&As[0][0]) + w * 1024;
  char* ldsW = ((char*)&Ws[0][0]) + w * 1024;
  f32x4 acc[4][4];
  #pragma unroll
  for (int a_ = 0; a_ < 4; a_++)
    #pragma unroll
    for (int b_ = 0; b_ < 4; b_++)
      acc[a_][b_] = (f32x4){0.f, 0.f, 0.f, 0.f};
  for (int k0 = 0; k0 < D; k0 += 32){
    gl_lds16(&A[(size_t)(m0 + r)      * D + k0 + cc], ldsA);
    gl_lds16(&A[(size_t)(m0 + r + 64) * D + k0 + cc], ldsA + 4096);
    gl_lds16(&W[(size_t)(n0 + r)      * D + k0 + cc], ldsW);
    gl_lds16(&W[(size_t)(n0 + r + 64) * D + k0 + cc], ldsW + 4096);
    __syncthreads();
    bf16x8 af[4], bf[4];
    #pragma unroll
    for (int mt = 0; mt < 4; mt++) af[mt] = *(const bf16x8*)&As[wm + mt*16 + lm][q*8];
    #pragma unroll
    for (int nt = 0; nt < 4; nt++) bf[nt] = *(const bf16x8*)&Ws[wn + nt*16 + lm][q*8];
    #pragma unroll
    for (int mt = 0; mt < 4; mt++)
      #pragma unroll
      for (int nt = 0; nt < 4; nt++)
        acc[mt][nt] = MFMA(af[mt], bf[nt], acc[mt][nt]);
    __syncthreads();
  }
  #pragma unroll
  for (int nt = 0; nt < 4; nt++){
    const int n = n0 + wn + nt*16 + lm;
    const float bs = bias[n];
    #pragma unroll
    for (int mt = 0; mt < 4; mt++){
      const int mb = m0 + wm + mt*16 + (q << 2);
      f32x4 c = acc[mt][nt];
      #pragma unroll
      for (int rr = 0; rr < 4; rr++){
        float vv = c[rr] + bs;
        if (OUTBF)
          ((unsigned short*)jb.C[z])[(size_t)(mb + rr) * D + n] = f2bf(vv);
        else
          ((float*)jb.C[z])[(size_t)(mb + rr) * D + n] = vv;
      }
    }
  }
}

// ================= V transpose: VT[bh][64][S] from V[b][S][D] =================
#define KS_LD 66
struct VTArgs { const unsigned short* v[2]; unsigned short* vt[2]; };
__global__ __launch_bounds__(256) void vt_kernel(VTArgs a)
{
  __shared__ unsigned short tile[64 * KS_LD];
  const int z = blockIdx.z, bh = blockIdx.y, b = bh >> 3, h = bh & 7;
  const int j0 = blockIdx.x * 64;
  const int t = threadIdx.x;
  const unsigned short* vp = a.v[z];
  unsigned short* vtp = a.vt[z] + (size_t)bh * 64 * S;
  #pragma unroll
  for (int p = 0; p < 2; p++){
    int lin = t + p * 256, row = lin >> 3, c8 = (lin & 7) << 3;
    *(uint4*)&tile[row * KS_LD + c8] =
      *(const uint4*)&vp[((size_t)b * S + j0 + row) * D + h * DKH + c8];
  }
  __syncthreads();
  #pragma unroll
  for (int p = 0; p < 2; p++){
    int lin = t + p * 256, d = lin >> 3, c8 = (lin & 7) << 3;
    unsigned short tmp[8];
    #pragma unroll
    for (int jx = 0; jx < 8; jx++) tmp[jx] = tile[(c8 + jx) * KS_LD + d];
    *(uint4*)&vtp[(size_t)d * S + j0 + c8] = *(const uint4*)tmp;
  }
}

// ================= fused attention: scores -> decay -> AV =================
// 16-row i-blocks; att (unnormalized pp) in LDS; row scale applied in phase 3.
// grid (S/16, B*H, nz). block 256 = 4 waves.
struct FAArgs {
  const unsigned short* qk[2];   // q==k source (bf16, [b][S][D])
  const unsigned short* vt[2];   // VT (bf16, [bh][64][S])
  unsigned short* ctx[2];        // out (bf16, [b][S][D])
  const float* g[2];
  const float* c3;               // fp32 [b][h][S] (C3 mode)
  int diag, zero_pad;
};
template<int C3>
__global__ __launch_bounds__(256) void fused_attn(FAArgs a)
{
  __shared__ __align__(16) unsigned short att[16 * ATT_LD];   // 33,024 B
  __shared__ float ls2s[16];                                   // per-row inv2
  const int t = threadIdx.x;
  const int z = blockIdx.z;
  const int bh = blockIdx.y, b = bh >> 3, h = bh & 7;
  const int i0 = blockIdx.x * 16;
  const int w = t >> 6, lane = t & 63, lm = lane & 15, q = lane >> 4;
  const unsigned short* qkp = a.qk[z];
  const unsigned short* vtp = a.vt[z] + (size_t)bh * 64 * S;
  unsigned short* ctxp = a.ctx[z];
  float gm2;
  { float gv = a.g[z][h];
    gm2 = -((gv > 20.f) ? gv : log1pf(expf(gv))) * LOG2E; }   // log2-space gamma

  // ---------- phase 1: scores tile [16 x 1024] -> att (bf16) ----------
  if (!C3){
    bf16x8 af0 = *(const bf16x8*)&qkp[((size_t)b * S + i0 + lm) * D + h * DKH + q*8];
    bf16x8 af1 = *(const bf16x8*)&qkp[((size_t)b * S + i0 + lm) * D + h * DKH + 32 + q*8];
    for (int jc = 0; jc < S; jc += 64){
      const int jrow = jc + w*16 + lm;
      const size_t kb = ((size_t)b * S + jrow) * D + h * DKH;
      bf16x8 bv0 = *(const bf16x8*)&qkp[kb + q*8];
      bf16x8 bv1 = *(const bf16x8*)&qkp[kb + 32 + q*8];
      f32x4 acc = (f32x4){0.f, 0.f, 0.f, 0.f};
      acc = MFMA(af0, bv0, acc);
      acc = MFMA(af1, bv1, acc);
      #pragma unroll
      for (int rr = 0; rr < 4; rr++)
        att[(q*4 + rr) * ATT_LD + jc + w*16 + lm] = f2bf_rhu(acc[rr] * 0.125f);
    }
  }
  __syncthreads();

  // ---------- phase 2: decay + double softmax, wave-per-row (4 rows/wave) ----------
  const int jA0 = lane * 8, jB0 = 512 + lane * 8;

  // C3: scores are row-invariant per (b,h) — hoist unpack + raw exp
  float cH[16], erH[16];
  if (C3){
    const float* c3p = a.c3 + ((size_t)b * H + h) * S;
    #pragma unroll
    for (int sg = 0; sg < 2; sg++)
      #pragma unroll
      for (int p4 = 0; p4 < 2; p4++){
        float4 x = *(const float4*)&c3p[sg*512 + lane*8 + p4*4];
        cH[sg*8+p4*4+0] = x.x * LOG2E; cH[sg*8+p4*4+1] = x.y * LOG2E;
        cH[sg*8+p4*4+2] = x.z * LOG2E; cH[sg*8+p4*4+3] = x.w * LOG2E;
      }
    #pragma unroll
    for (int k = 0; k < 16; k++) erH[k] = EXP2(cH[k]);
  }

  // per-row decay body (c, er in log2/raw-exp space)
  auto decay_row = [&](const float (&c)[16], const float (&er)[16],
                       const int i, unsigned short* rowp, const int rl){
    const int jmax = i + a.diag;
    const bool skipB = (jmax < 512);     // wave-uniform: whole B segment is upper (eff==1)
    float pl[16];
    float runA = 0.f;
    #pragma unroll
    for (int k = 0; k < 8; k++){
      float e = (jA0 + k <= jmax) ? er[k] : 0.f;
      runA += e; pl[k] = runA;
    }
    float sA = runA;
    #pragma unroll
    for (int off = 1; off < 64; off <<= 1){
      float u = __shfl_up(sA, off, 64);
      if (lane >= off) sA += u;
    }
    const float TA = __shfl(sA, 63, 64);
    float T = TA, sB = 0.f, runB = 0.f;
    if (!skipB){
      #pragma unroll
      for (int k = 0; k < 8; k++){
        float e = (jB0 + k <= jmax) ? er[8+k] : 0.f;
        runB += e; pl[8+k] = runB;
      }
      sB = runB;
      #pragma unroll
      for (int off = 1; off < 64; off <<= 1){
        float u = __shfl_up(sB, off, 64);
        if (lane >= off) sB += u;
      }
      T = TA + __shfl(sB, 63, 64);
    }
    const float inv1 = RCPF(T);
    const float cbaseA = (T - (sA - runA)) * inv1;
    const float fiA = (float)(i - jA0);
    float ls2 = 0.f;
    #pragma unroll
    for (int k = 0; k < 8; k++){
      float remn = fmaf(-pl[k], inv1, cbaseA);
      float pos  = fabsf(fiA - (float)k);
      float dist = SQRTF(fmaxf(remn * pos, 0.f));
      float eff  = fmaxf(EXP2(gm2 * dist), 1e-5f);
      float pp   = EXP2(c[k] * eff);
      ls2 += pp; pl[k] = pp;
    }
    if (!skipB){
      const float cbaseB = (T - (TA + sB - runB)) * inv1;
      const float fiB = (float)(i - jB0);
      #pragma unroll
      for (int k = 0; k < 8; k++){
        float remn = fmaf(-pl[8+k], inv1, cbaseB);
        float pos  = fabsf(fiB - (float)k);
        float dist = SQRTF(fmaxf(remn * pos, 0.f));
        float eff  = fmaxf(EXP2(gm2 * dist), 1e-5f);
        float pp   = EXP2(c[8+k] * eff);
        ls2 += pp; pl[8+k] = pp;
      }
    } else {
      #pragma unroll
      for (int k = 0; k < 8; k++){ pl[8+k] = er[8+k]; ls2 += er[8+k]; }
    }
    #pragma unroll
    for (int off = 1; off < 64; off <<= 1) ls2 += __shfl_xor(ls2, off, 64);
    if (lane == 0) ls2s[rl] = RCPF(ls2);
    #pragma unroll
    for (int sg = 0; sg < 2; sg++){
      uint4 o;
      o.x = pk_rhu(pl[sg*8+0], pl[sg*8+1]);
      o.y = pk_rhu(pl[sg*8+2], pl[sg*8+3]);
      o.z = pk_rhu(pl[sg*8+4], pl[sg*8+5]);
      o.w = pk_rhu(pl[sg*8+6], pl[sg*8+7]);
      *(uint4*)&rowp[sg*512 + lane*8] = o;
    }
  };

  for (int rloc = 0; rloc < 4; rloc++){
    const int rl = w*4 + rloc;
    const int i = i0 + rl;
    unsigned short* rowp = &att[rl * ATT_LD];
    if (C3 && a.zero_pad && i == 0){
      uint4 zz = make_uint4(0u,0u,0u,0u);
      *(uint4*)&rowp[jA0] = zz;
      *(uint4*)&rowp[jB0] = zz;
      if (lane == 0) ls2s[0] = 1.f;
      continue;
    }
    if (C3){
      decay_row(cH, erH, i, rowp, rl);
    } else {
      float c[16], er[16];
      #pragma unroll
      for (int sg = 0; sg < 2; sg++){
        uint4 u = *(const uint4*)&rowp[sg*512 + lane*8];
        unsigned int uu[4] = {u.x, u.y, u.z, u.w};
        #pragma unroll
        for (int mel = 0; mel < 4; mel++){
          c[sg*8 + mel*2]     = bf2f(uu[mel] & 0xffffu) * LOG2E;
          c[sg*8 + mel*2 + 1] = bf2f(uu[mel] >> 16) * LOG2E;
        }
      }
      #pragma unroll
      for (int k = 0; k < 16; k++) er[k] = EXP2(c[k]);
      decay_row(c, er, i, rowp, rl);
    }
  }
  __syncthreads();

  // ---------- phase 3: ctx = att @ V (B direct from VT in global), scale by inv2 ----------
  f32x4 acc = (f32x4){0.f,0.f,0.f,0.f};
  for (int kc = 0; kc < S; kc += 64){
    #pragma unroll
    for (int kft = 0; kft < 2; kft++){
      bf16x8 afv = *(const bf16x8*)&att[lm * ATT_LD + kc + kft*32 + q*8];
      bf16x8 bv  = *(const bf16x8*)&vtp[(size_t)(w*16 + lm) * S + kc + kft*32 + q*8];
      acc = MFMA(afv, bv, acc);
    }
  }
  #pragma unroll
  for (int rr = 0; rr < 4; rr++){
    const int rl = q*4 + rr;
    const float sc = ls2s[rl];
    const int row = i0 + rl;
    ctxp[((size_t)b * S + row) * D + h * DKH + w*16 + lm] = f2bf(acc[rr] * sc);
  }
}

// ================= residual + LayerNorm -> bf16 (batched) =================
struct LNJobs {
  const float* resid[2];
  const float* y[2];
  const float* ls[2];
  const float* lb[2];
  unsigned short* out[2];
  int bcast[2];
};
__global__ __launch_bounds__(256) void ln_residual_b(LNJobs j)
{
  const int z = blockIdx.y;
  const int r = blockIdx.x, t = threadIdx.x;
  __shared__ float red[256];
  const size_t base = (size_t)r * D;
  const float* resid = j.resid[z];
  const float* y = j.y[z];
  const int bcast = j.bcast[z];
  float r0 = bcast ? resid[t]       : resid[base + t];
  float r1 = bcast ? resid[t + 256] : resid[base + t + 256];
  float x0 = r0 + y[base + t];
  float x1 = r1 + y[base + t + 256];
  float mean = blk_sum(red, t, x0 + x1) * (1.0f / 512.0f);
  float d0 = x0 - mean, d1 = x1 - mean;
  float var = blk_sum(red, t, d0*d0 + d1*d1) * (1.0f / 512.0f);
  float inv = rsqrtf(var + 1e-5f);
  j.out[z][base + t]       = f2bf(d0 * inv * j.ls[z][t]       + j.lb[z][t]);
  j.out[z][base + t + 256] = f2bf(d1 * inv * j.ls[z][t + 256] + j.lb[z][t + 256]);
}

// ================= fp32 -> bf16 conversions =================
struct CvtJobs {
  const float* s[12];
  unsigned short* d[12];
  int n[12];
};
__global__ __launch_bounds__(256) void cvt_all(CvtJobs jb){
  const int z = blockIdx.y;
  const int n = jb.n[z];
  const float* s = jb.s[z];
  unsigned short* d = jb.d[z];
  for (int idx = blockIdx.x * 256 + threadIdx.x; idx < n; idx += gridDim.x * 256)
    d[idx] = f2bf(s[idx]);
}

// ================= know-derived small kernels (merged) =================
// blocks 0..127: qvec3 (wave per output n); blocks 128..143: keyt
__global__ __launch_bounds__(256) void know_kernel(
    const float* __restrict__ know, const float* __restrict__ Wq3,
    const float* __restrict__ bq3, float* __restrict__ q3,
    const float* __restrict__ Wlk, const float* __restrict__ blk_,
    float* __restrict__ keyt)
{
  if (blockIdx.x < 128){
    const int wv = (blockIdx.x * 256 + threadIdx.x) >> 6;
    const int lane = threadIdx.x & 63;
    const float* wr = Wq3 + (size_t)wv * 512 + lane * 8;
    const float* kr = know + lane * 8;
    float4 w0 = *(const float4*)&wr[0], w1 = *(const float4*)&wr[4];
    float4 k0 = *(const float4*)&kr[0], k1 = *(const float4*)&kr[4];
    float p = w0.x*k0.x + w0.y*k0.y + w0.z*k0.z + w0.w*k0.w
            + w1.x*k1.x + w1.y*k1.y + w1.z*k1.z + w1.w*k1.w;
    #pragma unroll
    for (int off = 1; off < 64; off <<= 1) p += __shfl_xor(p, off, 64);
    if (lane == 0) q3[wv] = p + bq3[wv];
  } else {
    int idx = (blockIdx.x - 128) * 256 + threadIdx.x;
    int h = idx >> 9, n = idx & 511;
    float acc = 0.f;
    for (int i = 0; i < 64; i++) acc += know[h * 64 + i] * Wlk[(size_t)n * 64 + i];
    keyt[idx] = 1.f / (1.f + __expf(-(acc + blk_[n])));
  }
}

__global__ __launch_bounds__(256) void scores3_kernel(
    const float* __restrict__ q3, const unsigned short* __restrict__ k3,
    float* __restrict__ c3)
{
  int idx = blockIdx.x * 256 + threadIdx.x;   // (b*H+h)*S + j
  int j  = idx & (S - 1);
  int bh = idx >> 10;
  int h  = bh & 7, b = bh >> 3;
  const unsigned short* kp = k3 + ((size_t)b * S + j) * D + h * DKH;
  const float* qp = q3 + h * DKH;
  float acc = 0.f;
  #pragma unroll
  for (int d8 = 0; d8 < 64; d8 += 8){
    uint4 u = *(const uint4*)&kp[d8];
    unsigned int uu[4] = {u.x, u.y, u.z, u.w};
    #pragma unroll
    for (int mel = 0; mel < 4; mel++){
      acc += qp[d8 + 2*mel]     * bf2f(uu[mel] & 0xffffu);
      acc += qp[d8 + 2*mel + 1] * bf2f(uu[mel] >> 16);
    }
  }
  c3[idx] = acc * 0.125f;
}

__global__ __launch_bounds__(256) void alphas_kernel(
    const float* __restrict__ keyt, const float* __restrict__ q_emb,
    float* __restrict__ alpha)
{
  const int row = blockIdx.x * 4 + (threadIdx.x >> 6);
  const int l = threadIdx.x & 63;
  const int h = l >> 3, sub = l & 7;
  const float* qr = q_emb + (size_t)row * D;
  const float* kt = keyt + h * D;
  float p = 0.f;
  for (int d = sub; d < D; d += 8) p += kt[d] * qr[d];
  p += __shfl_xor(p, 1, 64);
  p += __shfl_xor(p, 2, 64);
  p += __shfl_xor(p, 4, 64);
  float m = p;
  m = fmaxf(m, __shfl_xor(m, 8, 64));
  m = fmaxf(m, __shfl_xor(m, 16, 64));
  m = fmaxf(m, __shfl_xor(m, 32, 64));
  float e = __expf(p - m);
  float ssum = e;
  ssum += __shfl_xor(ssum, 8, 64);
  ssum += __shfl_xor(ssum, 16, 64);
  ssum += __shfl_xor(ssum, 32, 64);
  if (sub == 0) alpha[(size_t)row * H + h] = e / ssum;
}

// ================= fused val GEMM + sigmoid + alpha-combine =================
__global__ __launch_bounds__(256) void val_fused(
    const unsigned short* __restrict__ Ah,
    const unsigned short* __restrict__ Wv,
    const float* __restrict__ blv,
    const float* __restrict__ alpha,
    float* __restrict__ out)
{
  __shared__ __align__(16) short As[128][32];
  __shared__ __align__(16) short Ws[128][32];
  __shared__ float als[128];
  const int t = threadIdx.x;
  const int n0 = blockIdx.x * 128, m0 = blockIdx.y * 128;
  if (t < 128) als[t] = alpha[m0 + t];
  const int w = t >> 6, lane = t & 63;
  const int wm = (w >> 1) << 6, wn = (w & 1) << 6;
  const int lm = lane & 15, q = lane >> 4;
  const int r = t >> 2, cc = (t & 3) << 3;
  f32x4 acc[4][4];
  #pragma unroll
  for (int a_ = 0; a_ < 4; a_++)
    #pragma unroll
    for (int b_ = 0; b_ < 4; b_++)
      acc[a_][b_] = (f32x4){0.f, 0.f, 0.f, 0.f};
  for (int k0 = 0; k0 < 64; k0 += 32){
    *(uint4*)&As[r][cc]      = *(const uint4*)&Ah[(size_t)(m0 + r) * 64 + k0 + cc];
    *(uint4*)&As[r + 64][cc] = *(const uint4*)&Ah[(size_t)(m0 + r + 64) * 64 + k0 + cc];
    *(uint4*)&Ws[r][cc]      = *(const uint4*)&Wv[(size_t)(n0 + r) * 64 + k0 + cc];
    *(uint4*)&Ws[r + 64][cc] = *(const uint4*)&Wv[(size_t)(n0 + r + 64) * 64 + k0 + cc];
    __syncthreads();
    bf16x8 af[4], bf[4];
    #pragma unroll
    for (int mt = 0; mt < 4; mt++) af[mt] = *(const bf16x8*)&As[wm + mt*16 + lm][q*8];
    #pragma unroll
    for (int nt = 0; nt < 4; nt++) bf[nt] = *(const bf16x8*)&Ws[wn + nt*16 + lm][q*8];
    #pragma unroll
    for (int mt = 0; mt < 4; mt++)
      #pragma unroll
      for (int nt = 0; nt < 4; nt++)
        acc[mt][nt] = MFMA(af[mt], bf[nt], acc[mt][nt]);
    __syncthreads();
  }
  #pragma unroll
  for (int nt = 0; nt < 4; nt++){
    const int n = n0 + wn + nt*16 + lm;
    const float bs = blv[n];
    #pragma unroll
    for (int mt = 0; mt < 4; mt++){
      const int mb = m0 + wm + mt*16;
      f32x4 c = acc[mt][nt];
      float part = 0.f;
      #pragma unroll
      for (int rr = 0; rr < 4; rr++){
        const int ml = (mb - m0) + (q << 2) + rr;
        float sg = 1.f / (1.f + __expf(-(c[rr] + bs)));
        part += als[ml] * sg;
      }
      part += __shfl_xor(part, 16, 64);
      if ((q & 1) == 0){
        const int srow = (mb >> 3) + (q >> 1);
        out[(size_t)srow * D + n] = part;
      }
    }
  }
}

// ================= orchestration =================
extern "C" void kernel_launch(void* const* d_in, const int* in_sizes, int n_in,
                              void* d_out, int out_size, void* d_ws, size_t ws_size,
                              hipStream_t stream) {
  const float* q_emb  = (const float*)d_in[0];
  const float* qa_emb = (const float*)d_in[1];
  const float* Wq1 = (const float*)d_in[2],  *bq1 = (const float*)d_in[3];
  const float* Wv1 = (const float*)d_in[4],  *bv1 = (const float*)d_in[5];
  const float* Wo1 = (const float*)d_in[6],  *bo1 = (const float*)d_in[7];
  const float* g1  = (const float*)d_in[8],  *ls1 = (const float*)d_in[9],  *lb1 = (const float*)d_in[10];
  const float* Wq2 = (const float*)d_in[11], *bq2 = (const float*)d_in[12];
  const float* Wv2 = (const float*)d_in[13], *bv2 = (const float*)d_in[14];
  const float* Wo2 = (const float*)d_in[15], *bo2 = (const float*)d_in[16];
  const float* g2  = (const float*)d_in[17], *ls2 = (const float*)d_in[18], *lb2 = (const float*)d_in[19];
  const float* Wq3 = (const float*)d_in[20], *bq3 = (const float*)d_in[21];
  const float* Wk3 = (const float*)d_in[22], *bk3 = (const float*)d_in[23];
  const float* Wv3 = (const float*)d_in[24], *bv3 = (const float*)d_in[25];
  const float* Wo3 = (const float*)d_in[26], *bo3 = (const float*)d_in[27];
  const float* g3  = (const float*)d_in[28], *ls3 = (const float*)d_in[29], *lb3 = (const float*)d_in[30];
  const float* know = (const float*)d_in[31];
  const float* Wlk  = (const float*)d_in[32], *b_lk = (const float*)d_in[33];
  const float* Wlv  = (const float*)d_in[34], *b_lv = (const float*)d_in[35];
  float* outp = (float*)d_out;

  const size_t NSD = (size_t)BB * S * D;   // 2,097,152
  unsigned short* p = (unsigned short*)d_ws;
  unsigned short* qk1b = p; p += NSD;
  unsigned short* v1b  = p; p += NSD;
  unsigned short* qk2b = p; p += NSD;
  unsigned short* v2b  = p; p += NSD;
  unsigned short* k3b  = p; p += NSD;
  unsigned short* v3b  = p; p += NSD;
  unsigned short* ctx1b= p; p += NSD;
  unsigned short* ctx2b= p; p += NSD;
  unsigned short* ctx3b= p; p += NSD;
  unsigned short* xqb  = p; p += NSD;
  unsigned short* xab  = p; p += NSD;
  unsigned short* hqb  = p; p += NSD;
  unsigned short* hab  = p; p += NSD;
  unsigned short* hfb  = p; p += NSD;
  unsigned short* vt1  = p; p += NSD;   // [32][64][1024]
  unsigned short* vt2  = p; p += NSD;
  unsigned short* vt3  = p; p += NSD;
  unsigned short* wb   = p; p += (size_t)9 * D * D;
  unsigned short* wlvb = p; p += (size_t)D * DKH;
  float* yv0   = (float*)p;
  float* yv1   = yv0 + NSD;
  float* q3    = yv1 + NSD;
  float* keyt  = q3 + 512;
  float* c3    = keyt + 4096;
  float* alpha = c3 + (size_t)BB * H * S;

  unsigned short* Wq1b = wb + 0*(size_t)D*D;
  unsigned short* Wv1b = wb + 1*(size_t)D*D;
  unsigned short* Wo1b = wb + 2*(size_t)D*D;
  unsigned short* Wq2b = wb + 3*(size_t)D*D;
  unsigned short* Wv2b = wb + 4*(size_t)D*D;
  unsigned short* Wo2b = wb + 5*(size_t)D*D;
  unsigned short* Wk3b = wb + 6*(size_t)D*D;
  unsigned short* Wv3b = wb + 7*(size_t)D*D;
  unsigned short* Wo3b = wb + 8*(size_t)D*D;

  // ---- conversions ----
  CvtJobs jb;
  jb.s[0] = q_emb;  jb.d[0] = xqb;  jb.n[0] = (int)NSD;
  jb.s[1] = qa_emb; jb.d[1] = xab;  jb.n[1] = (int)NSD;
  jb.s[2] = Wq1; jb.d[2] = Wq1b; jb.n[2] = D*D;
  jb.s[3] = Wv1; jb.d[3] = Wv1b; jb.n[3] = D*D;
  jb.s[4] = Wo1; jb.d[4] = Wo1b; jb.n[4] = D*D;
  jb.s[5] = Wq2; jb.d[5] = Wq2b; jb.n[5] = D*D;
  jb.s[6] = Wv2; jb.d[6] = Wv2b; jb.n[6] = D*D;
  jb.s[7] = Wo2; jb.d[7] = Wo2b; jb.n[7] = D*D;
  jb.s[8] = Wk3; jb.d[8] = Wk3b; jb.n[8] = D*D;
  jb.s[9] = Wv3; jb.d[9] = Wv3b; jb.n[9] = D*D;
  jb.s[10] = Wo3; jb.d[10] = Wo3b; jb.n[10] = D*D;
  jb.s[11] = Wlv; jb.d[11] = wlvb; jb.n[11] = D*DKH;
  cvt_all<<<dim3(256, 12), 256, 0, stream>>>(jb);

  // ---- blocks 1&2: projections (z=4) ----
  {
    GemmJobs g;
    g.A[0]=xqb; g.W[0]=Wq1b; g.bias[0]=bq1; g.C[0]=qk1b;
    g.A[1]=xqb; g.W[1]=Wv1b; g.bias[1]=bv1; g.C[1]=v1b;
    g.A[2]=xab; g.W[2]=Wq2b; g.bias[2]=bq2; g.C[2]=qk2b;
    g.A[3]=xab; g.W[3]=Wv2b; g.bias[3]=bv2; g.C[3]=v2b;
    mfma_gemm_b<1><<<dim3(4, 32, 4), 256, 0, stream>>>(g);
  }
  { VTArgs a; a.v[0]=v1b; a.v[1]=v2b; a.vt[0]=vt1; a.vt[1]=vt2;
    vt_kernel<<<dim3(16, 32, 2), 256, 0, stream>>>(a); }
  { FAArgs a;
    a.qk[0]=qk1b; a.qk[1]=qk2b; a.vt[0]=vt1; a.vt[1]=vt2;
    a.ctx[0]=ctx1b; a.ctx[1]=ctx2b; a.g[0]=g1; a.g[1]=g2;
    a.c3=nullptr; a.diag=0; a.zero_pad=0;
    fused_attn<0><<<dim3(64, 32, 2), 256, 0, stream>>>(a); }
  {
    GemmJobs g;
    g.A[0]=ctx1b; g.W[0]=Wo1b; g.bias[0]=bo1; g.C[0]=yv0;
    g.A[1]=ctx2b; g.W[1]=Wo2b; g.bias[1]=bo2; g.C[1]=yv1;
    g.A[2]=ctx1b; g.W[2]=Wo1b; g.bias[2]=bo1; g.C[2]=yv0;
    g.A[3]=ctx1b; g.W[3]=Wo1b; g.bias[3]=bo1; g.C[3]=yv0;
    mfma_gemm_b<0><<<dim3(4, 32, 2), 256, 0, stream>>>(g);
  }
  {
    LNJobs lj;
    lj.resid[0]=q_emb;  lj.y[0]=yv0; lj.ls[0]=ls1; lj.lb[0]=lb1; lj.out[0]=hqb; lj.bcast[0]=0;
    lj.resid[1]=qa_emb; lj.y[1]=yv1; lj.ls[1]=ls2; lj.lb[1]=lb2; lj.out[1]=hab; lj.bcast[1]=0;
    ln_residual_b<<<dim3(BB*S, 2), 256, 0, stream>>>(lj);
  }

  // ---- block 3 ----
  know_kernel<<<144, 256, 0, stream>>>(know, Wq3, bq3, q3, Wlk, b_lk, keyt);
  {
    GemmJobs g;
    g.A[0]=hqb; g.W[0]=Wk3b; g.bias[0]=bk3; g.C[0]=k3b;
    g.A[1]=hab; g.W[1]=Wv3b; g.bias[1]=bv3; g.C[1]=v3b;
    g.A[2]=hqb; g.W[2]=Wk3b; g.bias[2]=bk3; g.C[2]=k3b;
    g.A[3]=hqb; g.W[3]=Wk3b; g.bias[3]=bk3; g.C[3]=k3b;
    mfma_gemm_b<1><<<dim3(4, 32, 2), 256, 0, stream>>>(g);
  }
  { VTArgs a; a.v[0]=v3b; a.v[1]=v3b; a.vt[0]=vt3; a.vt[1]=vt3;
    vt_kernel<<<dim3(16, 32, 1), 256, 0, stream>>>(a); }
  scores3_kernel<<<128, 256, 0, stream>>>(q3, k3b, c3);
  { FAArgs a;
    a.qk[0]=k3b; a.qk[1]=k3b; a.vt[0]=vt3; a.vt[1]=vt3;
    a.ctx[0]=ctx3b; a.ctx[1]=ctx3b; a.g[0]=g3; a.g[1]=g3;
    a.c3=c3; a.diag=-1; a.zero_pad=1;
    fused_attn<1><<<dim3(64, 32, 1), 256, 0, stream>>>(a); }
  {
    GemmJobs g;
    g.A[0]=ctx3b; g.W[0]=Wo3b; g.bias[0]=bo3; g.C[0]=yv0;
    g.A[1]=ctx3b; g.W[1]=Wo3b; g.bias[1]=bo3; g.C[1]=yv0;
    g.A[2]=ctx3b; g.W[2]=Wo3b; g.bias[2]=bo3; g.C[2]=yv0;
    g.A[3]=ctx3b; g.W[3]=Wo3b; g.bias[3]=bo3; g.C[3]=yv0;
    mfma_gemm_b<0><<<dim3(4, 32, 1), 256, 0, stream>>>(g);
  }
  {
    LNJobs lj;
    lj.resid[0]=know; lj.y[0]=yv0; lj.ls[0]=ls3; lj.lb[0]=lb3; lj.out[0]=hfb; lj.bcast[0]=1;
    lj.resid[1]=know; lj.y[1]=yv0; lj.ls[1]=ls3; lj.lb[1]=lb3; lj.out[1]=hfb; lj.bcast[1]=1;
    ln_residual_b<<<dim3(BB*S, 1), 256, 0, stream>>>(lj);
  }

  // ---- final combine ----
  alphas_kernel<<<1024, 256, 0, stream>>>(keyt, q_emb, alpha);
  val_fused<<<dim3(4, 256), 256, 0, stream>>>(hfb, wlvb, b_lv, alpha, outp);
}

// Round 7
// 432.462 us; speedup vs baseline: 3.6786x; 1.0150x over previous
//
#include <hip/hip_runtime.h>
#include <math.h>

#define BB 4
#define S 1024
#define D 512
#define H 8
#define DKH 64

#define ATT_LD 1032   // att row stride (shorts): 516 dwords == 4 mod 32 (2-way = free)
#define LOG2E 1.4426950408889634f

typedef __attribute__((ext_vector_type(8))) short bf16x8;
typedef __attribute__((ext_vector_type(4))) float f32x4;

#if __has_builtin(__builtin_amdgcn_exp2f)
#define EXP2(x) __builtin_amdgcn_exp2f(x)
#else
#define EXP2(x) exp2f(x)
#endif
#if __has_builtin(__builtin_amdgcn_sqrtf)
#define SQRTF(x) __builtin_amdgcn_sqrtf(x)
#else
#define SQRTF(x) sqrtf(x)
#endif
#if __has_builtin(__builtin_amdgcn_rcpf)
#define RCPF(x) __builtin_amdgcn_rcpf(x)
#else
#define RCPF(x) (1.0f / (x))
#endif

__device__ __forceinline__ unsigned short f2bf(float f){
  unsigned int u = __float_as_uint(f);
  u += 0x7FFFu + ((u >> 16) & 1u);
  return (unsigned short)(u >> 16);
}
__device__ __forceinline__ unsigned short f2bf_rhu(float f){
  return (unsigned short)((__float_as_uint(f) + 0x8000u) >> 16);
}
__device__ __forceinline__ unsigned int pk_rhu(float lo, float hi){
  unsigned int a = __float_as_uint(lo) + 0x8000u;
  unsigned int b = __float_as_uint(hi) + 0x8000u;
#if __has_builtin(__builtin_amdgcn_perm)
  return __builtin_amdgcn_perm(b, a, 0x07060302u);
#else
  return (a >> 16) | (b & 0xffff0000u);
#endif
}
__device__ __forceinline__ float bf2f(unsigned int v){
  return __uint_as_float(v << 16);
}
__device__ __forceinline__ f32x4 MFMA(bf16x8 a, bf16x8 b, f32x4 c){
  return __builtin_amdgcn_mfma_f32_16x16x32_bf16(a, b, c, 0, 0, 0);
}
__device__ __forceinline__ void gl_lds16(const void* g, void* l){
  __builtin_amdgcn_global_load_lds(
      (const __attribute__((address_space(1))) void*)g,
      (__attribute__((address_space(3))) void*)l, 16, 0, 0);
}

// ---- DPP cross-lane (pure VALU pipe, no ds_bpermute latency) ----
template<int CTRL>
__device__ __forceinline__ float dppadd(float v){
  int s = __builtin_amdgcn_update_dpp(0, __float_as_int(v), CTRL, 0xf, 0xf, true);
  return v + __int_as_float(s);
}
__device__ __forceinline__ float rdl(float v, int l){
  return __int_as_float(__builtin_amdgcn_readlane(__float_as_int(v), l));
}
// inclusive 64-lane prefix (order-exact) + total, via 16-lane row scans + row offsets
__device__ __forceinline__ void wave_scan64(float v, int lane, float& incl, float& total){
  float r = dppadd<0x111>(v);   // row_shr:1
  r = dppadd<0x112>(r);         // row_shr:2
  r = dppadd<0x114>(r);         // row_shr:4
  r = dppadd<0x118>(r);         // row_shr:8
  float t0 = rdl(r, 15), t1 = rdl(r, 31), t2 = rdl(r, 47), t3 = rdl(r, 63);
  const int row = lane >> 4;
  float off = (row > 0 ? t0 : 0.f) + (row > 1 ? t1 : 0.f) + (row > 2 ? t2 : 0.f);
  incl = r + off;
  total = (t0 + t1) + (t2 + t3);
}
__device__ __forceinline__ float wave_sum64(float v){
  float r = dppadd<0x111>(v);
  r = dppadd<0x112>(r);
  r = dppadd<0x114>(r);
  r = dppadd<0x118>(r);
  return (rdl(r, 15) + rdl(r, 31)) + (rdl(r, 47) + rdl(r, 63));
}

__device__ __forceinline__ float blk_sum(float* r, int t, float v){
  r[t] = v; __syncthreads();
  for (int s = 128; s > 0; s >>= 1){
    if (t < s) r[t] += r[t + s];
    __syncthreads();
  }
  float res = r[0]; __syncthreads();
  return res;
}

// ================= batched projection GEMM (M=4096,N=512,K=512) =================
struct GemmJobs {
  const unsigned short* A[4];
  const unsigned short* W[4];
  const float* bias[4];
  void* C[4];
};
template<int OUTBF>
__global__ __launch_bounds__(256) void mfma_gemm_b(GemmJobs jb)
{
  __shared__ __align__(16) short As[128][32];
  __shared__ __align__(16) short Ws[128][32];
  const int t = threadIdx.x;
  const int z = blockIdx.z;
  const int n0 = blockIdx.x * 128, m0 = blockIdx.y * 128;
  const unsigned short* A = jb.A[z];
  const unsigned short* W = jb.W[z];
  const float* bias = jb.bias[z];
  const int w = t >> 6, lane = t & 63;
  const int wm = (w >> 1) << 6, wn = (w & 1) << 6;
  const int lm = lane & 15, q = lane >> 4;
  const int r = t >> 2, cc = (t & 3) << 3;
  char* ldsA = ((char*)&As[0][0]) + w * 1024;
  char* ldsW = ((char*)&Ws[0][0]) + w * 1024;
  f32x4 acc[4][4];
  #pragma unroll
  for (int a_ = 0; a_ < 4; a_++)
    #pragma unroll
    for (int b_ = 0; b_ < 4; b_++)
      acc[a_][b_] = (f32x4){0.f, 0.f, 0.f, 0.f};
  for (int k0 = 0; k0 < D; k0 += 32){
    gl_lds16(&A[(size_t)(m0 + r)      * D + k0 + cc], ldsA);
    gl_lds16(&A[(size_t)(m0 + r + 64) * D + k0 + cc], ldsA + 4096);
    gl_lds16(&W[(size_t)(n0 + r)      * D + k0 + cc], ldsW);
    gl_lds16(&W[(size_t)(n0 + r + 64) * D + k0 + cc], ldsW + 4096);
    __syncthreads();
    bf16x8 af[4], bf[4];
    #pragma unroll
    for (int mt = 0; mt < 4; mt++) af[mt] = *(const bf16x8*)&As[wm + mt*16 + lm][q*8];
    #pragma unroll
    for (int nt = 0; nt < 4; nt++) bf[nt] = *(const bf16x8*)&Ws[wn + nt*16 + lm][q*8];
    #pragma unroll
    for (int mt = 0; mt < 4; mt++)
      #pragma unroll
      for (int nt = 0; nt < 4; nt++)
        acc[mt][nt] = MFMA(af[mt], bf[nt], acc[mt][nt]);
    __syncthreads();
  }
  #pragma unroll
  for (int nt = 0; nt < 4; nt++){
    const int n = n0 + wn + nt*16 + lm;
    const float bs = bias[n];
    #pragma unroll
    for (int mt = 0; mt < 4; mt++){
      const int mb = m0 + wm + mt*16 + (q << 2);
      f32x4 c = acc[mt][nt];
      #pragma unroll
      for (int rr = 0; rr < 4; rr++){
        float vv = c[rr] + bs;
        if (OUTBF)
          ((unsigned short*)jb.C[z])[(size_t)(mb + rr) * D + n] = f2bf(vv);
        else
          ((float*)jb.C[z])[(size_t)(mb + rr) * D + n] = vv;
      }
    }
  }
}

// ================= V transpose: VT[bh][64][S] from V[b][S][D] =================
#define KS_LD 66
struct VTArgs { const unsigned short* v[2]; unsigned short* vt[2]; };
__global__ __launch_bounds__(256) void vt_kernel(VTArgs a)
{
  __shared__ unsigned short tile[64 * KS_LD];
  const int z = blockIdx.z, bh = blockIdx.y, b = bh >> 3, h = bh & 7;
  const int j0 = blockIdx.x * 64;
  const int t = threadIdx.x;
  const unsigned short* vp = a.v[z];
  unsigned short* vtp = a.vt[z] + (size_t)bh * 64 * S;
  #pragma unroll
  for (int p = 0; p < 2; p++){
    int lin = t + p * 256, row = lin >> 3, c8 = (lin & 7) << 3;
    *(uint4*)&tile[row * KS_LD + c8] =
      *(const uint4*)&vp[((size_t)b * S + j0 + row) * D + h * DKH + c8];
  }
  __syncthreads();
  #pragma unroll
  for (int p = 0; p < 2; p++){
    int lin = t + p * 256, d = lin >> 3, c8 = (lin & 7) << 3;
    unsigned short tmp[8];
    #pragma unroll
    for (int jx = 0; jx < 8; jx++) tmp[jx] = tile[(c8 + jx) * KS_LD + d];
    *(uint4*)&vtp[(size_t)d * S + j0 + c8] = *(const uint4*)tmp;
  }
}

// ================= fused attention: scores -> decay -> AV =================
// 16-row i-blocks; att (unnormalized pp) in LDS; row scale applied in phase 3.
// grid (S/16, B*H, nz). block 256 = 4 waves.
struct FAArgs {
  const unsigned short* qk[2];   // q==k source (bf16, [b][S][D])
  const unsigned short* vt[2];   // VT (bf16, [bh][64][S])
  unsigned short* ctx[2];        // out (bf16, [b][S][D])
  const float* g[2];
  const float* c3;               // fp32 [b][h][S] (C3 mode)
  int diag, zero_pad;
};
template<int C3>
__global__ __launch_bounds__(256, 4) void fused_attn(FAArgs a)
{
  __shared__ __align__(16) unsigned short att[16 * ATT_LD];   // 33,024 B
  __shared__ float ls2s[16];                                   // per-row inv2
  const int t = threadIdx.x;
  const int z = blockIdx.z;
  const int bh = blockIdx.y, b = bh >> 3, h = bh & 7;
  const int i0 = blockIdx.x * 16;
  const int w = t >> 6, lane = t & 63, lm = lane & 15, q = lane >> 4;
  const unsigned short* qkp = a.qk[z];
  const unsigned short* vtp = a.vt[z] + (size_t)bh * 64 * S;
  unsigned short* ctxp = a.ctx[z];
  float gm2;
  { float gv = a.g[z][h];
    gm2 = -((gv > 20.f) ? gv : log1pf(expf(gv))) * LOG2E; }   // log2-space gamma

  // ---------- phase 1: scores tile [16 x 1024] -> att (bf16), K prefetched ----------
  if (!C3){
    const size_t rowbase = (size_t)b * S;
    bf16x8 af0 = *(const bf16x8*)&qkp[(rowbase + i0 + lm) * D + h * DKH + q*8];
    bf16x8 af1 = *(const bf16x8*)&qkp[(rowbase + i0 + lm) * D + h * DKH + 32 + q*8];
    size_t kb = (rowbase + w*16 + lm) * D + h * DKH;
    bf16x8 bv0 = *(const bf16x8*)&qkp[kb + q*8];
    bf16x8 bv1 = *(const bf16x8*)&qkp[kb + 32 + q*8];
    for (int jc = 0; jc < S; jc += 64){
      bf16x8 nb0, nb1;
      if (jc + 64 < S){
        size_t kb2 = (rowbase + jc + 64 + w*16 + lm) * D + h * DKH;
        nb0 = *(const bf16x8*)&qkp[kb2 + q*8];
        nb1 = *(const bf16x8*)&qkp[kb2 + 32 + q*8];
      }
      f32x4 acc = (f32x4){0.f, 0.f, 0.f, 0.f};
      acc = MFMA(af0, bv0, acc);
      acc = MFMA(af1, bv1, acc);
      #pragma unroll
      for (int rr = 0; rr < 4; rr++)
        att[(q*4 + rr) * ATT_LD + jc + w*16 + lm] = f2bf_rhu(acc[rr] * 0.125f);
      bv0 = nb0; bv1 = nb1;
    }
  }
  __syncthreads();

  // ---------- phase 2: decay + double softmax, wave-per-row (4 rows/wave) ----------
  const int jA0 = lane * 8, jB0 = 512 + lane * 8;

  // C3: scores are row-invariant per (b,h) — hoist unpack + raw exp
  float cH[16], erH[16];
  if (C3){
    const float* c3p = a.c3 + ((size_t)b * H + h) * S;
    #pragma unroll
    for (int sg = 0; sg < 2; sg++)
      #pragma unroll
      for (int p4 = 0; p4 < 2; p4++){
        float4 x = *(const float4*)&c3p[sg*512 + lane*8 + p4*4];
        cH[sg*8+p4*4+0] = x.x * LOG2E; cH[sg*8+p4*4+1] = x.y * LOG2E;
        cH[sg*8+p4*4+2] = x.z * LOG2E; cH[sg*8+p4*4+3] = x.w * LOG2E;
      }
    #pragma unroll
    for (int k = 0; k < 16; k++) erH[k] = EXP2(cH[k]);
  }

  auto decay_row = [&](const float (&c)[16], const float (&er)[16],
                       const int i, unsigned short* rowp, const int rl){
    const int jmax = i + a.diag;
    const bool skipB = (jmax < 512);     // wave-uniform
    float pl[16];
    float runA = 0.f;
    #pragma unroll
    for (int k = 0; k < 8; k++){
      float e = (jA0 + k <= jmax) ? er[k] : 0.f;
      runA += e; pl[k] = runA;
    }
    float sA, TA;
    wave_scan64(runA, lane, sA, TA);
    float T = TA, sB = 0.f, runB = 0.f;
    if (!skipB){
      #pragma unroll
      for (int k = 0; k < 8; k++){
        float e = (jB0 + k <= jmax) ? er[8+k] : 0.f;
        runB += e; pl[8+k] = runB;
      }
      float TB;
      wave_scan64(runB, lane, sB, TB);
      T = TA + TB;
    }
    const float inv1 = RCPF(T);
    const float cbaseA = (T - (sA - runA)) * inv1;
    const float fiA = (float)(i - jA0);
    float ls2 = 0.f;
    #pragma unroll
    for (int k = 0; k < 8; k++){
      float remn = fmaf(-pl[k], inv1, cbaseA);
      float pos  = fabsf(fiA - (float)k);
      float dist = SQRTF(fmaxf(remn * pos, 0.f));
      float eff  = fmaxf(EXP2(gm2 * dist), 1e-5f);
      float pp   = EXP2(c[k] * eff);
      ls2 += pp; pl[k] = pp;
    }
    if (!skipB){
      const float cbaseB = (T - (TA + sB - runB)) * inv1;
      const float fiB = (float)(i - jB0);
      #pragma unroll
      for (int k = 0; k < 8; k++){
        float remn = fmaf(-pl[8+k], inv1, cbaseB);
        float pos  = fabsf(fiB - (float)k);
        float dist = SQRTF(fmaxf(remn * pos, 0.f));
        float eff  = fmaxf(EXP2(gm2 * dist), 1e-5f);
        float pp   = EXP2(c[8+k] * eff);
        ls2 += pp; pl[8+k] = pp;
      }
    } else {
      #pragma unroll
      for (int k = 0; k < 8; k++){ pl[8+k] = er[8+k]; ls2 += er[8+k]; }
    }
    ls2 = wave_sum64(ls2);
    if (lane == 0) ls2s[rl] = RCPF(ls2);
    #pragma unroll
    for (int sg = 0; sg < 2; sg++){
      uint4 o;
      o.x = pk_rhu(pl[sg*8+0], pl[sg*8+1]);
      o.y = pk_rhu(pl[sg*8+2], pl[sg*8+3]);
      o.z = pk_rhu(pl[sg*8+4], pl[sg*8+5]);
      o.w = pk_rhu(pl[sg*8+6], pl[sg*8+7]);
      *(uint4*)&rowp[sg*512 + lane*8] = o;
    }
  };

  for (int rloc = 0; rloc < 4; rloc++){
    const int rl = w*4 + rloc;
    const int i = i0 + rl;
    unsigned short* rowp = &att[rl * ATT_LD];
    if (C3 && a.zero_pad && i == 0){
      uint4 zz = make_uint4(0u,0u,0u,0u);
      *(uint4*)&rowp[jA0] = zz;
      *(uint4*)&rowp[jB0] = zz;
      if (lane == 0) ls2s[0] = 1.f;
      continue;
    }
    if (C3){
      decay_row(cH, erH, i, rowp, rl);
    } else {
      float c[16], er[16];
      #pragma unroll
      for (int sg = 0; sg < 2; sg++){
        uint4 u = *(const uint4*)&rowp[sg*512 + lane*8];
        unsigned int uu[4] = {u.x, u.y, u.z, u.w};
        #pragma unroll
        for (int mel = 0; mel < 4; mel++){
          c[sg*8 + mel*2]     = bf2f(uu[mel] & 0xffffu) * LOG2E;
          c[sg*8 + mel*2 + 1] = bf2f(uu[mel] >> 16) * LOG2E;
        }
      }
      #pragma unroll
      for (int k = 0; k < 16; k++) er[k] = EXP2(c[k]);
      decay_row(c, er, i, rowp, rl);
    }
  }
  __syncthreads();

  // ---------- phase 3: ctx = att @ V (VT prefetched from global), scale by inv2 ----------
  f32x4 acc = (f32x4){0.f,0.f,0.f,0.f};
  const unsigned short* vrow = &vtp[(size_t)(w*16 + lm) * S];
  bf16x8 bv0 = *(const bf16x8*)&vrow[q*8];
  bf16x8 bv1 = *(const bf16x8*)&vrow[32 + q*8];
  for (int kc = 0; kc < S; kc += 64){
    bf16x8 nb0, nb1;
    if (kc + 64 < S){
      nb0 = *(const bf16x8*)&vrow[kc + 64 + q*8];
      nb1 = *(const bf16x8*)&vrow[kc + 96 + q*8];
    }
    bf16x8 a0 = *(const bf16x8*)&att[lm * ATT_LD + kc + q*8];
    bf16x8 a1 = *(const bf16x8*)&att[lm * ATT_LD + kc + 32 + q*8];
    acc = MFMA(a0, bv0, acc);
    acc = MFMA(a1, bv1, acc);
    bv0 = nb0; bv1 = nb1;
  }
  #pragma unroll
  for (int rr = 0; rr < 4; rr++){
    const int rl = q*4 + rr;
    const float sc = ls2s[rl];
    const int row = i0 + rl;
    ctxp[((size_t)b * S + row) * D + h * DKH + w*16 + lm] = f2bf(acc[rr] * sc);
  }
}

// ================= residual + LayerNorm -> bf16 (batched) =================
struct LNJobs {
  const float* resid[2];
  const float* y[2];
  const float* ls[2];
  const float* lb[2];
  unsigned short* out[2];
  int bcast[2];
};
__global__ __launch_bounds__(256) void ln_residual_b(LNJobs j)
{
  const int z = blockIdx.y;
  const int r = blockIdx.x, t = threadIdx.x;
  __shared__ float red[256];
  const size_t base = (size_t)r * D;
  const float* resid = j.resid[z];
  const float* y = j.y[z];
  const int bcast = j.bcast[z];
  float r0 = bcast ? resid[t]       : resid[base + t];
  float r1 = bcast ? resid[t + 256] : resid[base + t + 256];
  float x0 = r0 + y[base + t];
  float x1 = r1 + y[base + t + 256];
  float mean = blk_sum(red, t, x0 + x1) * (1.0f / 512.0f);
  float d0 = x0 - mean, d1 = x1 - mean;
  float var = blk_sum(red, t, d0*d0 + d1*d1) * (1.0f / 512.0f);
  float inv = rsqrtf(var + 1e-5f);
  j.out[z][base + t]       = f2bf(d0 * inv * j.ls[z][t]       + j.lb[z][t]);
  j.out[z][base + t + 256] = f2bf(d1 * inv * j.ls[z][t + 256] + j.lb[z][t + 256]);
}

// ================= fp32 -> bf16 conversions =================
struct CvtJobs {
  const float* s[12];
  unsigned short* d[12];
  int n[12];
};
__global__ __launch_bounds__(256) void cvt_all(CvtJobs jb){
  const int z = blockIdx.y;
  const int n = jb.n[z];
  const float* s = jb.s[z];
  unsigned short* d = jb.d[z];
  for (int idx = blockIdx.x * 256 + threadIdx.x; idx < n; idx += gridDim.x * 256)
    d[idx] = f2bf(s[idx]);
}

// ================= know-derived small kernels (merged) =================
__global__ __launch_bounds__(256) void know_kernel(
    const float* __restrict__ know, const float* __restrict__ Wq3,
    const float* __restrict__ bq3, float* __restrict__ q3,
    const float* __restrict__ Wlk, const float* __restrict__ blk_,
    float* __restrict__ keyt)
{
  if (blockIdx.x < 128){
    const int wv = (blockIdx.x * 256 + threadIdx.x) >> 6;
    const int lane = threadIdx.x & 63;
    const float* wr = Wq3 + (size_t)wv * 512 + lane * 8;
    const float* kr = know + lane * 8;
    float4 w0 = *(const float4*)&wr[0], w1 = *(const float4*)&wr[4];
    float4 k0 = *(const float4*)&kr[0], k1 = *(const float4*)&kr[4];
    float p = w0.x*k0.x + w0.y*k0.y + w0.z*k0.z + w0.w*k0.w
            + w1.x*k1.x + w1.y*k1.y + w1.z*k1.z + w1.w*k1.w;
    p = wave_sum64(p);
    if (lane == 0) q3[wv] = p + bq3[wv];
  } else {
    int idx = (blockIdx.x - 128) * 256 + threadIdx.x;
    int h = idx >> 9, n = idx & 511;
    float acc = 0.f;
    for (int i = 0; i < 64; i++) acc += know[h * 64 + i] * Wlk[(size_t)n * 64 + i];
    keyt[idx] = 1.f / (1.f + __expf(-(acc + blk_[n])));
  }
}

__global__ __launch_bounds__(256) void scores3_kernel(
    const float* __restrict__ q3, const unsigned short* __restrict__ k3,
    float* __restrict__ c3)
{
  int idx = blockIdx.x * 256 + threadIdx.x;   // (b*H+h)*S + j
  int j  = idx & (S - 1);
  int bh = idx >> 10;
  int h  = bh & 7, b = bh >> 3;
  const unsigned short* kp = k3 + ((size_t)b * S + j) * D + h * DKH;
  const float* qp = q3 + h * DKH;
  float acc = 0.f;
  #pragma unroll
  for (int d8 = 0; d8 < 64; d8 += 8){
    uint4 u = *(const uint4*)&kp[d8];
    unsigned int uu[4] = {u.x, u.y, u.z, u.w};
    #pragma unroll
    for (int mel = 0; mel < 4; mel++){
      acc += qp[d8 + 2*mel]     * bf2f(uu[mel] & 0xffffu);
      acc += qp[d8 + 2*mel + 1] * bf2f(uu[mel] >> 16);
    }
  }
  c3[idx] = acc * 0.125f;
}

__global__ __launch_bounds__(256) void alphas_kernel(
    const float* __restrict__ keyt, const float* __restrict__ q_emb,
    float* __restrict__ alpha)
{
  const int row = blockIdx.x * 4 + (threadIdx.x >> 6);
  const int l = threadIdx.x & 63;
  const int h = l >> 3, sub = l & 7;
  const float* qr = q_emb + (size_t)row * D;
  const float* kt = keyt + h * D;
  float p = 0.f;
  for (int d = sub; d < D; d += 8) p += kt[d] * qr[d];
  p += __shfl_xor(p, 1, 64);
  p += __shfl_xor(p, 2, 64);
  p += __shfl_xor(p, 4, 64);
  float m = p;
  m = fmaxf(m, __shfl_xor(m, 8, 64));
  m = fmaxf(m, __shfl_xor(m, 16, 64));
  m = fmaxf(m, __shfl_xor(m, 32, 64));
  float e = __expf(p - m);
  float ssum = e;
  ssum += __shfl_xor(ssum, 8, 64);
  ssum += __shfl_xor(ssum, 16, 64);
  ssum += __shfl_xor(ssum, 32, 64);
  if (sub == 0) alpha[(size_t)row * H + h] = e / ssum;
}

// ================= fused val GEMM + sigmoid + alpha-combine =================
__global__ __launch_bounds__(256) void val_fused(
    const unsigned short* __restrict__ Ah,
    const unsigned short* __restrict__ Wv,
    const float* __restrict__ blv,
    const float* __restrict__ alpha,
    float* __restrict__ out)
{
  __shared__ __align__(16) short As[128][32];
  __shared__ __align__(16) short Ws[128][32];
  __shared__ float als[128];
  const int t = threadIdx.x;
  const int n0 = blockIdx.x * 128, m0 = blockIdx.y * 128;
  if (t < 128) als[t] = alpha[m0 + t];
  const int w = t >> 6, lane = t & 63;
  const int wm = (w >> 1) << 6, wn = (w & 1) << 6;
  const int lm = lane & 15, q = lane >> 4;
  const int r = t >> 2, cc = (t & 3) << 3;
  f32x4 acc[4][4];
  #pragma unroll
  for (int a_ = 0; a_ < 4; a_++)
    #pragma unroll
    for (int b_ = 0; b_ < 4; b_++)
      acc[a_][b_] = (f32x4){0.f, 0.f, 0.f, 0.f};
  for (int k0 = 0; k0 < 64; k0 += 32){
    *(uint4*)&As[r][cc]      = *(const uint4*)&Ah[(size_t)(m0 + r) * 64 + k0 + cc];
    *(uint4*)&As[r + 64][cc] = *(const uint4*)&Ah[(size_t)(m0 + r + 64) * 64 + k0 + cc];
    *(uint4*)&Ws[r][cc]      = *(const uint4*)&Wv[(size_t)(n0 + r) * 64 + k0 + cc];
    *(uint4*)&Ws[r + 64][cc] = *(const uint4*)&Wv[(size_t)(n0 + r + 64) * 64 + k0 + cc];
    __syncthreads();
    bf16x8 af[4], bf[4];
    #pragma unroll
    for (int mt = 0; mt < 4; mt++) af[mt] = *(const bf16x8*)&As[wm + mt*16 + lm][q*8];
    #pragma unroll
    for (int nt = 0; nt < 4; nt++) bf[nt] = *(const bf16x8*)&Ws[wn + nt*16 + lm][q*8];
    #pragma unroll
    for (int mt = 0; mt < 4; mt++)
      #pragma unroll
      for (int nt = 0; nt < 4; nt++)
        acc[mt][nt] = MFMA(af[mt], bf[nt], acc[mt][nt]);
    __syncthreads();
  }
  #pragma unroll
  for (int nt = 0; nt < 4; nt++){
    const int n = n0 + wn + nt*16 + lm;
    const float bs = blv[n];
    #pragma unroll
    for (int mt = 0; mt < 4; mt++){
      const int mb = m0 + wm + mt*16;
      f32x4 c = acc[mt][nt];
      float part = 0.f;
      #pragma unroll
      for (int rr = 0; rr < 4; rr++){
        const int ml = (mb - m0) + (q << 2) + rr;
        float sg = 1.f / (1.f + __expf(-(c[rr] + bs)));
        part += als[ml] * sg;
      }
      part += __shfl_xor(part, 16, 64);
      if ((q & 1) == 0){
        const int srow = (mb >> 3) + (q >> 1);
        out[(size_t)srow * D + n] = part;
      }
    }
  }
}

// ================= orchestration =================
extern "C" void kernel_launch(void* const* d_in, const int* in_sizes, int n_in,
                              void* d_out, int out_size, void* d_ws, size_t ws_size,
                              hipStream_t stream) {
  const float* q_emb  = (const float*)d_in[0];
  const float* qa_emb = (const float*)d_in[1];
  const float* Wq1 = (const float*)d_in[2],  *bq1 = (const float*)d_in[3];
  const float* Wv1 = (const float*)d_in[4],  *bv1 = (const float*)d_in[5];
  const float* Wo1 = (const float*)d_in[6],  *bo1 = (const float*)d_in[7];
  const float* g1  = (const float*)d_in[8],  *ls1 = (const float*)d_in[9],  *lb1 = (const float*)d_in[10];
  const float* Wq2 = (const float*)d_in[11], *bq2 = (const float*)d_in[12];
  const float* Wv2 = (const float*)d_in[13], *bv2 = (const float*)d_in[14];
  const float* Wo2 = (const float*)d_in[15], *bo2 = (const float*)d_in[16];
  const float* g2  = (const float*)d_in[17], *ls2 = (const float*)d_in[18], *lb2 = (const float*)d_in[19];
  const float* Wq3 = (const float*)d_in[20], *bq3 = (const float*)d_in[21];
  const float* Wk3 = (const float*)d_in[22], *bk3 = (const float*)d_in[23];
  const float* Wv3 = (const float*)d_in[24], *bv3 = (const float*)d_in[25];
  const float* Wo3 = (const float*)d_in[26], *bo3 = (const float*)d_in[27];
  const float* g3  = (const float*)d_in[28], *ls3 = (const float*)d_in[29], *lb3 = (const float*)d_in[30];
  const float* know = (const float*)d_in[31];
  const float* Wlk  = (const float*)d_in[32], *b_lk = (const float*)d_in[33];
  const float* Wlv  = (const float*)d_in[34], *b_lv = (const float*)d_in[35];
  float* outp = (float*)d_out;

  const size_t NSD = (size_t)BB * S * D;   // 2,097,152
  unsigned short* p = (unsigned short*)d_ws;
  unsigned short* qk1b = p; p += NSD;
  unsigned short* v1b  = p; p += NSD;
  unsigned short* qk2b = p; p += NSD;
  unsigned short* v2b  = p; p += NSD;
  unsigned short* k3b  = p; p += NSD;
  unsigned short* v3b  = p; p += NSD;
  unsigned short* ctx1b= p; p += NSD;
  unsigned short* ctx2b= p; p += NSD;
  unsigned short* ctx3b= p; p += NSD;
  unsigned short* xqb  = p; p += NSD;
  unsigned short* xab  = p; p += NSD;
  unsigned short* hqb  = p; p += NSD;
  unsigned short* hab  = p; p += NSD;
  unsigned short* hfb  = p; p += NSD;
  unsigned short* vt1  = p; p += NSD;   // [32][64][1024]
  unsigned short* vt2  = p; p += NSD;
  unsigned short* vt3  = p; p += NSD;
  unsigned short* wb   = p; p += (size_t)9 * D * D;
  unsigned short* wlvb = p; p += (size_t)D * DKH;
  float* yv0   = (float*)p;
  float* yv1   = yv0 + NSD;
  float* q3    = yv1 + NSD;
  float* keyt  = q3 + 512;
  float* c3    = keyt + 4096;
  float* alpha = c3 + (size_t)BB * H * S;

  unsigned short* Wq1b = wb + 0*(size_t)D*D;
  unsigned short* Wv1b = wb + 1*(size_t)D*D;
  unsigned short* Wo1b = wb + 2*(size_t)D*D;
  unsigned short* Wq2b = wb + 3*(size_t)D*D;
  unsigned short* Wv2b = wb + 4*(size_t)D*D;
  unsigned short* Wo2b = wb + 5*(size_t)D*D;
  unsigned short* Wk3b = wb + 6*(size_t)D*D;
  unsigned short* Wv3b = wb + 7*(size_t)D*D;
  unsigned short* Wo3b = wb + 8*(size_t)D*D;

  // ---- conversions ----
  CvtJobs jb;
  jb.s[0] = q_emb;  jb.d[0] = xqb;  jb.n[0] = (int)NSD;
  jb.s[1] = qa_emb; jb.d[1] = xab;  jb.n[1] = (int)NSD;
  jb.s[2] = Wq1; jb.d[2] = Wq1b; jb.n[2] = D*D;
  jb.s[3] = Wv1; jb.d[3] = Wv1b; jb.n[3] = D*D;
  jb.s[4] = Wo1; jb.d[4] = Wo1b; jb.n[4] = D*D;
  jb.s[5] = Wq2; jb.d[5] = Wq2b; jb.n[5] = D*D;
  jb.s[6] = Wv2; jb.d[6] = Wv2b; jb.n[6] = D*D;
  jb.s[7] = Wo2; jb.d[7] = Wo2b; jb.n[7] = D*D;
  jb.s[8] = Wk3; jb.d[8] = Wk3b; jb.n[8] = D*D;
  jb.s[9] = Wv3; jb.d[9] = Wv3b; jb.n[9] = D*D;
  jb.s[10] = Wo3; jb.d[10] = Wo3b; jb.n[10] = D*D;
  jb.s[11] = Wlv; jb.d[11] = wlvb; jb.n[11] = D*DKH;
  cvt_all<<<dim3(256, 12), 256, 0, stream>>>(jb);

  // ---- blocks 1&2: projections (z=4) ----
  {
    GemmJobs g;
    g.A[0]=xqb; g.W[0]=Wq1b; g.bias[0]=bq1; g.C[0]=qk1b;
    g.A[1]=xqb; g.W[1]=Wv1b; g.bias[1]=bv1; g.C[1]=v1b;
    g.A[2]=xab; g.W[2]=Wq2b; g.bias[2]=bq2; g.C[2]=qk2b;
    g.A[3]=xab; g.W[3]=Wv2b; g.bias[3]=bv2; g.C[3]=v2b;
    mfma_gemm_b<1><<<dim3(4, 32, 4), 256, 0, stream>>>(g);
  }
  { VTArgs a; a.v[0]=v1b; a.v[1]=v2b; a.vt[0]=vt1; a.vt[1]=vt2;
    vt_kernel<<<dim3(16, 32, 2), 256, 0, stream>>>(a); }
  { FAArgs a;
    a.qk[0]=qk1b; a.qk[1]=qk2b; a.vt[0]=vt1; a.vt[1]=vt2;
    a.ctx[0]=ctx1b; a.ctx[1]=ctx2b; a.g[0]=g1; a.g[1]=g2;
    a.c3=nullptr; a.diag=0; a.zero_pad=0;
    fused_attn<0><<<dim3(64, 32, 2), 256, 0, stream>>>(a); }
  {
    GemmJobs g;
    g.A[0]=ctx1b; g.W[0]=Wo1b; g.bias[0]=bo1; g.C[0]=yv0;
    g.A[1]=ctx2b; g.W[1]=Wo2b; g.bias[1]=bo2; g.C[1]=yv1;
    g.A[2]=ctx1b; g.W[2]=Wo1b; g.bias[2]=bo1; g.C[2]=yv0;
    g.A[3]=ctx1b; g.W[3]=Wo1b; g.bias[3]=bo1; g.C[3]=yv0;
    mfma_gemm_b<0><<<dim3(4, 32, 2), 256, 0, stream>>>(g);
  }
  {
    LNJobs lj;
    lj.resid[0]=q_emb;  lj.y[0]=yv0; lj.ls[0]=ls1; lj.lb[0]=lb1; lj.out[0]=hqb; lj.bcast[0]=0;
    lj.resid[1]=qa_emb; lj.y[1]=yv1; lj.ls[1]=ls2; lj.lb[1]=lb2; lj.out[1]=hab; lj.bcast[1]=0;
    ln_residual_b<<<dim3(BB*S, 2), 256, 0, stream>>>(lj);
  }

  // ---- block 3 ----
  know_kernel<<<144, 256, 0, stream>>>(know, Wq3, bq3, q3, Wlk, b_lk, keyt);
  {
    GemmJobs g;
    g.A[0]=hqb; g.W[0]=Wk3b; g.bias[0]=bk3; g.C[0]=k3b;
    g.A[1]=hab; g.W[1]=Wv3b; g.bias[1]=bv3; g.C[1]=v3b;
    g.A[2]=hqb; g.W[2]=Wk3b; g.bias[2]=bk3; g.C[2]=k3b;
    g.A[3]=hqb; g.W[3]=Wk3b; g.bias[3]=bk3; g.C[3]=k3b;
    mfma_gemm_b<1><<<dim3(4, 32, 2), 256, 0, stream>>>(g);
  }
  { VTArgs a; a.v[0]=v3b; a.v[1]=v3b; a.vt[0]=vt3; a.vt[1]=vt3;
    vt_kernel<<<dim3(16, 32, 1), 256, 0, stream>>>(a); }
  scores3_kernel<<<128, 256, 0, stream>>>(q3, k3b, c3);
  { FAArgs a;
    a.qk[0]=k3b; a.qk[1]=k3b; a.vt[0]=vt3; a.vt[1]=vt3;
    a.ctx[0]=ctx3b; a.ctx[1]=ctx3b; a.g[0]=g3; a.g[1]=g3;
    a.c3=c3; a.diag=-1; a.zero_pad=1;
    fused_attn<1><<<dim3(64, 32, 1), 256, 0, stream>>>(a); }
  {
    GemmJobs g;
    g.A[0]=ctx3b; g.W[0]=Wo3b; g.bias[0]=bo3; g.C[0]=yv0;
    g.A[1]=ctx3b; g.W[1]=Wo3b; g.bias[1]=bo3; g.C[1]=yv0;
    g.A[2]=ctx3b; g.W[2]=Wo3b; g.bias[2]=bo3; g.C[2]=yv0;
    g.A[3]=ctx3b; g.W[3]=Wo3b; g.bias[3]=bo3; g.C[3]=yv0;
    mfma_gemm_b<0><<<dim3(4, 32, 1), 256, 0, stream>>>(g);
  }
  {
    LNJobs lj;
    lj.resid[0]=know; lj.y[0]=yv0; lj.ls[0]=ls3; lj.lb[0]=lb3; lj.out[0]=hfb; lj.bcast[0]=1;
    lj.resid[1]=know; lj.y[1]=yv0; lj.ls[1]=ls3; lj.lb[1]=lb3; lj.out[1]=hfb; lj.bcast[1]=1;
    ln_residual_b<<<dim3(BB*S, 1), 256, 0, stream>>>(lj);
  }

  // ---- final combine ----
  alphas_kernel<<<1024, 256, 0, stream>>>(keyt, q_emb, alpha);
  val_fused<<<dim3(4, 256), 256, 0, stream>>>(hfb, wlvb, b_lv, alpha, outp);
}